// Round 3
// baseline (2870.528 us; speedup 1.0000x reference)
//
#include <hip/hip_runtime.h>
#include <hip/hip_bf16.h>

typedef __hip_bfloat16 bf16;

#define B_      2
#define S_      2048
#define IN_     512
#define E_      1024
#define INNER_  2048
#define NH_     4
#define DH_     512
#define T_      (B_*S_)      // 4096 tokens
#define EPS_CELL 1e-6f
#define LN_EPS_  1e-5f

__device__ inline float b2f(bf16 x){ return __bfloat162float(x); }
__device__ inline bf16  f2b(float x){ return __float2bfloat16(x); }
__device__ inline float us2f(unsigned short u){ union{unsigned int i; float f;} v; v.i = ((unsigned int)u)<<16; return v.f; }
__device__ inline float u2f(unsigned int u){ union{unsigned int i; float f;} v; v.i = u; return v.f; }
__device__ inline unsigned short f2bu(float x){ bf16 t = __float2bfloat16(x); unsigned short r; __builtin_memcpy(&r,&t,2); return r; }
__device__ inline void unpack8(uint4 u, float* f){
  f[0]=u2f(u.x<<16); f[1]=u2f(u.x&0xffff0000u);
  f[2]=u2f(u.y<<16); f[3]=u2f(u.y&0xffff0000u);
  f[4]=u2f(u.z<<16); f[5]=u2f(u.z&0xffff0000u);
  f[6]=u2f(u.w<<16); f[7]=u2f(u.w&0xffff0000u);
}
__device__ inline void load4(const float* p, float* f){
  float4 v = *(const float4*)p; f[0]=v.x; f[1]=v.y; f[2]=v.z; f[3]=v.w;
}
__device__ inline void load4(const bf16* p, float* f){
  ushort4 v = *(const ushort4*)p; f[0]=us2f(v.x); f[1]=us2f(v.y); f[2]=us2f(v.z); f[3]=us2f(v.w);
}
__device__ inline void stv(bf16* p, float v){ *p = f2b(v); }
__device__ inline void stv(float* p, float v){ *p = v; }

// ---------------- generic GEMM: C[M,N] = A[M,K]@W[K,N] + bias ----------------
// A (fp32 or bf16) row-major (stride lda), W fp32 row-major (stride N), C bf16 (ldc)
template<typename AT>
__global__ __launch_bounds__(256) void gemm_bias(const AT* __restrict__ A,
    const float* __restrict__ W, const float* __restrict__ bias, bf16* __restrict__ C,
    int M, int N, int Kd, int lda, int ldc){
  __shared__ float As[16][68];   // transposed: As[k][m]
  __shared__ float Bs[16][68];
  int tid = threadIdx.x;
  int tx = tid & 15, ty = tid >> 4;
  int m0 = blockIdx.y*64, n0 = blockIdx.x*64;
  float acc[4][4];
  #pragma unroll
  for (int i=0;i<4;i++){
    #pragma unroll
    for (int j=0;j<4;j++) acc[i][j]=0.f;
  }
  for (int k0=0; k0<Kd; k0+=16){
    int idx = tid*4;
    { int ar = idx>>4, ac = idx&15;
      float f[4]; load4(A + (size_t)(m0+ar)*lda + k0 + ac, f);
      As[ac+0][ar]=f[0]; As[ac+1][ar]=f[1]; As[ac+2][ar]=f[2]; As[ac+3][ar]=f[3]; }
    { int br = idx>>6, bc = idx&63;
      float f[4]; load4(W + (size_t)(k0+br)*N + n0 + bc, f);
      Bs[br][bc+0]=f[0]; Bs[br][bc+1]=f[1]; Bs[br][bc+2]=f[2]; Bs[br][bc+3]=f[3]; }
    __syncthreads();
    #pragma unroll
    for (int kk=0; kk<16; kk++){
      float a4[4], b4[4];
      *(float4*)a4 = *(const float4*)&As[kk][ty*4];
      *(float4*)b4 = *(const float4*)&Bs[kk][tx*4];
      #pragma unroll
      for (int i=0;i<4;i++){
        #pragma unroll
        for (int j=0;j<4;j++) acc[i][j] += a4[i]*b4[j];
      }
    }
    __syncthreads();
  }
  float bb[4];
  #pragma unroll
  for (int j=0;j<4;j++) bb[j] = bias[n0+tx*4+j];
  #pragma unroll
  for (int i=0;i<4;i++){
    int row = m0+ty*4+i;
    ushort4 o4;
    o4.x=f2bu(acc[i][0]+bb[0]); o4.y=f2bu(acc[i][1]+bb[1]);
    o4.z=f2bu(acc[i][2]+bb[2]); o4.w=f2bu(acc[i][3]+bb[3]);
    *(ushort4*)(C + (size_t)row*ldc + n0 + tx*4) = o4;
  }
}

// ---------------- layernorm over rows of length E_ (opt. fused add) ----------------
template<typename OutT>
__global__ __launch_bounds__(256) void ln_rows(const bf16* __restrict__ X,
    const bf16* __restrict__ Xadd, const float* __restrict__ w, OutT* __restrict__ Y){
  int row = blockIdx.x, tid = threadIdx.x;
  size_t base = (size_t)row*E_;
  float vals[4], s=0.f, s2=0.f;
  #pragma unroll
  for (int e=0;e<4;e++){
    int c = e*256+tid;
    float v = b2f(X[base+c]);
    if (Xadd) v += b2f(Xadd[base+c]);
    vals[e]=v; s+=v; s2+=v*v;
  }
  __shared__ float sa[256], sb[256];
  sa[tid]=s; sb[tid]=s2; __syncthreads();
  for (int off=128; off>0; off>>=1){
    if (tid<off){ sa[tid]+=sa[tid+off]; sb[tid]+=sb[tid+off]; }
    __syncthreads();
  }
  float mean = sa[0]*(1.f/E_);
  float var  = sb[0]*(1.f/E_) - mean*mean;
  float rstd = rsqrtf(var + LN_EPS_);
  #pragma unroll
  for (int e=0;e<4;e++){
    int c = e*256+tid;
    stv(&Y[base+c], (vals[e]-mean)*rstd*w[c]);
  }
}

// ---------------- causal depthwise conv (K=4) + SiLU ----------------
// x_m lives in up[:, 0:2048] with row stride 4096
__global__ __launch_bounds__(256) void conv_silu_kernel(const bf16* __restrict__ up,
    const float* __restrict__ cw, const float* __restrict__ cb, bf16* __restrict__ xca){
  size_t gid = (size_t)blockIdx.x*256 + threadIdx.x;   // over T_*INNER_
  int c = (int)(gid & (INNER_-1));
  size_t bs = gid >> 11;
  int s = (int)(bs & (S_-1));
  float acc = cb[c];
  #pragma unroll
  for (int t=0;t<4;t++){
    int sp = s-3+t;
    if (sp>=0) acc += b2f(up[(bs + (size_t)(t-3))*(size_t)(2*INNER_) + c]) * cw[c*4+t];
  }
  float sg = 1.f/(1.f+expf(-acc));
  xca[gid] = f2b(acc*sg);
}

// ---------------- block-diagonal (4x4) q/k/v projections ----------------
__global__ __launch_bounds__(256) void headwise_kernel(const bf16* __restrict__ xca,
    const bf16* __restrict__ up,
    const float* __restrict__ qw, const float* __restrict__ qb,
    const float* __restrict__ kw, const float* __restrict__ kb,
    const float* __restrict__ vw, const float* __restrict__ vb,
    bf16* __restrict__ q, bf16* __restrict__ k, bf16* __restrict__ v){
  size_t gid = (size_t)blockIdx.x*256 + threadIdx.x;
  int c = (int)(gid & (INNER_-1));
  size_t bs = gid >> 11;
  int hw = c>>2, o = c&3;
  float aq=qb[c], ak=kb[c], av=vb[c];
  size_t xb = bs*(size_t)INNER_ + (hw<<2);
  size_t mb = bs*(size_t)(2*INNER_) + (hw<<2);
  #pragma unroll
  for (int d=0; d<4; d++){
    float xc = b2f(xca[xb+d]);
    float xm = b2f(up[mb+d]);
    int wi = hw*16 + o*4 + d;   // w[h][o][d]
    aq += xc*qw[wi]; ak += xc*kw[wi]; av += xm*vw[wi];
  }
  q[gid]=f2b(aq); k[gid]=f2b(ak); v[gid]=f2b(av);
}

// ---------------- ig/fg gate dots: (B,S) x (6144 -> 4+4) ----------------
__global__ __launch_bounds__(256) void gates_kernel(const bf16* __restrict__ q,
    const bf16* __restrict__ k, const bf16* __restrict__ v,
    const float* __restrict__ igw, const float* __restrict__ igb,
    const float* __restrict__ fgw, const float* __restrict__ fgb,
    float* __restrict__ igo, float* __restrict__ fgo){
  int bs = blockIdx.x, tid = threadIdx.x;
  int b = bs >> 11, s = bs & (S_-1);
  float pi[4]={0,0,0,0}, pf[4]={0,0,0,0};
  size_t rb = (size_t)bs*INNER_;
  for (int c=tid; c<INNER_; c+=256){
    float qv=b2f(q[rb+c]), kv=b2f(k[rb+c]), vv=b2f(v[rb+c]);
    #pragma unroll
    for (int n2=0;n2<4;n2++){
      pi[n2] += qv*igw[c*4+n2] + kv*igw[(INNER_+c)*4+n2] + vv*igw[(2*INNER_+c)*4+n2];
      pf[n2] += qv*fgw[c*4+n2] + kv*fgw[(INNER_+c)*4+n2] + vv*fgw[(2*INNER_+c)*4+n2];
    }
  }
  __shared__ float red[8][256];
  #pragma unroll
  for (int n2=0;n2<4;n2++){ red[n2][tid]=pi[n2]; red[4+n2][tid]=pf[n2]; }
  __syncthreads();
  for (int off=128; off>0; off>>=1){
    if (tid<off){
      #pragma unroll
      for (int n2=0;n2<8;n2++) red[n2][tid]+=red[n2][tid+off];
    }
    __syncthreads();
  }
  if (tid<4){
    igo[((size_t)(b*NH_+tid))*S_ + s] = red[tid][0]   + igb[tid];
    fgo[((size_t)(b*NH_+tid))*S_ + s] = red[4+tid][0] + fgb[tid];
  }
}

// ---------------- per-head scan: F=cumsum(logsigmoid(fg)); a=ig-F; M=prefmax(a) ----
__global__ __launch_bounds__(256) void scan8(const float* __restrict__ igp,
    const float* __restrict__ fgp, float* __restrict__ ap,
    float* __restrict__ Mp, float* __restrict__ flp){
  int h = blockIdx.x, tid = threadIdx.x;
  const float* fg = fgp + (size_t)h*S_;
  const float* ig = igp + (size_t)h*S_;
  int base = tid*8;
  float loc[8], run = 0.f;
  #pragma unroll
  for (int e=0;e<8;e++){
    float x = fg[base+e];
    float ls = fminf(x,0.f) - log1pf(expf(-fabsf(x)));
    run += ls; loc[e] = run;
  }
  __shared__ float sd[256];
  sd[tid]=run; __syncthreads();
  if (tid==0){ float r=0.f; for(int t=0;t<256;t++){ float t0=sd[t]; sd[t]=r; r+=t0; } }
  __syncthreads();
  float off = sd[tid];
  float lm[8], rm = -3e38f;
  #pragma unroll
  for (int e=0;e<8;e++){
    float F = loc[e]+off; loc[e]=F;
    float aj = ig[base+e]-F;
    ap[(size_t)h*S_+base+e]=aj;
    rm = fmaxf(rm, aj); lm[e]=rm;
  }
  __syncthreads();
  sd[tid]=rm; __syncthreads();
  if (tid==0){ float r=-3e38f; for(int t=0;t<256;t++){ float t0=sd[t]; sd[t]=r; r=fmaxf(r,t0); } }
  __syncthreads();
  float offm = sd[tid];
  #pragma unroll
  for (int e=0;e<8;e++){
    float M = fmaxf(lm[e], offm);
    Mp[(size_t)h*S_+base+e]=M;
    flp[(size_t)h*S_+base+e]=expf(-loc[e]-M);
  }
}

// ---------------- mLSTM attention, precomputed stabilizers (no online rescale) ----
#define QROW 65   // uint4 per LDS row (64 data + 1 pad)
__global__ __launch_bounds__(256) void attn_kernel(const bf16* __restrict__ qg,
    const bf16* __restrict__ kg, const bf16* __restrict__ vg,
    const float* __restrict__ ap, const float* __restrict__ Mp,
    const float* __restrict__ flp, bf16* __restrict__ hout){
  int it = blockIdx.x, bn = blockIdx.y;
  int b = bn >> 2, n = bn & 3;
  int i0 = it*32;
  __shared__ uint4 qs[32*QROW];
  __shared__ uint4 ks[32*QROW];
  __shared__ uint4 vs[32*QROW];
  __shared__ float ws[32][33];
  __shared__ float Ms[32], Fls[32], rs[32], as_[32];
  int tid = threadIdx.x;
  int irow = tid >> 3, jq = tid & 7;
  #pragma unroll
  for (int e=0;e<8;e++){
    int idx = e*256+tid; int r = idx>>6, c = idx&63;
    qs[r*QROW+c] = *(const uint4*)(qg + ((size_t)(b*S_+i0+r))*INNER_ + n*DH_ + c*8);
  }
  if (tid < 32){
    size_t o = (size_t)bn*S_ + i0 + tid;
    Ms[tid]=Mp[o]; Fls[tid]=flp[o]; rs[tid]=0.f;
  }
  float acc[64];
  #pragma unroll
  for (int i=0;i<64;i++) acc[i]=0.f;
  const float scale = 0.04419417382415922f;   // 1/sqrt(512)
  for (int jt=0; jt<=it; jt++){
    int j0 = jt*32;
    __syncthreads();   // previous phase3 done before overwriting ks/vs
    #pragma unroll
    for (int e=0;e<8;e++){
      int idx = e*256+tid; int r = idx>>6, c = idx&63;
      size_t go = ((size_t)(b*S_+j0+r))*INNER_ + n*DH_ + c*8;
      ks[r*QROW+c] = *(const uint4*)(kg + go);
      vs[r*QROW+c] = *(const uint4*)(vg + go);
    }
    if (tid < 32) as_[tid] = ap[(size_t)bn*S_ + j0 + tid];
    __syncthreads();
    // phase1: thread computes dots q[irow] . k[jq + 8*jj], jj=0..3
    {
      float d0=0,d1=0,d2=0,d3=0;
      const uint4* qr = &qs[irow*QROW];
      const uint4* k0 = &ks[(jq+ 0)*QROW];
      const uint4* k1 = &ks[(jq+ 8)*QROW];
      const uint4* k2 = &ks[(jq+16)*QROW];
      const uint4* k3 = &ks[(jq+24)*QROW];
      for (int g=0; g<64; g++){
        float qf[8], kf[8];
        unpack8(qr[g], qf);
        unpack8(k0[g], kf);
        #pragma unroll
        for (int e=0;e<8;e++) d0 += qf[e]*kf[e];
        unpack8(k1[g], kf);
        #pragma unroll
        for (int e=0;e<8;e++) d1 += qf[e]*kf[e];
        unpack8(k2[g], kf);
        #pragma unroll
        for (int e=0;e<8;e++) d2 += qf[e]*kf[e];
        unpack8(k3[g], kf);
        #pragma unroll
        for (int e=0;e<8;e++) d3 += qf[e]*kf[e];
      }
      int gi = i0 + irow;
      float dd[4] = {d0,d1,d2,d3};
      float psum = 0.f;
      #pragma unroll
      for (int jj=0;jj<4;jj++){
        int jl = jq + jj*8;
        int gj = j0 + jl;
        float w = 0.f;
        if (gj <= gi) w = dd[jj]*scale*expf(as_[jl]-Ms[irow]);
        ws[irow][jl] = w;
        psum += w;
      }
      atomicAdd(&rs[irow], psum);
    }
    __syncthreads();
    // phase3: acc[d-slice] += w * v ; thread owns uint4 groups {jq + 8t}
    for (int jj=0; jj<32; jj++){
      float w = ws[irow][jj];
      if (w != 0.f){
        const uint4* vr = &vs[jj*QROW + jq];
        #pragma unroll
        for (int t=0;t<8;t++){
          float vf[8]; unpack8(vr[t*8], vf);
          #pragma unroll
          for (int e=0;e<8;e++) acc[t*8+e] += w*vf[e];
        }
      }
    }
  }
  __syncthreads();
  float inv = 1.f/(fmaxf(fabsf(rs[irow]), Fls[irow]) + EPS_CELL);
  size_t ho = ((size_t)(b*S_+i0+irow))*INNER_ + n*DH_;
  #pragma unroll
  for (int t=0;t<8;t++){
    float f[8];
    #pragma unroll
    for (int e=0;e<8;e++) f[e] = acc[t*8+e]*inv;
    uint4 o;
    o.x = (unsigned)f2bu(f[0]) | ((unsigned)f2bu(f[1])<<16);
    o.y = (unsigned)f2bu(f[2]) | ((unsigned)f2bu(f[3])<<16);
    o.z = (unsigned)f2bu(f[4]) | ((unsigned)f2bu(f[5])<<16);
    o.w = (unsigned)f2bu(f[6]) | ((unsigned)f2bu(f[7])<<16);
    *(uint4*)(hout + ho + (size_t)(jq + t*8)*8) = o;
  }
}

// ---------------- head groupnorm + skip + output gate (in-place into z) ----------
__global__ __launch_bounds__(256) void headnorm_gate(const bf16* __restrict__ h,
    const float* __restrict__ onw, const float* __restrict__ skip,
    const bf16* __restrict__ xca, bf16* __restrict__ up){
  int bid = blockIdx.x;
  int n = bid & 3; int bs = bid >> 2;
  int tid = threadIdx.x;
  size_t hbase = (size_t)bs*INNER_ + n*DH_;
  float v0 = b2f(h[hbase+tid]);
  float v1 = b2f(h[hbase+256+tid]);
  __shared__ float sa[256], sb[256];
  sa[tid]=v0+v1; sb[tid]=v0*v0+v1*v1;
  __syncthreads();
  for (int off=128; off>0; off>>=1){
    if (tid<off){ sa[tid]+=sa[tid+off]; sb[tid]+=sb[tid+off]; }
    __syncthreads();
  }
  float mean = sa[0]*(1.f/DH_);
  float var  = sb[0]*(1.f/DH_) - mean*mean;
  float rstd = rsqrtf(var + LN_EPS_);
  #pragma unroll
  for (int e=0;e<2;e++){
    int dl = e*256+tid; int c = n*DH_+dl;
    float hv = e ? v1 : v0;
    float hn = (hv-mean)*rstd*onw[c];
    float hs = hn + skip[c]*b2f(xca[(size_t)bs*INNER_+c]);
    size_t zoff = (size_t)bs*(2*INNER_) + INNER_ + c;
    float zv = b2f(up[zoff]);
    float sz = zv/(1.f+expf(-zv));
    up[zoff] = f2b(hs*sz);   // same element read by same thread -> safe in place
  }
}

extern "C" void kernel_launch(void* const* d_in, const int* in_sizes, int n_in,
                              void* d_out, int out_size, void* d_ws, size_t ws_size,
                              hipStream_t stream) {
  const float* x      = (const float*)d_in[0];
  const float* w_in   = (const float*)d_in[1];
  const float* b_in   = (const float*)d_in[2];
  const float* ln1_w  = (const float*)d_in[3];
  const float* w_up   = (const float*)d_in[4];
  const float* b_up   = (const float*)d_in[5];
  const float* conv_w = (const float*)d_in[6];
  const float* conv_b = (const float*)d_in[7];
  const float* q_w    = (const float*)d_in[8];
  const float* q_b    = (const float*)d_in[9];
  const float* k_w    = (const float*)d_in[10];
  const float* k_b    = (const float*)d_in[11];
  const float* v_w    = (const float*)d_in[12];
  const float* v_b    = (const float*)d_in[13];
  const float* ig_w   = (const float*)d_in[14];
  const float* ig_b   = (const float*)d_in[15];
  const float* fg_w   = (const float*)d_in[16];
  const float* fg_b   = (const float*)d_in[17];
  const float* onw    = (const float*)d_in[18];
  const float* skip   = (const float*)d_in[19];
  const float* w_down = (const float*)d_in[20];
  const float* b_down = (const float*)d_in[21];
  const float* post_w = (const float*)d_in[22];

  char* p = (char*)d_ws;
  auto alloc = [&](size_t bytes)->void*{ void* r = p; p += (bytes + 255) & ~(size_t)255; return r; };
  bf16* h_in = (bf16*)alloc((size_t)T_*E_*2);        // 8 MB
  bf16* xn   = (bf16*)alloc((size_t)T_*E_*2);        // 8 MB (reused as y later)
  bf16* up   = (bf16*)alloc((size_t)T_*2*INNER_*2);  // 32 MB (x_m | z; z later holds h_gated)
  bf16* xca  = (bf16*)alloc((size_t)T_*INNER_*2);    // 16 MB
  bf16* qb_  = (bf16*)alloc((size_t)T_*INNER_*2);
  bf16* kb_  = (bf16*)alloc((size_t)T_*INNER_*2);
  bf16* vb_  = (bf16*)alloc((size_t)T_*INNER_*2);
  bf16* hb_  = (bf16*)alloc((size_t)T_*INNER_*2);
  float* igbuf = (float*)alloc((size_t)B_*NH_*S_*4);
  float* fgbuf = (float*)alloc((size_t)B_*NH_*S_*4);
  float* abuf  = (float*)alloc((size_t)B_*NH_*S_*4);
  float* Mbuf  = (float*)alloc((size_t)B_*NH_*S_*4);
  float* flbuf = (float*)alloc((size_t)B_*NH_*S_*4);
  bf16* ybuf = xn;   // xn dead after up-projection

  // 1. h_in = x @ w_in + b_in
  gemm_bias<float><<<dim3(E_/64, T_/64), 256, 0, stream>>>(x, w_in, b_in, h_in, T_, E_, IN_, IN_, E_);
  // 2. xn = LN(h_in)*ln1_w
  ln_rows<bf16><<<T_, 256, 0, stream>>>(h_in, nullptr, ln1_w, xn);
  // 3. up = xn @ w_up + b_up   (x_m | z)
  gemm_bias<bf16><<<dim3((2*INNER_)/64, T_/64), 256, 0, stream>>>(xn, w_up, b_up, up, T_, 2*INNER_, E_, E_, 2*INNER_);
  // 4. x_conv_act = silu(causal_conv(x_m))
  conv_silu_kernel<<<(T_*INNER_)/256, 256, 0, stream>>>(up, conv_w, conv_b, xca);
  // 5. q,k from x_conv_act; v from x_m (block-diagonal 4x4)
  headwise_kernel<<<(T_*INNER_)/256, 256, 0, stream>>>(xca, up, q_w, q_b, k_w, k_b, v_w, v_b, qb_, kb_, vb_);
  // 6. gate pre-activations
  gates_kernel<<<T_, 256, 0, stream>>>(qb_, kb_, vb_, ig_w, ig_b, fg_w, fg_b, igbuf, fgbuf);
  // 7. scans: a, M, floor
  scan8<<<B_*NH_, 256, 0, stream>>>(igbuf, fgbuf, abuf, Mbuf, flbuf);
  // 8. mLSTM attention -> hb_ in (b,s,n*DH+d) layout
  attn_kernel<<<dim3(S_/32, B_*NH_), 256, 0, stream>>>(qb_, kb_, vb_, abuf, Mbuf, flbuf, hb_);
  // 9. headnorm + skip + output gate, written in place over z
  headnorm_gate<<<T_*NH_, 256, 0, stream>>>(hb_, onw, skip, xca, up);
  // 10. y = h_gated @ w_down + b_down
  gemm_bias<bf16><<<dim3(E_/64, T_/64), 256, 0, stream>>>(up + INNER_, w_down, b_down, ybuf, T_, E_, INNER_, 2*INNER_, E_);
  // 11. out = LN(h_in + y)*post_w
  ln_rows<float><<<T_, 256, 0, stream>>>(h_in, ybuf, post_w, (float*)d_out);
}

// Round 4
// 1168.479 us; speedup vs baseline: 2.4566x; 2.4566x over previous
//
#include <hip/hip_runtime.h>
#include <hip/hip_bf16.h>

typedef __hip_bfloat16 bf16;
typedef float floatx4 __attribute__((ext_vector_type(4)));
typedef short bf16x8 __attribute__((ext_vector_type(8)));

#define B_      2
#define S_      2048
#define IN_     512
#define E_      1024
#define INNER_  2048
#define NH_     4
#define DH_     512
#define T_      (B_*S_)      // 4096 tokens
#define EPS_CELL 1e-6f
#define LN_EPS_  1e-5f
#define LS      72           // LDS row stride in shorts for 64-wide tiles (16B-aligned rows)

__device__ inline float b2f(bf16 x){ return __bfloat162float(x); }
__device__ inline bf16  f2b(float x){ return __float2bfloat16(x); }
__device__ inline float us2f(unsigned short u){ union{unsigned int i; float f;} v; v.i = ((unsigned int)u)<<16; return v.f; }
__device__ inline unsigned short f2bu(float x){ bf16 t = __float2bfloat16(x); unsigned short r; __builtin_memcpy(&r,&t,2); return r; }
__device__ inline void load4(const float* p, float* f){
  float4 v = *(const float4*)p; f[0]=v.x; f[1]=v.y; f[2]=v.z; f[3]=v.w;
}
__device__ inline void load4(const bf16* p, float* f){
  ushort4 v = *(const ushort4*)p; f[0]=us2f(v.x); f[1]=us2f(v.y); f[2]=us2f(v.z); f[3]=us2f(v.w);
}
__device__ inline void stv(bf16* p, float v){ *p = f2b(v); }
__device__ inline void stv(float* p, float v){ *p = v; }

// ---------------- generic GEMM: C[M,N] = A[M,K]@W[K,N] + bias (fp32 VALU) --------
template<typename AT>
__global__ __launch_bounds__(256) void gemm_bias(const AT* __restrict__ A,
    const float* __restrict__ W, const float* __restrict__ bias, bf16* __restrict__ C,
    int M, int N, int Kd, int lda, int ldc){
  __shared__ float As[16][68];   // transposed: As[k][m]
  __shared__ float Bs[16][68];
  int tid = threadIdx.x;
  int tx = tid & 15, ty = tid >> 4;
  int m0 = blockIdx.y*64, n0 = blockIdx.x*64;
  float acc[4][4];
  #pragma unroll
  for (int i=0;i<4;i++){
    #pragma unroll
    for (int j=0;j<4;j++) acc[i][j]=0.f;
  }
  for (int k0=0; k0<Kd; k0+=16){
    int idx = tid*4;
    { int ar = idx>>4, ac = idx&15;
      float f[4]; load4(A + (size_t)(m0+ar)*lda + k0 + ac, f);
      As[ac+0][ar]=f[0]; As[ac+1][ar]=f[1]; As[ac+2][ar]=f[2]; As[ac+3][ar]=f[3]; }
    { int br = idx>>6, bc = idx&63;
      float f[4]; load4(W + (size_t)(k0+br)*N + n0 + bc, f);
      Bs[br][bc+0]=f[0]; Bs[br][bc+1]=f[1]; Bs[br][bc+2]=f[2]; Bs[br][bc+3]=f[3]; }
    __syncthreads();
    #pragma unroll
    for (int kk=0; kk<16; kk++){
      float a4[4], b4[4];
      *(float4*)a4 = *(const float4*)&As[kk][ty*4];
      *(float4*)b4 = *(const float4*)&Bs[kk][tx*4];
      #pragma unroll
      for (int i=0;i<4;i++){
        #pragma unroll
        for (int j=0;j<4;j++) acc[i][j] += a4[i]*b4[j];
      }
    }
    __syncthreads();
  }
  float bb[4];
  #pragma unroll
  for (int j=0;j<4;j++) bb[j] = bias[n0+tx*4+j];
  #pragma unroll
  for (int i=0;i<4;i++){
    int row = m0+ty*4+i;
    ushort4 o4;
    o4.x=f2bu(acc[i][0]+bb[0]); o4.y=f2bu(acc[i][1]+bb[1]);
    o4.z=f2bu(acc[i][2]+bb[2]); o4.w=f2bu(acc[i][3]+bb[3]);
    *(ushort4*)(C + (size_t)row*ldc + n0 + tx*4) = o4;
  }
}

// ---------------- layernorm over rows of length E_ (opt. fused add) ----------------
template<typename OutT>
__global__ __launch_bounds__(256) void ln_rows(const bf16* __restrict__ X,
    const bf16* __restrict__ Xadd, const float* __restrict__ w, OutT* __restrict__ Y){
  int row = blockIdx.x, tid = threadIdx.x;
  size_t base = (size_t)row*E_;
  float vals[4], s=0.f, s2=0.f;
  #pragma unroll
  for (int e=0;e<4;e++){
    int c = e*256+tid;
    float v = b2f(X[base+c]);
    if (Xadd) v += b2f(Xadd[base+c]);
    vals[e]=v; s+=v; s2+=v*v;
  }
  __shared__ float sa[256], sb[256];
  sa[tid]=s; sb[tid]=s2; __syncthreads();
  for (int off=128; off>0; off>>=1){
    if (tid<off){ sa[tid]+=sa[tid+off]; sb[tid]+=sb[tid+off]; }
    __syncthreads();
  }
  float mean = sa[0]*(1.f/E_);
  float var  = sb[0]*(1.f/E_) - mean*mean;
  float rstd = rsqrtf(var + LN_EPS_);
  #pragma unroll
  for (int e=0;e<4;e++){
    int c = e*256+tid;
    stv(&Y[base+c], (vals[e]-mean)*rstd*w[c]);
  }
}

// ---------------- causal depthwise conv (K=4) + SiLU ----------------
__global__ __launch_bounds__(256) void conv_silu_kernel(const bf16* __restrict__ up,
    const float* __restrict__ cw, const float* __restrict__ cb, bf16* __restrict__ xca){
  size_t gid = (size_t)blockIdx.x*256 + threadIdx.x;   // over T_*INNER_
  int c = (int)(gid & (INNER_-1));
  size_t bs = gid >> 11;
  int s = (int)(bs & (S_-1));
  float acc = cb[c];
  #pragma unroll
  for (int t=0;t<4;t++){
    int sp = s-3+t;
    if (sp>=0) acc += b2f(up[(bs + (size_t)(t-3))*(size_t)(2*INNER_) + c]) * cw[c*4+t];
  }
  float sg = 1.f/(1.f+expf(-acc));
  xca[gid] = f2b(acc*sg);
}

// ---------------- block-diagonal (4x4) q/k/v projections ----------------
__global__ __launch_bounds__(256) void headwise_kernel(const bf16* __restrict__ xca,
    const bf16* __restrict__ up,
    const float* __restrict__ qw, const float* __restrict__ qb,
    const float* __restrict__ kw, const float* __restrict__ kb,
    const float* __restrict__ vw, const float* __restrict__ vb,
    bf16* __restrict__ q, bf16* __restrict__ k, bf16* __restrict__ v){
  size_t gid = (size_t)blockIdx.x*256 + threadIdx.x;
  int c = (int)(gid & (INNER_-1));
  size_t bs = gid >> 11;
  int hw = c>>2, o = c&3;
  float aq=qb[c], ak=kb[c], av=vb[c];
  size_t xb = bs*(size_t)INNER_ + (hw<<2);
  size_t mb = bs*(size_t)(2*INNER_) + (hw<<2);
  #pragma unroll
  for (int d=0; d<4; d++){
    float xc = b2f(xca[xb+d]);
    float xm = b2f(up[mb+d]);
    int wi = hw*16 + o*4 + d;   // w[h][o][d]
    aq += xc*qw[wi]; ak += xc*kw[wi]; av += xm*vw[wi];
  }
  q[gid]=f2b(aq); k[gid]=f2b(ak); v[gid]=f2b(av);
}

// ---------------- ig/fg gate dots: (B,S) x (6144 -> 4+4) ----------------
__global__ __launch_bounds__(256) void gates_kernel(const bf16* __restrict__ q,
    const bf16* __restrict__ k, const bf16* __restrict__ v,
    const float* __restrict__ igw, const float* __restrict__ igb,
    const float* __restrict__ fgw, const float* __restrict__ fgb,
    float* __restrict__ igo, float* __restrict__ fgo){
  int bs = blockIdx.x, tid = threadIdx.x;
  int b = bs >> 11, s = bs & (S_-1);
  float pi[4]={0,0,0,0}, pf[4]={0,0,0,0};
  size_t rb = (size_t)bs*INNER_;
  for (int c=tid; c<INNER_; c+=256){
    float qv=b2f(q[rb+c]), kv=b2f(k[rb+c]), vv=b2f(v[rb+c]);
    #pragma unroll
    for (int n2=0;n2<4;n2++){
      pi[n2] += qv*igw[c*4+n2] + kv*igw[(INNER_+c)*4+n2] + vv*igw[(2*INNER_+c)*4+n2];
      pf[n2] += qv*fgw[c*4+n2] + kv*fgw[(INNER_+c)*4+n2] + vv*fgw[(2*INNER_+c)*4+n2];
    }
  }
  __shared__ float red[8][256];
  #pragma unroll
  for (int n2=0;n2<4;n2++){ red[n2][tid]=pi[n2]; red[4+n2][tid]=pf[n2]; }
  __syncthreads();
  for (int off=128; off>0; off>>=1){
    if (tid<off){
      #pragma unroll
      for (int n2=0;n2<8;n2++) red[n2][tid]+=red[n2][tid+off];
    }
    __syncthreads();
  }
  if (tid<4){
    igo[((size_t)(b*NH_+tid))*S_ + s] = red[tid][0]   + igb[tid];
    fgo[((size_t)(b*NH_+tid))*S_ + s] = red[4+tid][0] + fgb[tid];
  }
}

// ---------------- per-head scan: F=cumsum(logsigmoid(fg)); a=ig-F; M=prefmax(a) ----
// also zeroes rowsum for the attention pass
__global__ __launch_bounds__(256) void scan8(const float* __restrict__ igp,
    const float* __restrict__ fgp, float* __restrict__ ap,
    float* __restrict__ Mp, float* __restrict__ flp, float* __restrict__ rowsum){
  int h = blockIdx.x, tid = threadIdx.x;
  const float* fg = fgp + (size_t)h*S_;
  const float* ig = igp + (size_t)h*S_;
  int base = tid*8;
  float loc[8], run = 0.f;
  #pragma unroll
  for (int e=0;e<8;e++){
    float x = fg[base+e];
    float ls = fminf(x,0.f) - log1pf(expf(-fabsf(x)));
    run += ls; loc[e] = run;
  }
  __shared__ float sd[256];
  sd[tid]=run; __syncthreads();
  if (tid==0){ float r=0.f; for(int t=0;t<256;t++){ float t0=sd[t]; sd[t]=r; r+=t0; } }
  __syncthreads();
  float off = sd[tid];
  float lm[8], rm = -3e38f;
  #pragma unroll
  for (int e=0;e<8;e++){
    float F = loc[e]+off; loc[e]=F;
    float aj = ig[base+e]-F;
    ap[(size_t)h*S_+base+e]=aj;
    rm = fmaxf(rm, aj); lm[e]=rm;
  }
  __syncthreads();
  sd[tid]=rm; __syncthreads();
  if (tid==0){ float r=-3e38f; for(int t=0;t<256;t++){ float t0=sd[t]; sd[t]=r; r=fmaxf(r,t0); } }
  __syncthreads();
  float offm = sd[tid];
  #pragma unroll
  for (int e=0;e<8;e++){
    float M = fmaxf(lm[e], offm);
    Mp[(size_t)h*S_+base+e]=M;
    flp[(size_t)h*S_+base+e]=expf(-loc[e]-M);
    rowsum[(size_t)h*S_+base+e]=0.f;
  }
}

// ---------------- v (b,s,n*DH+d) -> vT (h, d, s) ----------------
__global__ __launch_bounds__(256) void transpose_v(const bf16* __restrict__ v,
    bf16* __restrict__ vT){
  int sb = blockIdx.x, db = blockIdx.y, h = blockIdx.z;
  int b = h >> 2, n = h & 3;
  int s0 = sb*64, d0 = db*64;
  __shared__ short tl[64*LS];
  int tid = threadIdx.x;
  #pragma unroll
  for (int i=0;i<2;i++){
    int vv = tid + i*256; int r = vv>>3, c8 = vv&7;
    uint4 x = *(const uint4*)(v + (size_t)(b*S_+s0+r)*INNER_ + n*DH_ + d0 + c8*8);
    *(uint4*)&tl[r*LS + c8*8] = x;
  }
  __syncthreads();
  #pragma unroll
  for (int i=0;i<2;i++){
    int vv = tid + i*256; int r = vv>>3, c8 = vv&7;   // r = local d, c8 = s-chunk
    unsigned short tmp[8];
    #pragma unroll
    for (int e=0;e<8;e++) tmp[e] = (unsigned short)tl[(c8*8+e)*LS + r];
    uint4 o; __builtin_memcpy(&o, tmp, 16);
    *(uint4*)(vT + ((size_t)h*DH_ + d0 + r)*S_ + s0 + c8*8) = o;
  }
}

// ---------------- W = (Q K^T)*scale*exp(a_j - M_i), causal; + rowsums ----------------
__global__ __launch_bounds__(256) void qk_decay_kernel(const bf16* __restrict__ qg,
    const bf16* __restrict__ kg, const float* __restrict__ ap,
    const float* __restrict__ Mp, float* __restrict__ rowsum, bf16* __restrict__ W){
  int tj = blockIdx.x, ti = 15 - blockIdx.y, h = blockIdx.z;
  if (tj > ti) return;
  int b = h >> 2, n = h & 3;
  int i0 = ti*128, j0 = tj*128;
  __shared__ short Qs[128*LS];
  __shared__ short Ks[128*LS];
  __shared__ float a_s[128], m_s[128];
  int tid = threadIdx.x;
  if (tid < 128){
    a_s[tid] = ap[(size_t)h*S_ + j0 + tid];
    m_s[tid] = Mp[(size_t)h*S_ + i0 + tid];
  }
  int w = tid>>6, l = tid&63, lq = l>>4, lr = l&15;
  int wm = (w>>1)*64, wn = (w&1)*64;
  floatx4 acc[4][4];
  #pragma unroll
  for (int mi=0;mi<4;mi++){
    #pragma unroll
    for (int ni=0;ni<4;ni++) acc[mi][ni] = (floatx4){0.f,0.f,0.f,0.f};
  }
  for (int d0=0; d0<DH_; d0+=64){
    __syncthreads();
    #pragma unroll
    for (int kk=0;kk<4;kk++){
      int v = tid + kk*256; int r = v>>3, c8 = v&7;
      *(uint4*)&Qs[r*LS + c8*8] = *(const uint4*)(qg + (size_t)(b*S_+i0+r)*INNER_ + n*DH_ + d0 + c8*8);
      *(uint4*)&Ks[r*LS + c8*8] = *(const uint4*)(kg + (size_t)(b*S_+j0+r)*INNER_ + n*DH_ + d0 + c8*8);
    }
    __syncthreads();
    #pragma unroll
    for (int ks=0; ks<2; ks++){
      bf16x8 af[4], bfr[4];
      #pragma unroll
      for (int mi=0;mi<4;mi++) af[mi] = *(const bf16x8*)&Qs[(wm+mi*16+lr)*LS + ks*32 + lq*8];
      #pragma unroll
      for (int ni=0;ni<4;ni++) bfr[ni] = *(const bf16x8*)&Ks[(wn+ni*16+lr)*LS + ks*32 + lq*8];
      #pragma unroll
      for (int mi=0;mi<4;mi++){
        #pragma unroll
        for (int ni=0;ni<4;ni++)
          acc[mi][ni] = __builtin_amdgcn_mfma_f32_16x16x32_bf16(af[mi], bfr[ni], acc[mi][ni], 0,0,0);
      }
    }
  }
  const float scale = 0.04419417382415922f;   // 1/sqrt(512)
  float rpart[4][4];
  #pragma unroll
  for (int mi=0;mi<4;mi++){
    #pragma unroll
    for (int r=0;r<4;r++) rpart[mi][r]=0.f;
  }
  #pragma unroll
  for (int mi=0;mi<4;mi++){
    #pragma unroll
    for (int ni=0;ni<4;ni++){
      #pragma unroll
      for (int r=0;r<4;r++){
        int rowl = wm + mi*16 + lq*4 + r;
        int coll = wn + ni*16 + lr;
        int gi = i0 + rowl, gj = j0 + coll;
        float wv = 0.f;
        if (gj <= gi) wv = acc[mi][ni][r]*scale*__expf(a_s[coll]-m_s[rowl]);
        W[((size_t)h*S_ + gi)*S_ + gj] = f2b(wv);
        rpart[mi][r] += wv;
      }
    }
  }
  #pragma unroll
  for (int mi=0;mi<4;mi++){
    #pragma unroll
    for (int r=0;r<4;r++){
      float v = rpart[mi][r];
      v += __shfl_xor(v, 1, 16);
      v += __shfl_xor(v, 2, 16);
      v += __shfl_xor(v, 4, 16);
      v += __shfl_xor(v, 8, 16);
      if (lr == 0)
        atomicAdd(&rowsum[(size_t)h*S_ + i0 + wm + mi*16 + lq*4 + r], v);
    }
  }
}

// ---------------- inv_i = 1/(max(|rowsum_i|, fl_i)+eps) ----------------
__global__ __launch_bounds__(256) void norm_kernel(const float* __restrict__ rowsum,
    const float* __restrict__ fl, float* __restrict__ inv){
  int o = blockIdx.x*256 + threadIdx.x;
  inv[o] = 1.f/(fmaxf(fabsf(rowsum[o]), fl[o]) + EPS_CELL);
}

// ---------------- O = (W * inv_row) @ V  (causal k-range) ----------------
__global__ __launch_bounds__(256) void pv_kernel(const bf16* __restrict__ W,
    const bf16* __restrict__ vT, const float* __restrict__ inv, bf16* __restrict__ O){
  int tn = blockIdx.x, ti = 15 - blockIdx.y, h = blockIdx.z;
  int b = h >> 2, n = h & 3;
  int i0 = ti*128, d0 = tn*128;
  __shared__ short Ws[128*LS];
  __shared__ short Vs[128*LS];
  __shared__ float inv_s[128];
  int tid = threadIdx.x;
  if (tid < 128) inv_s[tid] = inv[(size_t)h*S_ + i0 + tid];
  int w = tid>>6, l = tid&63, lq = l>>4, lr = l&15;
  int wm = (w>>1)*64, wn = (w&1)*64;
  floatx4 acc[4][4];
  #pragma unroll
  for (int mi=0;mi<4;mi++){
    #pragma unroll
    for (int ni=0;ni<4;ni++) acc[mi][ni] = (floatx4){0.f,0.f,0.f,0.f};
  }
  int jmax = i0 + 128;
  for (int j0=0; j0<jmax; j0+=64){
    __syncthreads();
    #pragma unroll
    for (int kk=0;kk<4;kk++){
      int v = tid + kk*256; int r = v>>3, c8 = v&7;
      *(uint4*)&Ws[r*LS + c8*8] = *(const uint4*)(W + ((size_t)h*S_ + i0 + r)*S_ + j0 + c8*8);
      *(uint4*)&Vs[r*LS + c8*8] = *(const uint4*)(vT + ((size_t)h*DH_ + d0 + r)*S_ + j0 + c8*8);
    }
    __syncthreads();
    #pragma unroll
    for (int ks=0; ks<2; ks++){
      bf16x8 af[4], bfr[4];
      #pragma unroll
      for (int mi=0;mi<4;mi++) af[mi] = *(const bf16x8*)&Ws[(wm+mi*16+lr)*LS + ks*32 + lq*8];
      #pragma unroll
      for (int ni=0;ni<4;ni++) bfr[ni] = *(const bf16x8*)&Vs[(wn+ni*16+lr)*LS + ks*32 + lq*8];
      #pragma unroll
      for (int mi=0;mi<4;mi++){
        #pragma unroll
        for (int ni=0;ni<4;ni++)
          acc[mi][ni] = __builtin_amdgcn_mfma_f32_16x16x32_bf16(af[mi], bfr[ni], acc[mi][ni], 0,0,0);
      }
    }
  }
  #pragma unroll
  for (int mi=0;mi<4;mi++){
    #pragma unroll
    for (int ni=0;ni<4;ni++){
      #pragma unroll
      for (int r=0;r<4;r++){
        int rowl = wm + mi*16 + lq*4 + r;
        int dl = wn + ni*16 + lr;
        float o = acc[mi][ni][r] * inv_s[rowl];
        O[(size_t)(b*S_ + i0 + rowl)*INNER_ + n*DH_ + d0 + dl] = f2b(o);
      }
    }
  }
}

// ---------------- head groupnorm + skip + output gate (in-place into z) ----------
__global__ __launch_bounds__(256) void headnorm_gate(const bf16* __restrict__ h,
    const float* __restrict__ onw, const float* __restrict__ skip,
    const bf16* __restrict__ xca, bf16* __restrict__ up){
  int bid = blockIdx.x;
  int n = bid & 3; int bs = bid >> 2;
  int tid = threadIdx.x;
  size_t hbase = (size_t)bs*INNER_ + n*DH_;
  float v0 = b2f(h[hbase+tid]);
  float v1 = b2f(h[hbase+256+tid]);
  __shared__ float sa[256], sb[256];
  sa[tid]=v0+v1; sb[tid]=v0*v0+v1*v1;
  __syncthreads();
  for (int off=128; off>0; off>>=1){
    if (tid<off){ sa[tid]+=sa[tid+off]; sb[tid]+=sb[tid+off]; }
    __syncthreads();
  }
  float mean = sa[0]*(1.f/DH_);
  float var  = sb[0]*(1.f/DH_) - mean*mean;
  float rstd = rsqrtf(var + LN_EPS_);
  #pragma unroll
  for (int e=0;e<2;e++){
    int dl = e*256+tid; int c = n*DH_+dl;
    float hv = e ? v1 : v0;
    float hn = (hv-mean)*rstd*onw[c];
    float hs = hn + skip[c]*b2f(xca[(size_t)bs*INNER_+c]);
    size_t zoff = (size_t)bs*(2*INNER_) + INNER_ + c;
    float zv = b2f(up[zoff]);
    float sz = zv/(1.f+expf(-zv));
    up[zoff] = f2b(hs*sz);
  }
}

extern "C" void kernel_launch(void* const* d_in, const int* in_sizes, int n_in,
                              void* d_out, int out_size, void* d_ws, size_t ws_size,
                              hipStream_t stream) {
  const float* x      = (const float*)d_in[0];
  const float* w_in   = (const float*)d_in[1];
  const float* b_in   = (const float*)d_in[2];
  const float* ln1_w  = (const float*)d_in[3];
  const float* w_up   = (const float*)d_in[4];
  const float* b_up   = (const float*)d_in[5];
  const float* conv_w = (const float*)d_in[6];
  const float* conv_b = (const float*)d_in[7];
  const float* q_w    = (const float*)d_in[8];
  const float* q_b    = (const float*)d_in[9];
  const float* k_w    = (const float*)d_in[10];
  const float* k_b    = (const float*)d_in[11];
  const float* v_w    = (const float*)d_in[12];
  const float* v_b    = (const float*)d_in[13];
  const float* ig_w   = (const float*)d_in[14];
  const float* ig_b   = (const float*)d_in[15];
  const float* fg_w   = (const float*)d_in[16];
  const float* fg_b   = (const float*)d_in[17];
  const float* onw    = (const float*)d_in[18];
  const float* skip   = (const float*)d_in[19];
  const float* w_down = (const float*)d_in[20];
  const float* b_down = (const float*)d_in[21];
  const float* post_w = (const float*)d_in[22];

  char* p = (char*)d_ws;
  auto alloc = [&](size_t bytes)->void*{ void* r = p; p += (bytes + 255) & ~(size_t)255; return r; };
  bf16* h_in = (bf16*)alloc((size_t)T_*E_*2);        // 8 MB
  bf16* xn   = (bf16*)alloc((size_t)T_*E_*2);        // 8 MB (reused as y later)
  bf16* up   = (bf16*)alloc((size_t)T_*2*INNER_*2);  // 32 MB (x_m | z; z later holds h_gated)
  bf16* xca  = (bf16*)alloc((size_t)T_*INNER_*2);    // 16 MB
  bf16* qb_  = (bf16*)alloc((size_t)T_*INNER_*2);
  bf16* kb_  = (bf16*)alloc((size_t)T_*INNER_*2);
  bf16* vb_  = (bf16*)alloc((size_t)T_*INNER_*2);    // v; later reused as attention O
  bf16* hb_  = (bf16*)alloc((size_t)T_*INNER_*2);    // reused as vT (h,d,s)
  float* igbuf = (float*)alloc((size_t)B_*NH_*S_*4);
  float* fgbuf = (float*)alloc((size_t)B_*NH_*S_*4);
  float* abuf  = (float*)alloc((size_t)B_*NH_*S_*4);
  float* Mbuf  = (float*)alloc((size_t)B_*NH_*S_*4);
  float* flbuf = (float*)alloc((size_t)B_*NH_*S_*4);
  float* rsbuf = (float*)alloc((size_t)B_*NH_*S_*4);
  float* invbuf= (float*)alloc((size_t)B_*NH_*S_*4);
  bf16* Wbuf = (bf16*)alloc((size_t)B_*NH_*S_*S_*2); // 67 MB decay-weighted scores
  bf16* ybuf = xn;   // xn dead after up-projection
  bf16* vTb  = hb_;
  bf16* obuf = vb_;

  // 1. h_in = x @ w_in + b_in
  gemm_bias<float><<<dim3(E_/64, T_/64), 256, 0, stream>>>(x, w_in, b_in, h_in, T_, E_, IN_, IN_, E_);
  // 2. xn = LN(h_in)*ln1_w
  ln_rows<bf16><<<T_, 256, 0, stream>>>(h_in, nullptr, ln1_w, xn);
  // 3. up = xn @ w_up + b_up   (x_m | z)
  gemm_bias<bf16><<<dim3((2*INNER_)/64, T_/64), 256, 0, stream>>>(xn, w_up, b_up, up, T_, 2*INNER_, E_, E_, 2*INNER_);
  // 4. x_conv_act = silu(causal_conv(x_m))
  conv_silu_kernel<<<(T_*INNER_)/256, 256, 0, stream>>>(up, conv_w, conv_b, xca);
  // 5. q,k from x_conv_act; v from x_m (block-diagonal 4x4)
  headwise_kernel<<<(T_*INNER_)/256, 256, 0, stream>>>(xca, up, q_w, q_b, k_w, k_b, v_w, v_b, qb_, kb_, vb_);
  // 6. gate pre-activations
  gates_kernel<<<T_, 256, 0, stream>>>(qb_, kb_, vb_, ig_w, ig_b, fg_w, fg_b, igbuf, fgbuf);
  // 7. scans: a, M, floor; zero rowsums
  scan8<<<B_*NH_, 256, 0, stream>>>(igbuf, fgbuf, abuf, Mbuf, flbuf, rsbuf);
  // 8. v -> vT (head-major, d-major)
  transpose_v<<<dim3(S_/64, DH_/64, B_*NH_), 256, 0, stream>>>(vb_, vTb);
  // 9. W = QK^T * scale * decay (lower triangle), rowsums
  qk_decay_kernel<<<dim3(16, 16, B_*NH_), 256, 0, stream>>>(qb_, kb_, abuf, Mbuf, rsbuf, Wbuf);
  // 10. normalizers
  norm_kernel<<<(B_*NH_*S_)/256, 256, 0, stream>>>(rsbuf, flbuf, invbuf);
  // 11. O = (W*inv) @ V   -> obuf (b,s,n*DH+d)
  pv_kernel<<<dim3(4, 16, B_*NH_), 256, 0, stream>>>(Wbuf, vTb, invbuf, obuf);
  // 12. headnorm + skip + output gate, written in place over z
  headnorm_gate<<<T_*NH_, 256, 0, stream>>>(obuf, onw, skip, xca, up);
  // 13. y = h_gated @ w_down + b_down
  gemm_bias<bf16><<<dim3(E_/64, T_/64), 256, 0, stream>>>(up + INNER_, w_down, b_down, ybuf, T_, E_, INNER_, 2*INNER_, E_);
  // 14. out = LN(h_in + y)*post_w
  ln_rows<float><<<T_, 256, 0, stream>>>(h_in, ybuf, post_w, (float*)d_out);
}

// Round 5
// 586.706 us; speedup vs baseline: 4.8926x; 1.9916x over previous
//
#include <hip/hip_runtime.h>
#include <hip/hip_bf16.h>

typedef __hip_bfloat16 bf16;
typedef float floatx4 __attribute__((ext_vector_type(4)));
typedef short bf16x8 __attribute__((ext_vector_type(8)));

#define B_      2
#define S_      2048
#define IN_     512
#define E_      1024
#define INNER_  2048
#define NH_     4
#define DH_     512
#define T_      (B_*S_)      // 4096 tokens
#define EPS_CELL 1e-6f
#define LN_EPS_  1e-5f
#define LS      72           // LDS row stride in shorts (16B-aligned rows, conflict-broken)

__device__ inline float b2f(bf16 x){ return __bfloat162float(x); }
__device__ inline bf16  f2b(float x){ return __float2bfloat16(x); }
__device__ inline float us2f(unsigned short u){ union{unsigned int i; float f;} v; v.i = ((unsigned int)u)<<16; return v.f; }
__device__ inline unsigned short f2bu(float x){ bf16 t = __float2bfloat16(x); unsigned short r; __builtin_memcpy(&r,&t,2); return r; }
__device__ inline void stv(bf16* p, float v){ *p = f2b(v); }
__device__ inline void stv(float* p, float v){ *p = v; }

// ---------------- fp32 -> bf16 elementwise convert ----------------
__global__ __launch_bounds__(256) void convert_bf16(const float* __restrict__ X,
    bf16* __restrict__ Y, int n8){
  int i = blockIdx.x*256 + threadIdx.x;
  if (i >= n8) return;
  const float4* p = (const float4*)(X) + i*2;
  float4 a = p[0], b = p[1];
  ushort4 o0, o1;
  o0.x=f2bu(a.x); o0.y=f2bu(a.y); o0.z=f2bu(a.z); o0.w=f2bu(a.w);
  o1.x=f2bu(b.x); o1.y=f2bu(b.y); o1.z=f2bu(b.z); o1.w=f2bu(b.w);
  ushort4* q = (ushort4*)(Y) + i*2;
  q[0]=o0; q[1]=o1;
}

// ---------------- W[K,N] fp32 -> Wt[N,K] bf16 (64x64 LDS tiles) ----------------
__global__ __launch_bounds__(256) void transpose_conv_w(const float* __restrict__ W,
    bf16* __restrict__ Wt, int K, int N){
  int n0 = blockIdx.x*64, k0 = blockIdx.y*64;
  __shared__ float tl[64][65];
  int tid = threadIdx.x;
  #pragma unroll
  for (int i=0;i<4;i++){
    int idx = tid + i*256; int r = idx>>4, c4 = idx&15;
    float4 v = *(const float4*)(W + (size_t)(k0+r)*N + n0 + c4*4);
    tl[r][c4*4+0]=v.x; tl[r][c4*4+1]=v.y; tl[r][c4*4+2]=v.z; tl[r][c4*4+3]=v.w;
  }
  __syncthreads();
  #pragma unroll
  for (int i=0;i<4;i++){
    int idx = tid + i*256; int rn = idx>>4, c4 = idx&15;
    ushort4 o;
    o.x=f2bu(tl[c4*4+0][rn]); o.y=f2bu(tl[c4*4+1][rn]);
    o.z=f2bu(tl[c4*4+2][rn]); o.w=f2bu(tl[c4*4+3][rn]);
    *(ushort4*)(Wt + (size_t)(n0+rn)*K + k0 + c4*4) = o;
  }
}

// ---------------- MFMA GEMM: C[M,N] = A[M,K] @ Bt[N,K]^T + bias ----------------
// A bf16 (row stride lda), Bt bf16 (N x K dense), C bf16 (row stride ldc)
__global__ __launch_bounds__(256) void mfma_gemm(const bf16* __restrict__ A,
    const bf16* __restrict__ Bt, const float* __restrict__ bias, bf16* __restrict__ C,
    int Kd, int lda, int ldc){
  int n0 = blockIdx.x*128, m0 = blockIdx.y*128;
  __shared__ short As[128*LS];
  __shared__ short Bs[128*LS];
  int tid = threadIdx.x;
  int w = tid>>6, l = tid&63, lq = l>>4, lr = l&15;
  int wm = (w>>1)*64, wn = (w&1)*64;
  floatx4 acc[4][4];
  #pragma unroll
  for (int mi=0;mi<4;mi++){
    #pragma unroll
    for (int ni=0;ni<4;ni++) acc[mi][ni] = (floatx4){0.f,0.f,0.f,0.f};
  }
  for (int k0=0; k0<Kd; k0+=64){
    __syncthreads();
    #pragma unroll
    for (int kk=0;kk<4;kk++){
      int v = tid + kk*256; int r = v>>3, c8 = v&7;
      *(uint4*)&As[r*LS + c8*8] = *(const uint4*)(A + (size_t)(m0+r)*lda + k0 + c8*8);
      *(uint4*)&Bs[r*LS + c8*8] = *(const uint4*)(Bt + (size_t)(n0+r)*Kd + k0 + c8*8);
    }
    __syncthreads();
    #pragma unroll
    for (int ks=0; ks<2; ks++){
      bf16x8 af[4], bfr[4];
      #pragma unroll
      for (int mi=0;mi<4;mi++) af[mi] = *(const bf16x8*)&As[(wm+mi*16+lr)*LS + ks*32 + lq*8];
      #pragma unroll
      for (int ni=0;ni<4;ni++) bfr[ni] = *(const bf16x8*)&Bs[(wn+ni*16+lr)*LS + ks*32 + lq*8];
      #pragma unroll
      for (int mi=0;mi<4;mi++){
        #pragma unroll
        for (int ni=0;ni<4;ni++)
          acc[mi][ni] = __builtin_amdgcn_mfma_f32_16x16x32_bf16(af[mi], bfr[ni], acc[mi][ni], 0,0,0);
      }
    }
  }
  float bb[4];
  #pragma unroll
  for (int ni=0;ni<4;ni++) bb[ni] = bias[n0 + wn + ni*16 + lr];
  #pragma unroll
  for (int mi=0;mi<4;mi++){
    #pragma unroll
    for (int ni=0;ni<4;ni++){
      #pragma unroll
      for (int r=0;r<4;r++){
        int rowl = wm + mi*16 + lq*4 + r;
        int coll = wn + ni*16 + lr;
        C[(size_t)(m0+rowl)*ldc + n0 + coll] = f2b(acc[mi][ni][r] + bb[ni]);
      }
    }
  }
}

// ---------------- layernorm over rows of length E_ (opt. fused add) ----------------
template<typename OutT>
__global__ __launch_bounds__(256) void ln_rows(const bf16* __restrict__ X,
    const bf16* __restrict__ Xadd, const float* __restrict__ w, OutT* __restrict__ Y){
  int row = blockIdx.x, tid = threadIdx.x;
  size_t base = (size_t)row*E_;
  float vals[4], s=0.f, s2=0.f;
  #pragma unroll
  for (int e=0;e<4;e++){
    int c = e*256+tid;
    float v = b2f(X[base+c]);
    if (Xadd) v += b2f(Xadd[base+c]);
    vals[e]=v; s+=v; s2+=v*v;
  }
  __shared__ float sa[256], sb[256];
  sa[tid]=s; sb[tid]=s2; __syncthreads();
  for (int off=128; off>0; off>>=1){
    if (tid<off){ sa[tid]+=sa[tid+off]; sb[tid]+=sb[tid+off]; }
    __syncthreads();
  }
  float mean = sa[0]*(1.f/E_);
  float var  = sb[0]*(1.f/E_) - mean*mean;
  float rstd = rsqrtf(var + LN_EPS_);
  #pragma unroll
  for (int e=0;e<4;e++){
    int c = e*256+tid;
    stv(&Y[base+c], (vals[e]-mean)*rstd*w[c]);
  }
}

// ---------------- causal depthwise conv (K=4) + SiLU ----------------
__global__ __launch_bounds__(256) void conv_silu_kernel(const bf16* __restrict__ up,
    const float* __restrict__ cw, const float* __restrict__ cb, bf16* __restrict__ xca){
  size_t gid = (size_t)blockIdx.x*256 + threadIdx.x;   // over T_*INNER_
  int c = (int)(gid & (INNER_-1));
  size_t bs = gid >> 11;
  int s = (int)(bs & (S_-1));
  float acc = cb[c];
  #pragma unroll
  for (int t=0;t<4;t++){
    int sp = s-3+t;
    if (sp>=0) acc += b2f(up[(bs + (size_t)(t-3))*(size_t)(2*INNER_) + c]) * cw[c*4+t];
  }
  float sg = 1.f/(1.f+expf(-acc));
  xca[gid] = f2b(acc*sg);
}

// ---------------- block-diagonal (4x4) q/k/v projections ----------------
__global__ __launch_bounds__(256) void headwise_kernel(const bf16* __restrict__ xca,
    const bf16* __restrict__ up,
    const float* __restrict__ qw, const float* __restrict__ qb,
    const float* __restrict__ kw, const float* __restrict__ kb,
    const float* __restrict__ vw, const float* __restrict__ vb,
    bf16* __restrict__ q, bf16* __restrict__ k, bf16* __restrict__ v){
  size_t gid = (size_t)blockIdx.x*256 + threadIdx.x;
  int c = (int)(gid & (INNER_-1));
  size_t bs = gid >> 11;
  int hw = c>>2, o = c&3;
  float aq=qb[c], ak=kb[c], av=vb[c];
  size_t xb = bs*(size_t)INNER_ + (hw<<2);
  size_t mb = bs*(size_t)(2*INNER_) + (hw<<2);
  #pragma unroll
  for (int d=0; d<4; d++){
    float xc = b2f(xca[xb+d]);
    float xm = b2f(up[mb+d]);
    int wi = hw*16 + o*4 + d;   // w[h][o][d]
    aq += xc*qw[wi]; ak += xc*kw[wi]; av += xm*vw[wi];
  }
  q[gid]=f2b(aq); k[gid]=f2b(ak); v[gid]=f2b(av);
}

// ---------------- ig/fg gate dots: (B,S) x (6144 -> 4+4) ----------------
__global__ __launch_bounds__(256) void gates_kernel(const bf16* __restrict__ q,
    const bf16* __restrict__ k, const bf16* __restrict__ v,
    const float* __restrict__ igw, const float* __restrict__ igb,
    const float* __restrict__ fgw, const float* __restrict__ fgb,
    float* __restrict__ igo, float* __restrict__ fgo){
  int bs = blockIdx.x, tid = threadIdx.x;
  int b = bs >> 11, s = bs & (S_-1);
  float pi[4]={0,0,0,0}, pf[4]={0,0,0,0};
  size_t rb = (size_t)bs*INNER_;
  for (int c=tid; c<INNER_; c+=256){
    float qv=b2f(q[rb+c]), kv=b2f(k[rb+c]), vv=b2f(v[rb+c]);
    #pragma unroll
    for (int n2=0;n2<4;n2++){
      pi[n2] += qv*igw[c*4+n2] + kv*igw[(INNER_+c)*4+n2] + vv*igw[(2*INNER_+c)*4+n2];
      pf[n2] += qv*fgw[c*4+n2] + kv*fgw[(INNER_+c)*4+n2] + vv*fgw[(2*INNER_+c)*4+n2];
    }
  }
  __shared__ float red[8][256];
  #pragma unroll
  for (int n2=0;n2<4;n2++){ red[n2][tid]=pi[n2]; red[4+n2][tid]=pf[n2]; }
  __syncthreads();
  for (int off=128; off>0; off>>=1){
    if (tid<off){
      #pragma unroll
      for (int n2=0;n2<8;n2++) red[n2][tid]+=red[n2][tid+off];
    }
    __syncthreads();
  }
  if (tid<4){
    igo[((size_t)(b*NH_+tid))*S_ + s] = red[tid][0]   + igb[tid];
    fgo[((size_t)(b*NH_+tid))*S_ + s] = red[4+tid][0] + fgb[tid];
  }
}

// ---------------- per-head scan: F=cumsum(logsigmoid(fg)); a=ig-F; M=prefmax(a) ----
__global__ __launch_bounds__(256) void scan8(const float* __restrict__ igp,
    const float* __restrict__ fgp, float* __restrict__ ap,
    float* __restrict__ Mp, float* __restrict__ flp, float* __restrict__ rowsum){
  int h = blockIdx.x, tid = threadIdx.x;
  const float* fg = fgp + (size_t)h*S_;
  const float* ig = igp + (size_t)h*S_;
  int base = tid*8;
  float loc[8], run = 0.f;
  #pragma unroll
  for (int e=0;e<8;e++){
    float x = fg[base+e];
    float ls = fminf(x,0.f) - log1pf(expf(-fabsf(x)));
    run += ls; loc[e] = run;
  }
  __shared__ float sd[256];
  sd[tid]=run; __syncthreads();
  if (tid==0){ float r=0.f; for(int t=0;t<256;t++){ float t0=sd[t]; sd[t]=r; r+=t0; } }
  __syncthreads();
  float off = sd[tid];
  float lm[8], rm = -3e38f;
  #pragma unroll
  for (int e=0;e<8;e++){
    float F = loc[e]+off; loc[e]=F;
    float aj = ig[base+e]-F;
    ap[(size_t)h*S_+base+e]=aj;
    rm = fmaxf(rm, aj); lm[e]=rm;
  }
  __syncthreads();
  sd[tid]=rm; __syncthreads();
  if (tid==0){ float r=-3e38f; for(int t=0;t<256;t++){ float t0=sd[t]; sd[t]=r; r=fmaxf(r,t0); } }
  __syncthreads();
  float offm = sd[tid];
  #pragma unroll
  for (int e=0;e<8;e++){
    float M = fmaxf(lm[e], offm);
    Mp[(size_t)h*S_+base+e]=M;
    flp[(size_t)h*S_+base+e]=expf(-loc[e]-M);
    rowsum[(size_t)h*S_+base+e]=0.f;
  }
}

// ---------------- v (b,s,n*DH+d) -> vT (h, d, s) ----------------
__global__ __launch_bounds__(256) void transpose_v(const bf16* __restrict__ v,
    bf16* __restrict__ vT){
  int sb = blockIdx.x, db = blockIdx.y, h = blockIdx.z;
  int b = h >> 2, n = h & 3;
  int s0 = sb*64, d0 = db*64;
  __shared__ short tl[64*LS];
  int tid = threadIdx.x;
  #pragma unroll
  for (int i=0;i<2;i++){
    int vv = tid + i*256; int r = vv>>3, c8 = vv&7;
    uint4 x = *(const uint4*)(v + (size_t)(b*S_+s0+r)*INNER_ + n*DH_ + d0 + c8*8);
    *(uint4*)&tl[r*LS + c8*8] = x;
  }
  __syncthreads();
  #pragma unroll
  for (int i=0;i<2;i++){
    int vv = tid + i*256; int r = vv>>3, c8 = vv&7;   // r = local d, c8 = s-chunk
    unsigned short tmp[8];
    #pragma unroll
    for (int e=0;e<8;e++) tmp[e] = (unsigned short)tl[(c8*8+e)*LS + r];
    uint4 o; __builtin_memcpy(&o, tmp, 16);
    *(uint4*)(vT + ((size_t)h*DH_ + d0 + r)*S_ + s0 + c8*8) = o;
  }
}

// ---------------- W = (Q K^T)*scale*exp(a_j - M_i), causal; + rowsums ----------------
__global__ __launch_bounds__(256) void qk_decay_kernel(const bf16* __restrict__ qg,
    const bf16* __restrict__ kg, const float* __restrict__ ap,
    const float* __restrict__ Mp, float* __restrict__ rowsum, bf16* __restrict__ W){
  int tj = blockIdx.x, ti = 15 - blockIdx.y, h = blockIdx.z;
  if (tj > ti) return;
  int b = h >> 2, n = h & 3;
  int i0 = ti*128, j0 = tj*128;
  __shared__ short Qs[128*LS];
  __shared__ short Ks[128*LS];
  __shared__ float a_s[128], m_s[128];
  int tid = threadIdx.x;
  if (tid < 128){
    a_s[tid] = ap[(size_t)h*S_ + j0 + tid];
    m_s[tid] = Mp[(size_t)h*S_ + i0 + tid];
  }
  int w = tid>>6, l = tid&63, lq = l>>4, lr = l&15;
  int wm = (w>>1)*64, wn = (w&1)*64;
  floatx4 acc[4][4];
  #pragma unroll
  for (int mi=0;mi<4;mi++){
    #pragma unroll
    for (int ni=0;ni<4;ni++) acc[mi][ni] = (floatx4){0.f,0.f,0.f,0.f};
  }
  for (int d0=0; d0<DH_; d0+=64){
    __syncthreads();
    #pragma unroll
    for (int kk=0;kk<4;kk++){
      int v = tid + kk*256; int r = v>>3, c8 = v&7;
      *(uint4*)&Qs[r*LS + c8*8] = *(const uint4*)(qg + (size_t)(b*S_+i0+r)*INNER_ + n*DH_ + d0 + c8*8);
      *(uint4*)&Ks[r*LS + c8*8] = *(const uint4*)(kg + (size_t)(b*S_+j0+r)*INNER_ + n*DH_ + d0 + c8*8);
    }
    __syncthreads();
    #pragma unroll
    for (int ks=0; ks<2; ks++){
      bf16x8 af[4], bfr[4];
      #pragma unroll
      for (int mi=0;mi<4;mi++) af[mi] = *(const bf16x8*)&Qs[(wm+mi*16+lr)*LS + ks*32 + lq*8];
      #pragma unroll
      for (int ni=0;ni<4;ni++) bfr[ni] = *(const bf16x8*)&Ks[(wn+ni*16+lr)*LS + ks*32 + lq*8];
      #pragma unroll
      for (int mi=0;mi<4;mi++){
        #pragma unroll
        for (int ni=0;ni<4;ni++)
          acc[mi][ni] = __builtin_amdgcn_mfma_f32_16x16x32_bf16(af[mi], bfr[ni], acc[mi][ni], 0,0,0);
      }
    }
  }
  const float scale = 0.04419417382415922f;   // 1/sqrt(512)
  float rpart[4][4];
  #pragma unroll
  for (int mi=0;mi<4;mi++){
    #pragma unroll
    for (int r=0;r<4;r++) rpart[mi][r]=0.f;
  }
  #pragma unroll
  for (int mi=0;mi<4;mi++){
    #pragma unroll
    for (int ni=0;ni<4;ni++){
      #pragma unroll
      for (int r=0;r<4;r++){
        int rowl = wm + mi*16 + lq*4 + r;
        int coll = wn + ni*16 + lr;
        int gi = i0 + rowl, gj = j0 + coll;
        float wv = 0.f;
        if (gj <= gi) wv = acc[mi][ni][r]*scale*__expf(a_s[coll]-m_s[rowl]);
        W[((size_t)h*S_ + gi)*S_ + gj] = f2b(wv);
        rpart[mi][r] += wv;
      }
    }
  }
  #pragma unroll
  for (int mi=0;mi<4;mi++){
    #pragma unroll
    for (int r=0;r<4;r++){
      float v = rpart[mi][r];
      v += __shfl_xor(v, 1, 16);
      v += __shfl_xor(v, 2, 16);
      v += __shfl_xor(v, 4, 16);
      v += __shfl_xor(v, 8, 16);
      if (lr == 0)
        atomicAdd(&rowsum[(size_t)h*S_ + i0 + wm + mi*16 + lq*4 + r], v);
    }
  }
}

// ---------------- inv_i = 1/(max(|rowsum_i|, fl_i)+eps) ----------------
__global__ __launch_bounds__(256) void norm_kernel(const float* __restrict__ rowsum,
    const float* __restrict__ fl, float* __restrict__ inv){
  int o = blockIdx.x*256 + threadIdx.x;
  inv[o] = 1.f/(fmaxf(fabsf(rowsum[o]), fl[o]) + EPS_CELL);
}

// ---------------- O = (W * inv_row) @ V  (causal k-range) ----------------
__global__ __launch_bounds__(256) void pv_kernel(const bf16* __restrict__ W,
    const bf16* __restrict__ vT, const float* __restrict__ inv, bf16* __restrict__ O){
  int tn = blockIdx.x, ti = 15 - blockIdx.y, h = blockIdx.z;
  int b = h >> 2, n = h & 3;
  int i0 = ti*128, d0 = tn*128;
  __shared__ short Ws[128*LS];
  __shared__ short Vs[128*LS];
  __shared__ float inv_s[128];
  int tid = threadIdx.x;
  if (tid < 128) inv_s[tid] = inv[(size_t)h*S_ + i0 + tid];
  int w = tid>>6, l = tid&63, lq = l>>4, lr = l&15;
  int wm = (w>>1)*64, wn = (w&1)*64;
  floatx4 acc[4][4];
  #pragma unroll
  for (int mi=0;mi<4;mi++){
    #pragma unroll
    for (int ni=0;ni<4;ni++) acc[mi][ni] = (floatx4){0.f,0.f,0.f,0.f};
  }
  int jmax = i0 + 128;
  for (int j0=0; j0<jmax; j0+=64){
    __syncthreads();
    #pragma unroll
    for (int kk=0;kk<4;kk++){
      int v = tid + kk*256; int r = v>>3, c8 = v&7;
      *(uint4*)&Ws[r*LS + c8*8] = *(const uint4*)(W + ((size_t)h*S_ + i0 + r)*S_ + j0 + c8*8);
      *(uint4*)&Vs[r*LS + c8*8] = *(const uint4*)(vT + ((size_t)h*DH_ + d0 + r)*S_ + j0 + c8*8);
    }
    __syncthreads();
    #pragma unroll
    for (int ks=0; ks<2; ks++){
      bf16x8 af[4], bfr[4];
      #pragma unroll
      for (int mi=0;mi<4;mi++) af[mi] = *(const bf16x8*)&Ws[(wm+mi*16+lr)*LS + ks*32 + lq*8];
      #pragma unroll
      for (int ni=0;ni<4;ni++) bfr[ni] = *(const bf16x8*)&Vs[(wn+ni*16+lr)*LS + ks*32 + lq*8];
      #pragma unroll
      for (int mi=0;mi<4;mi++){
        #pragma unroll
        for (int ni=0;ni<4;ni++)
          acc[mi][ni] = __builtin_amdgcn_mfma_f32_16x16x32_bf16(af[mi], bfr[ni], acc[mi][ni], 0,0,0);
      }
    }
  }
  #pragma unroll
  for (int mi=0;mi<4;mi++){
    #pragma unroll
    for (int ni=0;ni<4;ni++){
      #pragma unroll
      for (int r=0;r<4;r++){
        int rowl = wm + mi*16 + lq*4 + r;
        int dl = wn + ni*16 + lr;
        float o = acc[mi][ni][r] * inv_s[rowl];
        O[(size_t)(b*S_ + i0 + rowl)*INNER_ + n*DH_ + d0 + dl] = f2b(o);
      }
    }
  }
}

// ---------------- head groupnorm + skip + output gate (in-place into z) ----------
__global__ __launch_bounds__(256) void headnorm_gate(const bf16* __restrict__ h,
    const float* __restrict__ onw, const float* __restrict__ skip,
    const bf16* __restrict__ xca, bf16* __restrict__ up){
  int bid = blockIdx.x;
  int n = bid & 3; int bs = bid >> 2;
  int tid = threadIdx.x;
  size_t hbase = (size_t)bs*INNER_ + n*DH_;
  float v0 = b2f(h[hbase+tid]);
  float v1 = b2f(h[hbase+256+tid]);
  __shared__ float sa[256], sb[256];
  sa[tid]=v0+v1; sb[tid]=v0*v0+v1*v1;
  __syncthreads();
  for (int off=128; off>0; off>>=1){
    if (tid<off){ sa[tid]+=sa[tid+off]; sb[tid]+=sb[tid+off]; }
    __syncthreads();
  }
  float mean = sa[0]*(1.f/DH_);
  float var  = sb[0]*(1.f/DH_) - mean*mean;
  float rstd = rsqrtf(var + LN_EPS_);
  #pragma unroll
  for (int e=0;e<2;e++){
    int dl = e*256+tid; int c = n*DH_+dl;
    float hv = e ? v1 : v0;
    float hn = (hv-mean)*rstd*onw[c];
    float hs = hn + skip[c]*b2f(xca[(size_t)bs*INNER_+c]);
    size_t zoff = (size_t)bs*(2*INNER_) + INNER_ + c;
    float zv = b2f(up[zoff]);
    float sz = zv/(1.f+expf(-zv));
    up[zoff] = f2b(hs*sz);
  }
}

extern "C" void kernel_launch(void* const* d_in, const int* in_sizes, int n_in,
                              void* d_out, int out_size, void* d_ws, size_t ws_size,
                              hipStream_t stream) {
  const float* x      = (const float*)d_in[0];
  const float* w_in   = (const float*)d_in[1];
  const float* b_in   = (const float*)d_in[2];
  const float* ln1_w  = (const float*)d_in[3];
  const float* w_up   = (const float*)d_in[4];
  const float* b_up   = (const float*)d_in[5];
  const float* conv_w = (const float*)d_in[6];
  const float* conv_b = (const float*)d_in[7];
  const float* q_w    = (const float*)d_in[8];
  const float* q_b    = (const float*)d_in[9];
  const float* k_w    = (const float*)d_in[10];
  const float* k_b    = (const float*)d_in[11];
  const float* v_w    = (const float*)d_in[12];
  const float* v_b    = (const float*)d_in[13];
  const float* ig_w   = (const float*)d_in[14];
  const float* ig_b   = (const float*)d_in[15];
  const float* fg_w   = (const float*)d_in[16];
  const float* fg_b   = (const float*)d_in[17];
  const float* onw    = (const float*)d_in[18];
  const float* skip   = (const float*)d_in[19];
  const float* w_down = (const float*)d_in[20];
  const float* b_down = (const float*)d_in[21];
  const float* post_w = (const float*)d_in[22];

  char* p = (char*)d_ws;
  auto alloc = [&](size_t bytes)->void*{ void* r = p; p += (bytes + 255) & ~(size_t)255; return r; };
  bf16* h_in = (bf16*)alloc((size_t)T_*E_*2);        // 8 MB
  bf16* xn   = (bf16*)alloc((size_t)T_*E_*2);        // 8 MB (reused as y later)
  bf16* up   = (bf16*)alloc((size_t)T_*2*INNER_*2);  // 32 MB (x_m | z; z later holds h_gated)
  bf16* xca  = (bf16*)alloc((size_t)T_*INNER_*2);    // 16 MB
  bf16* qb_  = (bf16*)alloc((size_t)T_*INNER_*2);
  bf16* kb_  = (bf16*)alloc((size_t)T_*INNER_*2);
  bf16* vb_  = (bf16*)alloc((size_t)T_*INNER_*2);    // v; later reused as attention O
  bf16* hb_  = (bf16*)alloc((size_t)T_*INNER_*2);    // reused as vT (h,d,s)
  float* igbuf = (float*)alloc((size_t)B_*NH_*S_*4);
  float* fgbuf = (float*)alloc((size_t)B_*NH_*S_*4);
  float* abuf  = (float*)alloc((size_t)B_*NH_*S_*4);
  float* Mbuf  = (float*)alloc((size_t)B_*NH_*S_*4);
  float* flbuf = (float*)alloc((size_t)B_*NH_*S_*4);
  float* rsbuf = (float*)alloc((size_t)B_*NH_*S_*4);
  float* invbuf= (float*)alloc((size_t)B_*NH_*S_*4);
  bf16* Wbuf = (bf16*)alloc((size_t)B_*NH_*S_*S_*2); // 67 MB decay-weighted scores
  bf16* ybuf = xn;   // xn dead after up-projection
  bf16* vTb  = hb_;
  bf16* obuf = vb_;
  // converted-weight scratch overlapping Wbuf (dead until qk_decay / after pv)
  bf16* xbf    = Wbuf;                               // 4 MB, dead after GEMM1
  bf16* w_in_t = Wbuf + (size_t)T_*IN_;              // 1 MB, dead after GEMM1
  bf16* w_up_t = w_in_t + (size_t)E_*IN_;            // 8 MB, dead after GEMM2
  bf16* w_down_t = Wbuf;                             // written AFTER pv_kernel frees Wbuf

  // 0a. convert x -> bf16 ; transpose+convert w_in, w_up
  convert_bf16<<<(T_*IN_/8+255)/256, 256, 0, stream>>>(x, xbf, T_*IN_/8);
  transpose_conv_w<<<dim3(E_/64, IN_/64), 256, 0, stream>>>(w_in, w_in_t, IN_, E_);
  transpose_conv_w<<<dim3((2*INNER_)/64, E_/64), 256, 0, stream>>>(w_up, w_up_t, E_, 2*INNER_);
  // 1. h_in = x @ w_in + b_in
  mfma_gemm<<<dim3(E_/128, T_/128), 256, 0, stream>>>(xbf, w_in_t, b_in, h_in, IN_, IN_, E_);
  // 2. xn = LN(h_in)*ln1_w
  ln_rows<bf16><<<T_, 256, 0, stream>>>(h_in, nullptr, ln1_w, xn);
  // 3. up = xn @ w_up + b_up   (x_m | z)
  mfma_gemm<<<dim3((2*INNER_)/128, T_/128), 256, 0, stream>>>(xn, w_up_t, b_up, up, E_, E_, 2*INNER_);
  // 4. x_conv_act = silu(causal_conv(x_m))
  conv_silu_kernel<<<(T_*INNER_)/256, 256, 0, stream>>>(up, conv_w, conv_b, xca);
  // 5. q,k from x_conv_act; v from x_m (block-diagonal 4x4)
  headwise_kernel<<<(T_*INNER_)/256, 256, 0, stream>>>(xca, up, q_w, q_b, k_w, k_b, v_w, v_b, qb_, kb_, vb_);
  // 6. gate pre-activations
  gates_kernel<<<T_, 256, 0, stream>>>(qb_, kb_, vb_, ig_w, ig_b, fg_w, fg_b, igbuf, fgbuf);
  // 7. scans: a, M, floor; zero rowsums
  scan8<<<B_*NH_, 256, 0, stream>>>(igbuf, fgbuf, abuf, Mbuf, flbuf, rsbuf);
  // 8. v -> vT (head-major, d-major)
  transpose_v<<<dim3(S_/64, DH_/64, B_*NH_), 256, 0, stream>>>(vb_, vTb);
  // 9. W = QK^T * scale * decay (lower triangle), rowsums
  qk_decay_kernel<<<dim3(16, 16, B_*NH_), 256, 0, stream>>>(qb_, kb_, abuf, Mbuf, rsbuf, Wbuf);
  // 10. normalizers
  norm_kernel<<<(B_*NH_*S_)/256, 256, 0, stream>>>(rsbuf, flbuf, invbuf);
  // 11. O = (W*inv) @ V   -> obuf (b,s,n*DH+d)
  pv_kernel<<<dim3(4, 16, B_*NH_), 256, 0, stream>>>(Wbuf, vTb, invbuf, obuf);
  // 12. headnorm + skip + output gate, written in place over z
  headnorm_gate<<<T_*NH_, 256, 0, stream>>>(obuf, onw, skip, xca, up);
  // 12b. transpose+convert w_down (Wbuf now dead)
  transpose_conv_w<<<dim3(E_/64, INNER_/64), 256, 0, stream>>>(w_down, w_down_t, INNER_, E_);
  // 13. y = h_gated @ w_down + b_down
  mfma_gemm<<<dim3(E_/128, T_/128), 256, 0, stream>>>(up + INNER_, w_down_t, b_down, ybuf, INNER_, 2*INNER_, E_);
  // 14. out = LN(h_in + y)*post_w
  ln_rows<float><<<T_, 256, 0, stream>>>(h_in, ybuf, post_w, (float*)d_out);
}

// Round 7
// 509.286 us; speedup vs baseline: 5.6364x; 1.1520x over previous
//
#include <hip/hip_runtime.h>
#include <hip/hip_bf16.h>

typedef __hip_bfloat16 bf16;
typedef float floatx4 __attribute__((ext_vector_type(4)));
typedef short bf16x8 __attribute__((ext_vector_type(8)));

#define B_      2
#define S_      2048
#define IN_     512
#define E_      1024
#define INNER_  2048
#define NH_     4
#define DH_     512
#define T_      (B_*S_)      // 4096 tokens
#define EPS_CELL 1e-6f
#define LN_EPS_  1e-5f
#define LS      72           // LDS row stride in shorts (16B-aligned rows, conflict-broken)

__device__ inline float b2f(bf16 x){ return __bfloat162float(x); }
__device__ inline bf16  f2b(float x){ return __float2bfloat16(x); }
__device__ inline float us2f(unsigned short u){ union{unsigned int i; float f;} v; v.i = ((unsigned int)u)<<16; return v.f; }
__device__ inline float u2f(unsigned int u){ union{unsigned int i; float f;} v; v.i = u; return v.f; }
__device__ inline unsigned short f2bu(float x){ bf16 t = __float2bfloat16(x); unsigned short r; __builtin_memcpy(&r,&t,2); return r; }
__device__ inline void unpack8(uint4 u, float* f){
  f[0]=u2f(u.x<<16); f[1]=u2f(u.x&0xffff0000u);
  f[2]=u2f(u.y<<16); f[3]=u2f(u.y&0xffff0000u);
  f[4]=u2f(u.z<<16); f[5]=u2f(u.z&0xffff0000u);
  f[6]=u2f(u.w<<16); f[7]=u2f(u.w&0xffff0000u);
}
__device__ inline void stv(bf16* p, float v){ *p = f2b(v); }
__device__ inline void stv(float* p, float v){ *p = v; }

// ---------------- fp32 -> bf16 elementwise convert ----------------
__global__ __launch_bounds__(256) void convert_bf16(const float* __restrict__ X,
    bf16* __restrict__ Y, int n8){
  int i = blockIdx.x*256 + threadIdx.x;
  if (i >= n8) return;
  const float4* p = (const float4*)(X) + i*2;
  float4 a = p[0], b = p[1];
  ushort4 o0, o1;
  o0.x=f2bu(a.x); o0.y=f2bu(a.y); o0.z=f2bu(a.z); o0.w=f2bu(a.w);
  o1.x=f2bu(b.x); o1.y=f2bu(b.y); o1.z=f2bu(b.z); o1.w=f2bu(b.w);
  ushort4* q = (ushort4*)(Y) + i*2;
  q[0]=o0; q[1]=o1;
}

// ---------------- W[K,N] fp32 -> Wt[N,K] bf16 (64x64 LDS tiles) ----------------
__global__ __launch_bounds__(256) void transpose_conv_w(const float* __restrict__ W,
    bf16* __restrict__ Wt, int K, int N){
  int n0 = blockIdx.x*64, k0 = blockIdx.y*64;
  __shared__ float tl[64][65];
  int tid = threadIdx.x;
  #pragma unroll
  for (int i=0;i<4;i++){
    int idx = tid + i*256; int r = idx>>4, c4 = idx&15;
    float4 v = *(const float4*)(W + (size_t)(k0+r)*N + n0 + c4*4);
    tl[r][c4*4+0]=v.x; tl[r][c4*4+1]=v.y; tl[r][c4*4+2]=v.z; tl[r][c4*4+3]=v.w;
  }
  __syncthreads();
  #pragma unroll
  for (int i=0;i<4;i++){
    int idx = tid + i*256; int rn = idx>>4, c4 = idx&15;
    ushort4 o;
    o.x=f2bu(tl[c4*4+0][rn]); o.y=f2bu(tl[c4*4+1][rn]);
    o.z=f2bu(tl[c4*4+2][rn]); o.w=f2bu(tl[c4*4+3][rn]);
    *(ushort4*)(Wt + (size_t)(n0+rn)*K + k0 + c4*4) = o;
  }
}

// ---------------- MFMA GEMM: C[M,N] = A[M,K] @ Bt[N,K]^T + bias ----------------
__global__ __launch_bounds__(256) void mfma_gemm(const bf16* __restrict__ A,
    const bf16* __restrict__ Bt, const float* __restrict__ bias, bf16* __restrict__ C,
    int Kd, int lda, int ldc){
  int n0 = blockIdx.x*128, m0 = blockIdx.y*128;
  __shared__ short As[128*LS];
  __shared__ short Bs[128*LS];
  int tid = threadIdx.x;
  int w = tid>>6, l = tid&63, lq = l>>4, lr = l&15;
  int wm = (w>>1)*64, wn = (w&1)*64;
  floatx4 acc[4][4];
  #pragma unroll
  for (int mi=0;mi<4;mi++){
    #pragma unroll
    for (int ni=0;ni<4;ni++) acc[mi][ni] = (floatx4){0.f,0.f,0.f,0.f};
  }
  for (int k0=0; k0<Kd; k0+=64){
    __syncthreads();
    #pragma unroll
    for (int kk=0;kk<4;kk++){
      int v = tid + kk*256; int r = v>>3, c8 = v&7;
      *(uint4*)&As[r*LS + c8*8] = *(const uint4*)(A + (size_t)(m0+r)*lda + k0 + c8*8);
      *(uint4*)&Bs[r*LS + c8*8] = *(const uint4*)(Bt + (size_t)(n0+r)*Kd + k0 + c8*8);
    }
    __syncthreads();
    #pragma unroll
    for (int ks=0; ks<2; ks++){
      bf16x8 af[4], bfr[4];
      #pragma unroll
      for (int mi=0;mi<4;mi++) af[mi] = *(const bf16x8*)&As[(wm+mi*16+lr)*LS + ks*32 + lq*8];
      #pragma unroll
      for (int ni=0;ni<4;ni++) bfr[ni] = *(const bf16x8*)&Bs[(wn+ni*16+lr)*LS + ks*32 + lq*8];
      #pragma unroll
      for (int mi=0;mi<4;mi++){
        #pragma unroll
        for (int ni=0;ni<4;ni++)
          acc[mi][ni] = __builtin_amdgcn_mfma_f32_16x16x32_bf16(af[mi], bfr[ni], acc[mi][ni], 0,0,0);
      }
    }
  }
  float bb[4];
  #pragma unroll
  for (int ni=0;ni<4;ni++) bb[ni] = bias[n0 + wn + ni*16 + lr];
  #pragma unroll
  for (int mi=0;mi<4;mi++){
    #pragma unroll
    for (int ni=0;ni<4;ni++){
      #pragma unroll
      for (int r=0;r<4;r++){
        int rowl = wm + mi*16 + lq*4 + r;
        int coll = wn + ni*16 + lr;
        C[(size_t)(m0+rowl)*ldc + n0 + coll] = f2b(acc[mi][ni][r] + bb[ni]);
      }
    }
  }
}

// ---------------- layernorm over rows of length E_ (opt. fused add) ----------------
template<typename OutT>
__global__ __launch_bounds__(256) void ln_rows(const bf16* __restrict__ X,
    const bf16* __restrict__ Xadd, const float* __restrict__ w, OutT* __restrict__ Y){
  int row = blockIdx.x, tid = threadIdx.x;
  size_t base = (size_t)row*E_;
  float vals[4], s=0.f, s2=0.f;
  #pragma unroll
  for (int e=0;e<4;e++){
    int c = e*256+tid;
    float v = b2f(X[base+c]);
    if (Xadd) v += b2f(Xadd[base+c]);
    vals[e]=v; s+=v; s2+=v*v;
  }
  __shared__ float sa[256], sb[256];
  sa[tid]=s; sb[tid]=s2; __syncthreads();
  for (int off=128; off>0; off>>=1){
    if (tid<off){ sa[tid]+=sa[tid+off]; sb[tid]+=sb[tid+off]; }
    __syncthreads();
  }
  float mean = sa[0]*(1.f/E_);
  float var  = sb[0]*(1.f/E_) - mean*mean;
  float rstd = rsqrtf(var + LN_EPS_);
  #pragma unroll
  for (int e=0;e<4;e++){
    int c = e*256+tid;
    stv(&Y[base+c], (vals[e]-mean)*rstd*w[c]);
  }
}

// ---------------- causal depthwise conv (K=4) + SiLU ----------------
__global__ __launch_bounds__(256) void conv_silu_kernel(const bf16* __restrict__ up,
    const float* __restrict__ cw, const float* __restrict__ cb, bf16* __restrict__ xca){
  size_t gid = (size_t)blockIdx.x*256 + threadIdx.x;   // over T_*INNER_
  int c = (int)(gid & (INNER_-1));
  size_t bs = gid >> 11;
  int s = (int)(bs & (S_-1));
  float acc = cb[c];
  #pragma unroll
  for (int t=0;t<4;t++){
    int sp = s-3+t;
    if (sp>=0) acc += b2f(up[(bs + (size_t)(t-3))*(size_t)(2*INNER_) + c]) * cw[c*4+t];
  }
  float sg = 1.f/(1.f+expf(-acc));
  xca[gid] = f2b(acc*sg);
}

// ---------------- block-diagonal (4x4) q/k/v projections ----------------
__global__ __launch_bounds__(256) void headwise_kernel(const bf16* __restrict__ xca,
    const bf16* __restrict__ up,
    const float* __restrict__ qw, const float* __restrict__ qb,
    const float* __restrict__ kw, const float* __restrict__ kb,
    const float* __restrict__ vw, const float* __restrict__ vb,
    bf16* __restrict__ q, bf16* __restrict__ k, bf16* __restrict__ v){
  size_t gid = (size_t)blockIdx.x*256 + threadIdx.x;
  int c = (int)(gid & (INNER_-1));
  size_t bs = gid >> 11;
  int hw = c>>2, o = c&3;
  float aq=qb[c], ak=kb[c], av=vb[c];
  size_t xb = bs*(size_t)INNER_ + (hw<<2);
  size_t mb = bs*(size_t)(2*INNER_) + (hw<<2);
  #pragma unroll
  for (int d=0; d<4; d++){
    float xc = b2f(xca[xb+d]);
    float xm = b2f(up[mb+d]);
    int wi = hw*16 + o*4 + d;   // w[h][o][d]
    aq += xc*qw[wi]; ak += xc*kw[wi]; av += xm*vw[wi];
  }
  q[gid]=f2b(aq); k[gid]=f2b(ak); v[gid]=f2b(av);
}

// ---------------- ig/fg gates: 16 tokens/block, weights staged in LDS ----------------
// gw LDS layout: row r stored at slot = r ^ ((r>>3)&7)  (XOR swizzle, injective;
// breaks the 8-row stride bank aliasing to 2-way). 8 bf16/row: [ig0..3|fg0..3]
__global__ __launch_bounds__(256) void gates_kernel(const bf16* __restrict__ q,
    const bf16* __restrict__ k, const bf16* __restrict__ v,
    const float* __restrict__ igw, const float* __restrict__ igb,
    const float* __restrict__ fgw, const float* __restrict__ fgb,
    float* __restrict__ igo, float* __restrict__ fgo){
  __shared__ short gw[49160];   // 6144*8 + pad
  int tid = threadIdx.x;
  for (int r = tid; r < 3*INNER_; r += 256){
    float4 a = *(const float4*)(igw + (size_t)r*4);
    float4 b = *(const float4*)(fgw + (size_t)r*4);
    int slot = r ^ ((r>>3)&7);
    ushort4 o0, o1;
    o0.x=f2bu(a.x); o0.y=f2bu(a.y); o0.z=f2bu(a.z); o0.w=f2bu(a.w);
    o1.x=f2bu(b.x); o1.y=f2bu(b.y); o1.z=f2bu(b.z); o1.w=f2bu(b.w);
    *(ushort4*)&gw[slot*8]   = o0;
    *(ushort4*)&gw[slot*8+4] = o1;
  }
  __syncthreads();
  int tok = blockIdx.x*16 + (tid>>4);   // global token
  int sl  = tid & 15;
  int b = tok >> 11, s = tok & (S_-1);
  size_t rb = (size_t)tok * INNER_;
  const bf16* srcs[3] = {q + rb, k + rb, v + rb};
  float acc[8];
  #pragma unroll
  for (int n=0;n<8;n++) acc[n]=0.f;
  #pragma unroll
  for (int src=0; src<3; src++){
    const bf16* ptr = srcs[src];
    int kb = src*INNER_;
    #pragma unroll 4
    for (int j=0; j<16; j++){
      int pos = j*128 + sl*8;
      uint4 dv = *(const uint4*)(ptr + pos);
      float d[8]; unpack8(dv, d);
      int rbase = kb + pos;                 // multiple of 8
      int cxor = (rbase>>3)&7;              // constant over e within the group
      #pragma unroll
      for (int e=0;e<8;e++){
        int slot = (rbase + e) ^ cxor;
        uint4 wv = *(const uint4*)&gw[slot*8];
        float w8[8]; unpack8(wv, w8);
        #pragma unroll
        for (int n=0;n<8;n++) acc[n] += d[e]*w8[n];
      }
    }
  }
  // reduce across the 16 lanes of this token
  #pragma unroll
  for (int off=1; off<16; off<<=1){
    #pragma unroll
    for (int n=0;n<8;n++) acc[n] += __shfl_xor(acc[n], off, 16);
  }
  if (sl < 8){
    int n = sl & 3;
    if (sl < 4) igo[((size_t)(b*NH_+n))*S_ + s] = acc[sl] + igb[n];
    else        fgo[((size_t)(b*NH_+n))*S_ + s] = acc[sl] + fgb[n];
  }
}

// ---------------- per-head scan: F=cumsum(logsigmoid(fg)); a=ig-F; M=prefmax(a) ----
__global__ __launch_bounds__(256) void scan8(const float* __restrict__ igp,
    const float* __restrict__ fgp, float* __restrict__ ap,
    float* __restrict__ Mp, float* __restrict__ flp, float* __restrict__ rowsum){
  int h = blockIdx.x, tid = threadIdx.x;
  const float* fg = fgp + (size_t)h*S_;
  const float* ig = igp + (size_t)h*S_;
  int base = tid*8;
  float loc[8], run = 0.f;
  #pragma unroll
  for (int e=0;e<8;e++){
    float x = fg[base+e];
    float ls = fminf(x,0.f) - log1pf(expf(-fabsf(x)));
    run += ls; loc[e] = run;
  }
  __shared__ float sd[256];
  sd[tid]=run; __syncthreads();
  if (tid==0){ float r=0.f; for(int t=0;t<256;t++){ float t0=sd[t]; sd[t]=r; r+=t0; } }
  __syncthreads();
  float off = sd[tid];
  float lm[8], rm = -3e38f;
  #pragma unroll
  for (int e=0;e<8;e++){
    float F = loc[e]+off; loc[e]=F;
    float aj = ig[base+e]-F;
    ap[(size_t)h*S_+base+e]=aj;
    rm = fmaxf(rm, aj); lm[e]=rm;
  }
  __syncthreads();
  sd[tid]=rm; __syncthreads();
  if (tid==0){ float r=-3e38f; for(int t=0;t<256;t++){ float t0=sd[t]; sd[t]=r; r=fmaxf(r,t0); } }
  __syncthreads();
  float offm = sd[tid];
  #pragma unroll
  for (int e=0;e<8;e++){
    float M = fmaxf(lm[e], offm);
    Mp[(size_t)h*S_+base+e]=M;
    flp[(size_t)h*S_+base+e]=expf(-loc[e]-M);
    rowsum[(size_t)h*S_+base+e]=0.f;
  }
}

// ---------------- v (b,s,n*DH+d) -> vT (h, d, s) ----------------
__global__ __launch_bounds__(256) void transpose_v(const bf16* __restrict__ v,
    bf16* __restrict__ vT){
  int sb = blockIdx.x, db = blockIdx.y, h = blockIdx.z;
  int b = h >> 2, n = h & 3;
  int s0 = sb*64, d0 = db*64;
  __shared__ short tl[64*LS];
  int tid = threadIdx.x;
  #pragma unroll
  for (int i=0;i<2;i++){
    int vv = tid + i*256; int r = vv>>3, c8 = vv&7;
    uint4 x = *(const uint4*)(v + (size_t)(b*S_+s0+r)*INNER_ + n*DH_ + d0 + c8*8);
    *(uint4*)&tl[r*LS + c8*8] = x;
  }
  __syncthreads();
  #pragma unroll
  for (int i=0;i<2;i++){
    int vv = tid + i*256; int r = vv>>3, c8 = vv&7;   // r = local d, c8 = s-chunk
    unsigned short tmp[8];
    #pragma unroll
    for (int e=0;e<8;e++) tmp[e] = (unsigned short)tl[(c8*8+e)*LS + r];
    uint4 o; __builtin_memcpy(&o, tmp, 16);
    *(uint4*)(vT + ((size_t)h*DH_ + d0 + r)*S_ + s0 + c8*8) = o;
  }
}

// ---------------- W = (Q K^T)*scale*exp(a_j - M_i), causal; + rowsums ----------------
__global__ __launch_bounds__(256) void qk_decay_kernel(const bf16* __restrict__ qg,
    const bf16* __restrict__ kg, const float* __restrict__ ap,
    const float* __restrict__ Mp, float* __restrict__ rowsum, bf16* __restrict__ W){
  int tj = blockIdx.x, ti = 15 - blockIdx.y, h = blockIdx.z;
  if (tj > ti) return;
  int b = h >> 2, n = h & 3;
  int i0 = ti*128, j0 = tj*128;
  __shared__ short Qs[128*LS];
  __shared__ short Ks[128*LS];
  __shared__ float a_s[128], m_s[128];
  int tid = threadIdx.x;
  if (tid < 128){
    a_s[tid] = ap[(size_t)h*S_ + j0 + tid];
    m_s[tid] = Mp[(size_t)h*S_ + i0 + tid];
  }
  int w = tid>>6, l = tid&63, lq = l>>4, lr = l&15;
  int wm = (w>>1)*64, wn = (w&1)*64;
  floatx4 acc[4][4];
  #pragma unroll
  for (int mi=0;mi<4;mi++){
    #pragma unroll
    for (int ni=0;ni<4;ni++) acc[mi][ni] = (floatx4){0.f,0.f,0.f,0.f};
  }
  for (int d0=0; d0<DH_; d0+=64){
    __syncthreads();
    #pragma unroll
    for (int kk=0;kk<4;kk++){
      int v = tid + kk*256; int r = v>>3, c8 = v&7;
      *(uint4*)&Qs[r*LS + c8*8] = *(const uint4*)(qg + (size_t)(b*S_+i0+r)*INNER_ + n*DH_ + d0 + c8*8);
      *(uint4*)&Ks[r*LS + c8*8] = *(const uint4*)(kg + (size_t)(b*S_+j0+r)*INNER_ + n*DH_ + d0 + c8*8);
    }
    __syncthreads();
    #pragma unroll
    for (int ks=0; ks<2; ks++){
      bf16x8 af[4], bfr[4];
      #pragma unroll
      for (int mi=0;mi<4;mi++) af[mi] = *(const bf16x8*)&Qs[(wm+mi*16+lr)*LS + ks*32 + lq*8];
      #pragma unroll
      for (int ni=0;ni<4;ni++) bfr[ni] = *(const bf16x8*)&Ks[(wn+ni*16+lr)*LS + ks*32 + lq*8];
      #pragma unroll
      for (int mi=0;mi<4;mi++){
        #pragma unroll
        for (int ni=0;ni<4;ni++)
          acc[mi][ni] = __builtin_amdgcn_mfma_f32_16x16x32_bf16(af[mi], bfr[ni], acc[mi][ni], 0,0,0);
      }
    }
  }
  const float scale = 0.04419417382415922f;   // 1/sqrt(512)
  float rpart[4][4];
  #pragma unroll
  for (int mi=0;mi<4;mi++){
    #pragma unroll
    for (int r=0;r<4;r++) rpart[mi][r]=0.f;
  }
  #pragma unroll
  for (int mi=0;mi<4;mi++){
    #pragma unroll
    for (int ni=0;ni<4;ni++){
      #pragma unroll
      for (int r=0;r<4;r++){
        int rowl = wm + mi*16 + lq*4 + r;
        int coll = wn + ni*16 + lr;
        int gi = i0 + rowl, gj = j0 + coll;
        float wv = 0.f;
        if (gj <= gi) wv = acc[mi][ni][r]*scale*__expf(a_s[coll]-m_s[rowl]);
        W[((size_t)h*S_ + gi)*S_ + gj] = f2b(wv);
        rpart[mi][r] += wv;
      }
    }
  }
  #pragma unroll
  for (int mi=0;mi<4;mi++){
    #pragma unroll
    for (int r=0;r<4;r++){
      float v = rpart[mi][r];
      v += __shfl_xor(v, 1, 16);
      v += __shfl_xor(v, 2, 16);
      v += __shfl_xor(v, 4, 16);
      v += __shfl_xor(v, 8, 16);
      if (lr == 0)
        atomicAdd(&rowsum[(size_t)h*S_ + i0 + wm + mi*16 + lq*4 + r], v);
    }
  }
}

// ---------------- inv_i = 1/(max(|rowsum_i|, fl_i)+eps) ----------------
__global__ __launch_bounds__(256) void norm_kernel(const float* __restrict__ rowsum,
    const float* __restrict__ fl, float* __restrict__ inv){
  int o = blockIdx.x*256 + threadIdx.x;
  inv[o] = 1.f/(fmaxf(fabsf(rowsum[o]), fl[o]) + EPS_CELL);
}

// ---------------- O = (W * inv_row) @ V  (causal k-range) ----------------
__global__ __launch_bounds__(256) void pv_kernel(const bf16* __restrict__ W,
    const bf16* __restrict__ vT, const float* __restrict__ inv, bf16* __restrict__ O){
  int tn = blockIdx.x, ti = 15 - blockIdx.y, h = blockIdx.z;
  int b = h >> 2, n = h & 3;
  int i0 = ti*128, d0 = tn*128;
  __shared__ short Ws[128*LS];
  __shared__ short Vs[128*LS];
  __shared__ float inv_s[128];
  int tid = threadIdx.x;
  if (tid < 128) inv_s[tid] = inv[(size_t)h*S_ + i0 + tid];
  int w = tid>>6, l = tid&63, lq = l>>4, lr = l&15;
  int wm = (w>>1)*64, wn = (w&1)*64;
  floatx4 acc[4][4];
  #pragma unroll
  for (int mi=0;mi<4;mi++){
    #pragma unroll
    for (int ni=0;ni<4;ni++) acc[mi][ni] = (floatx4){0.f,0.f,0.f,0.f};
  }
  int jmax = i0 + 128;
  for (int j0=0; j0<jmax; j0+=64){
    __syncthreads();
    #pragma unroll
    for (int kk=0;kk<4;kk++){
      int v = tid + kk*256; int r = v>>3, c8 = v&7;
      *(uint4*)&Ws[r*LS + c8*8] = *(const uint4*)(W + ((size_t)h*S_ + i0 + r)*S_ + j0 + c8*8);
      *(uint4*)&Vs[r*LS + c8*8] = *(const uint4*)(vT + ((size_t)h*DH_ + d0 + r)*S_ + j0 + c8*8);
    }
    __syncthreads();
    #pragma unroll
    for (int ks=0; ks<2; ks++){
      bf16x8 af[4], bfr[4];
      #pragma unroll
      for (int mi=0;mi<4;mi++) af[mi] = *(const bf16x8*)&Ws[(wm+mi*16+lr)*LS + ks*32 + lq*8];
      #pragma unroll
      for (int ni=0;ni<4;ni++) bfr[ni] = *(const bf16x8*)&Vs[(wn+ni*16+lr)*LS + ks*32 + lq*8];
      #pragma unroll
      for (int mi=0;mi<4;mi++){
        #pragma unroll
        for (int ni=0;ni<4;ni++)
          acc[mi][ni] = __builtin_amdgcn_mfma_f32_16x16x32_bf16(af[mi], bfr[ni], acc[mi][ni], 0,0,0);
      }
    }
  }
  #pragma unroll
  for (int mi=0;mi<4;mi++){
    #pragma unroll
    for (int ni=0;ni<4;ni++){
      #pragma unroll
      for (int r=0;r<4;r++){
        int rowl = wm + mi*16 + lq*4 + r;
        int dl = wn + ni*16 + lr;
        float o = acc[mi][ni][r] * inv_s[rowl];
        O[(size_t)(b*S_ + i0 + rowl)*INNER_ + n*DH_ + d0 + dl] = f2b(o);
      }
    }
  }
}

// ---------------- head groupnorm + skip + output gate (in-place into z) ----------
__global__ __launch_bounds__(256) void headnorm_gate(const bf16* __restrict__ h,
    const float* __restrict__ onw, const float* __restrict__ skip,
    const bf16* __restrict__ xca, bf16* __restrict__ up){
  int bid = blockIdx.x;
  int n = bid & 3; int bs = bid >> 2;
  int tid = threadIdx.x;
  size_t hbase = (size_t)bs*INNER_ + n*DH_;
  float v0 = b2f(h[hbase+tid]);
  float v1 = b2f(h[hbase+256+tid]);
  __shared__ float sa[256], sb[256];
  sa[tid]=v0+v1; sb[tid]=v0*v0+v1*v1;
  __syncthreads();
  for (int off=128; off>0; off>>=1){
    if (tid<off){ sa[tid]+=sa[tid+off]; sb[tid]+=sb[tid+off]; }
    __syncthreads();
  }
  float mean = sa[0]*(1.f/DH_);
  float var  = sb[0]*(1.f/DH_) - mean*mean;
  float rstd = rsqrtf(var + LN_EPS_);
  #pragma unroll
  for (int e=0;e<2;e++){
    int dl = e*256+tid; int c = n*DH_+dl;
    float hv = e ? v1 : v0;
    float hn = (hv-mean)*rstd*onw[c];
    float hs = hn + skip[c]*b2f(xca[(size_t)bs*INNER_+c]);
    size_t zoff = (size_t)bs*(2*INNER_) + INNER_ + c;
    float zv = b2f(up[zoff]);
    float sz = zv/(1.f+expf(-zv));
    up[zoff] = f2b(hs*sz);
  }
}

extern "C" void kernel_launch(void* const* d_in, const int* in_sizes, int n_in,
                              void* d_out, int out_size, void* d_ws, size_t ws_size,
                              hipStream_t stream) {
  const float* x      = (const float*)d_in[0];
  const float* w_in   = (const float*)d_in[1];
  const float* b_in   = (const float*)d_in[2];
  const float* ln1_w  = (const float*)d_in[3];
  const float* w_up   = (const float*)d_in[4];
  const float* b_up   = (const float*)d_in[5];
  const float* conv_w = (const float*)d_in[6];
  const float* conv_b = (const float*)d_in[7];
  const float* q_w    = (const float*)d_in[8];
  const float* q_b    = (const float*)d_in[9];
  const float* k_w    = (const float*)d_in[10];
  const float* k_b    = (const float*)d_in[11];
  const float* v_w    = (const float*)d_in[12];
  const float* v_b    = (const float*)d_in[13];
  const float* ig_w   = (const float*)d_in[14];
  const float* ig_b   = (const float*)d_in[15];
  const float* fg_w   = (const float*)d_in[16];
  const float* fg_b   = (const float*)d_in[17];
  const float* onw    = (const float*)d_in[18];
  const float* skip   = (const float*)d_in[19];
  const float* w_down = (const float*)d_in[20];
  const float* b_down = (const float*)d_in[21];
  const float* post_w = (const float*)d_in[22];

  char* p = (char*)d_ws;
  auto alloc = [&](size_t bytes)->void*{ void* r = p; p += (bytes + 255) & ~(size_t)255; return r; };
  bf16* h_in = (bf16*)alloc((size_t)T_*E_*2);        // 8 MB
  bf16* xn   = (bf16*)alloc((size_t)T_*E_*2);        // 8 MB (reused as y later)
  bf16* up   = (bf16*)alloc((size_t)T_*2*INNER_*2);  // 32 MB (x_m | z; z later holds h_gated)
  bf16* xca  = (bf16*)alloc((size_t)T_*INNER_*2);    // 16 MB
  bf16* qb_  = (bf16*)alloc((size_t)T_*INNER_*2);
  bf16* kb_  = (bf16*)alloc((size_t)T_*INNER_*2);
  bf16* vb_  = (bf16*)alloc((size_t)T_*INNER_*2);    // v; later reused as attention O
  bf16* hb_  = (bf16*)alloc((size_t)T_*INNER_*2);    // reused as vT (h,d,s)
  float* igbuf = (float*)alloc((size_t)B_*NH_*S_*4);
  float* fgbuf = (float*)alloc((size_t)B_*NH_*S_*4);
  float* abuf  = (float*)alloc((size_t)B_*NH_*S_*4);
  float* Mbuf  = (float*)alloc((size_t)B_*NH_*S_*4);
  float* flbuf = (float*)alloc((size_t)B_*NH_*S_*4);
  float* rsbuf = (float*)alloc((size_t)B_*NH_*S_*4);
  float* invbuf= (float*)alloc((size_t)B_*NH_*S_*4);
  bf16* Wbuf = (bf16*)alloc((size_t)B_*NH_*S_*S_*2); // 67 MB decay-weighted scores
  bf16* ybuf = xn;   // xn dead after up-projection
  bf16* vTb  = hb_;
  bf16* obuf = vb_;
  // converted-weight scratch overlapping Wbuf (dead until qk_decay / after pv)
  bf16* xbf    = Wbuf;                               // 4 MB, dead after GEMM1
  bf16* w_in_t = Wbuf + (size_t)T_*IN_;              // 1 MB, dead after GEMM1
  bf16* w_up_t = w_in_t + (size_t)E_*IN_;            // 8 MB, dead after GEMM2
  bf16* w_down_t = Wbuf;                             // written AFTER pv_kernel frees Wbuf

  // 0a. convert x -> bf16 ; transpose+convert w_in, w_up
  convert_bf16<<<(T_*IN_/8+255)/256, 256, 0, stream>>>(x, xbf, T_*IN_/8);
  transpose_conv_w<<<dim3(E_/64, IN_/64), 256, 0, stream>>>(w_in, w_in_t, IN_, E_);
  transpose_conv_w<<<dim3((2*INNER_)/64, E_/64), 256, 0, stream>>>(w_up, w_up_t, E_, 2*INNER_);
  // 1. h_in = x @ w_in + b_in
  mfma_gemm<<<dim3(E_/128, T_/128), 256, 0, stream>>>(xbf, w_in_t, b_in, h_in, IN_, IN_, E_);
  // 2. xn = LN(h_in)*ln1_w
  ln_rows<bf16><<<T_, 256, 0, stream>>>(h_in, nullptr, ln1_w, xn);
  // 3. up = xn @ w_up + b_up   (x_m | z)
  mfma_gemm<<<dim3((2*INNER_)/128, T_/128), 256, 0, stream>>>(xn, w_up_t, b_up, up, E_, E_, 2*INNER_);
  // 4. x_conv_act = silu(causal_conv(x_m))
  conv_silu_kernel<<<(T_*INNER_)/256, 256, 0, stream>>>(up, conv_w, conv_b, xca);
  // 5. q,k from x_conv_act; v from x_m (block-diagonal 4x4)
  headwise_kernel<<<(T_*INNER_)/256, 256, 0, stream>>>(xca, up, q_w, q_b, k_w, k_b, v_w, v_b, qb_, kb_, vb_);
  // 6. gate pre-activations (16 tokens/block, LDS-staged weights)
  gates_kernel<<<T_/16, 256, 0, stream>>>(qb_, kb_, vb_, ig_w, ig_b, fg_w, fg_b, igbuf, fgbuf);
  // 7. scans: a, M, floor; zero rowsums
  scan8<<<B_*NH_, 256, 0, stream>>>(igbuf, fgbuf, abuf, Mbuf, flbuf, rsbuf);
  // 8. v -> vT (head-major, d-major)
  transpose_v<<<dim3(S_/64, DH_/64, B_*NH_), 256, 0, stream>>>(vb_, vTb);
  // 9. W = QK^T * scale * decay (lower triangle), rowsums
  qk_decay_kernel<<<dim3(16, 16, B_*NH_), 256, 0, stream>>>(qb_, kb_, abuf, Mbuf, rsbuf, Wbuf);
  // 10. normalizers
  norm_kernel<<<(B_*NH_*S_)/256, 256, 0, stream>>>(rsbuf, flbuf, invbuf);
  // 11. O = (W*inv) @ V   -> obuf (b,s,n*DH+d)
  pv_kernel<<<dim3(4, 16, B_*NH_), 256, 0, stream>>>(Wbuf, vTb, invbuf, obuf);
  // 12. headnorm + skip + output gate, written in place over z
  headnorm_gate<<<T_*NH_, 256, 0, stream>>>(obuf, onw, skip, xca, up);
  // 12b. transpose+convert w_down (Wbuf now dead)
  transpose_conv_w<<<dim3(E_/64, INNER_/64), 256, 0, stream>>>(w_down, w_down_t, INNER_, E_);
  // 13. y = h_gated @ w_down + b_down
  mfma_gemm<<<dim3(E_/128, T_/128), 256, 0, stream>>>(up + INNER_, w_down_t, b_down, ybuf, INNER_, 2*INNER_, E_);
  // 14. out = LN(h_in + y)*post_w
  ln_rows<float><<<T_, 256, 0, stream>>>(h_in, ybuf, post_w, (float*)d_out);
}

// Round 8
// 489.535 us; speedup vs baseline: 5.8638x; 1.0403x over previous
//
#include <hip/hip_runtime.h>
#include <hip/hip_bf16.h>

typedef __hip_bfloat16 bf16;
typedef float floatx4 __attribute__((ext_vector_type(4)));
typedef short bf16x8 __attribute__((ext_vector_type(8)));

#define B_      2
#define S_      2048
#define IN_     512
#define E_      1024
#define INNER_  2048
#define NH_     4
#define DH_     512
#define T_      (B_*S_)      // 4096 tokens
#define EPS_CELL 1e-6f
#define LN_EPS_  1e-5f
#define LS      72           // padded LDS row stride (shorts) for non-async kernels

__device__ inline float b2f(bf16 x){ return __bfloat162float(x); }
__device__ inline bf16  f2b(float x){ return __float2bfloat16(x); }
__device__ inline float us2f(unsigned short u){ union{unsigned int i; float f;} v; v.i = ((unsigned int)u)<<16; return v.f; }
__device__ inline float u2f(unsigned int u){ union{unsigned int i; float f;} v; v.i = u; return v.f; }
__device__ inline unsigned short f2bu(float x){ bf16 t = __float2bfloat16(x); unsigned short r; __builtin_memcpy(&r,&t,2); return r; }
__device__ inline void unpack8(uint4 u, float* f){
  f[0]=u2f(u.x<<16); f[1]=u2f(u.x&0xffff0000u);
  f[2]=u2f(u.y<<16); f[3]=u2f(u.y&0xffff0000u);
  f[4]=u2f(u.z<<16); f[5]=u2f(u.z&0xffff0000u);
  f[6]=u2f(u.w<<16); f[7]=u2f(u.w&0xffff0000u);
}
__device__ inline void stv(bf16* p, float v){ *p = f2b(v); }
__device__ inline void stv(float* p, float v){ *p = v; }

// ---- async 16B global->LDS copy (wave-uniform base + lane*16 pattern) ----
typedef __attribute__((address_space(3))) unsigned int lds_u32_t;
typedef __attribute__((address_space(1))) const unsigned int glb_u32_t;
__device__ __forceinline__ void cp_async16(const bf16* g, short* l){
  __builtin_amdgcn_global_load_lds((glb_u32_t*)(const void*)g,
                                   (lds_u32_t*)(void*)l, 16, 0, 0);
}
// swizzled LDS offset (shorts) for 128x64 tile: row-dense, chunk XOR row&7
__device__ __forceinline__ int so_(int row, int c8){ return row*64 + (((c8) ^ (row&7))<<3); }

// stage a 128x64-short tile (rows stride `stride` in global) into dst via async DMA
// kk = issue index 0..3, tid = threadIdx.x (256 threads)
#define STAGE_ASYNC(dst, srcbase, stride, kk) \
  { int slot_ = (kk)*256 + tid; int r_ = slot_>>3; int c8_ = (slot_&7) ^ (r_&7); \
    cp_async16((srcbase) + (size_t)r_*(stride) + c8_*8, &dst[slot_*8]); }

// ---------------- fp32 -> bf16 elementwise convert ----------------
__global__ __launch_bounds__(256) void convert_bf16(const float* __restrict__ X,
    bf16* __restrict__ Y, int n8){
  int i = blockIdx.x*256 + threadIdx.x;
  if (i >= n8) return;
  const float4* p = (const float4*)(X) + i*2;
  float4 a = p[0], b = p[1];
  ushort4 o0, o1;
  o0.x=f2bu(a.x); o0.y=f2bu(a.y); o0.z=f2bu(a.z); o0.w=f2bu(a.w);
  o1.x=f2bu(b.x); o1.y=f2bu(b.y); o1.z=f2bu(b.z); o1.w=f2bu(b.w);
  ushort4* q = (ushort4*)(Y) + i*2;
  q[0]=o0; q[1]=o1;
}

// ---------------- W[K,N] fp32 -> Wt[N,K] bf16 (64x64 LDS tiles) ----------------
__global__ __launch_bounds__(256) void transpose_conv_w(const float* __restrict__ W,
    bf16* __restrict__ Wt, int K, int N){
  int n0 = blockIdx.x*64, k0 = blockIdx.y*64;
  __shared__ float tl[64][65];
  int tid = threadIdx.x;
  #pragma unroll
  for (int i=0;i<4;i++){
    int idx = tid + i*256; int r = idx>>4, c4 = idx&15;
    float4 v = *(const float4*)(W + (size_t)(k0+r)*N + n0 + c4*4);
    tl[r][c4*4+0]=v.x; tl[r][c4*4+1]=v.y; tl[r][c4*4+2]=v.z; tl[r][c4*4+3]=v.w;
  }
  __syncthreads();
  #pragma unroll
  for (int i=0;i<4;i++){
    int idx = tid + i*256; int rn = idx>>4, c4 = idx&15;
    ushort4 o;
    o.x=f2bu(tl[c4*4+0][rn]); o.y=f2bu(tl[c4*4+1][rn]);
    o.z=f2bu(tl[c4*4+2][rn]); o.w=f2bu(tl[c4*4+3][rn]);
    *(ushort4*)(Wt + (size_t)(n0+rn)*K + k0 + c4*4) = o;
  }
}

// ---------------- MFMA GEMM: C[M,N] = A[M,K] @ Bt[N,K]^T + bias ----------------
__global__ __launch_bounds__(256) void mfma_gemm(const bf16* __restrict__ A,
    const bf16* __restrict__ Bt, const float* __restrict__ bias, bf16* __restrict__ C,
    int Kd, int lda, int ldc){
  int n0 = blockIdx.x*128, m0 = blockIdx.y*128;
  __shared__ __align__(16) short As[128*64];
  __shared__ __align__(16) short Bs[128*64];
  int tid = threadIdx.x;
  int w = tid>>6, l = tid&63, lq = l>>4, lr = l&15;
  int wm = (w>>1)*64, wn = (w&1)*64;
  const bf16* Abase = A + (size_t)m0*lda;
  const bf16* Bbase = Bt + (size_t)n0*Kd;
  floatx4 acc[4][4];
  #pragma unroll
  for (int mi=0;mi<4;mi++){
    #pragma unroll
    for (int ni=0;ni<4;ni++) acc[mi][ni] = (floatx4){0.f,0.f,0.f,0.f};
  }
  for (int k0=0; k0<Kd; k0+=64){
    __syncthreads();
    #pragma unroll
    for (int kk=0;kk<4;kk++){
      STAGE_ASYNC(As, Abase + k0, lda, kk);
      STAGE_ASYNC(Bs, Bbase + k0, Kd, kk);
    }
    __syncthreads();
    #pragma unroll
    for (int ks=0; ks<2; ks++){
      bf16x8 af[4], bfr[4];
      #pragma unroll
      for (int mi=0;mi<4;mi++) af[mi] = *(const bf16x8*)&As[so_(wm+mi*16+lr, ks*4+lq)];
      #pragma unroll
      for (int ni=0;ni<4;ni++) bfr[ni] = *(const bf16x8*)&Bs[so_(wn+ni*16+lr, ks*4+lq)];
      #pragma unroll
      for (int mi=0;mi<4;mi++){
        #pragma unroll
        for (int ni=0;ni<4;ni++)
          acc[mi][ni] = __builtin_amdgcn_mfma_f32_16x16x32_bf16(af[mi], bfr[ni], acc[mi][ni], 0,0,0);
      }
    }
  }
  float bb[4];
  #pragma unroll
  for (int ni=0;ni<4;ni++) bb[ni] = bias[n0 + wn + ni*16 + lr];
  #pragma unroll
  for (int mi=0;mi<4;mi++){
    #pragma unroll
    for (int ni=0;ni<4;ni++){
      #pragma unroll
      for (int r=0;r<4;r++){
        int rowl = wm + mi*16 + lq*4 + r;
        int coll = wn + ni*16 + lr;
        C[(size_t)(m0+rowl)*ldc + n0 + coll] = f2b(acc[mi][ni][r] + bb[ni]);
      }
    }
  }
}

// ---------------- layernorm over rows of length E_ (opt. fused add) ----------------
template<typename OutT>
__global__ __launch_bounds__(256) void ln_rows(const bf16* __restrict__ X,
    const bf16* __restrict__ Xadd, const float* __restrict__ w, OutT* __restrict__ Y){
  int row = blockIdx.x, tid = threadIdx.x;
  size_t base = (size_t)row*E_;
  float vals[4], s=0.f, s2=0.f;
  #pragma unroll
  for (int e=0;e<4;e++){
    int c = e*256+tid;
    float v = b2f(X[base+c]);
    if (Xadd) v += b2f(Xadd[base+c]);
    vals[e]=v; s+=v; s2+=v*v;
  }
  __shared__ float sa[256], sb[256];
  sa[tid]=s; sb[tid]=s2; __syncthreads();
  for (int off=128; off>0; off>>=1){
    if (tid<off){ sa[tid]+=sa[tid+off]; sb[tid]+=sb[tid+off]; }
    __syncthreads();
  }
  float mean = sa[0]*(1.f/E_);
  float var  = sb[0]*(1.f/E_) - mean*mean;
  float rstd = rsqrtf(var + LN_EPS_);
  #pragma unroll
  for (int e=0;e<4;e++){
    int c = e*256+tid;
    stv(&Y[base+c], (vals[e]-mean)*rstd*w[c]);
  }
}

// ---------------- causal depthwise conv (K=4) + SiLU ----------------
__global__ __launch_bounds__(256) void conv_silu_kernel(const bf16* __restrict__ up,
    const float* __restrict__ cw, const float* __restrict__ cb, bf16* __restrict__ xca){
  size_t gid = (size_t)blockIdx.x*256 + threadIdx.x;   // over T_*INNER_
  int c = (int)(gid & (INNER_-1));
  size_t bs = gid >> 11;
  int s = (int)(bs & (S_-1));
  float acc = cb[c];
  #pragma unroll
  for (int t=0;t<4;t++){
    int sp = s-3+t;
    if (sp>=0) acc += b2f(up[(bs + (size_t)(t-3))*(size_t)(2*INNER_) + c]) * cw[c*4+t];
  }
  float sg = 1.f/(1.f+expf(-acc));
  xca[gid] = f2b(acc*sg);
}

// ---------------- block-diagonal (4x4) q/k/v projections ----------------
__global__ __launch_bounds__(256) void headwise_kernel(const bf16* __restrict__ xca,
    const bf16* __restrict__ up,
    const float* __restrict__ qw, const float* __restrict__ qb,
    const float* __restrict__ kw, const float* __restrict__ kb,
    const float* __restrict__ vw, const float* __restrict__ vb,
    bf16* __restrict__ q, bf16* __restrict__ k, bf16* __restrict__ v){
  size_t gid = (size_t)blockIdx.x*256 + threadIdx.x;
  int c = (int)(gid & (INNER_-1));
  size_t bs = gid >> 11;
  int hw = c>>2, o = c&3;
  float aq=qb[c], ak=kb[c], av=vb[c];
  size_t xb = bs*(size_t)INNER_ + (hw<<2);
  size_t mb = bs*(size_t)(2*INNER_) + (hw<<2);
  #pragma unroll
  for (int d=0; d<4; d++){
    float xc = b2f(xca[xb+d]);
    float xm = b2f(up[mb+d]);
    int wi = hw*16 + o*4 + d;   // w[h][o][d]
    aq += xc*qw[wi]; ak += xc*kw[wi]; av += xm*vw[wi];
  }
  q[gid]=f2b(aq); k[gid]=f2b(ak); v[gid]=f2b(av);
}

// ---------------- ig/fg gates: 16 tokens/block, weights staged in LDS ----------------
__global__ __launch_bounds__(256) void gates_kernel(const bf16* __restrict__ q,
    const bf16* __restrict__ k, const bf16* __restrict__ v,
    const float* __restrict__ igw, const float* __restrict__ igb,
    const float* __restrict__ fgw, const float* __restrict__ fgb,
    float* __restrict__ igo, float* __restrict__ fgo){
  __shared__ short gw[49160];   // 6144*8 + pad
  int tid = threadIdx.x;
  for (int r = tid; r < 3*INNER_; r += 256){
    float4 a = *(const float4*)(igw + (size_t)r*4);
    float4 b = *(const float4*)(fgw + (size_t)r*4);
    int slot = r ^ ((r>>3)&7);
    ushort4 o0, o1;
    o0.x=f2bu(a.x); o0.y=f2bu(a.y); o0.z=f2bu(a.z); o0.w=f2bu(a.w);
    o1.x=f2bu(b.x); o1.y=f2bu(b.y); o1.z=f2bu(b.z); o1.w=f2bu(b.w);
    *(ushort4*)&gw[slot*8]   = o0;
    *(ushort4*)&gw[slot*8+4] = o1;
  }
  __syncthreads();
  int tok = blockIdx.x*16 + (tid>>4);   // global token
  int sl  = tid & 15;
  int b = tok >> 11, s = tok & (S_-1);
  size_t rb = (size_t)tok * INNER_;
  const bf16* srcs[3] = {q + rb, k + rb, v + rb};
  float acc[8];
  #pragma unroll
  for (int n=0;n<8;n++) acc[n]=0.f;
  #pragma unroll
  for (int src=0; src<3; src++){
    const bf16* ptr = srcs[src];
    int kb = src*INNER_;
    #pragma unroll 4
    for (int j=0; j<16; j++){
      int pos = j*128 + sl*8;
      uint4 dv = *(const uint4*)(ptr + pos);
      float d[8]; unpack8(dv, d);
      int rbase = kb + pos;                 // multiple of 8
      int cxor = (rbase>>3)&7;              // constant over e within the group
      #pragma unroll
      for (int e=0;e<8;e++){
        int slot = (rbase + e) ^ cxor;
        uint4 wv = *(const uint4*)&gw[slot*8];
        float w8[8]; unpack8(wv, w8);
        #pragma unroll
        for (int n=0;n<8;n++) acc[n] += d[e]*w8[n];
      }
    }
  }
  #pragma unroll
  for (int off=1; off<16; off<<=1){
    #pragma unroll
    for (int n=0;n<8;n++) acc[n] += __shfl_xor(acc[n], off, 16);
  }
  if (sl < 8){
    int n = sl & 3;
    if (sl < 4) igo[((size_t)(b*NH_+n))*S_ + s] = acc[sl] + igb[n];
    else        fgo[((size_t)(b*NH_+n))*S_ + s] = acc[sl] + fgb[n];
  }
}

// ---------------- per-head scan: F=cumsum(logsigmoid(fg)); a=ig-F; M=prefmax(a) ----
__global__ __launch_bounds__(256) void scan8(const float* __restrict__ igp,
    const float* __restrict__ fgp, float* __restrict__ ap,
    float* __restrict__ Mp, float* __restrict__ flp, float* __restrict__ rowsum){
  int h = blockIdx.x, tid = threadIdx.x;
  const float* fg = fgp + (size_t)h*S_;
  const float* ig = igp + (size_t)h*S_;
  int base = tid*8;
  float loc[8], run = 0.f;
  #pragma unroll
  for (int e=0;e<8;e++){
    float x = fg[base+e];
    float ls = fminf(x,0.f) - log1pf(expf(-fabsf(x)));
    run += ls; loc[e] = run;
  }
  __shared__ float sd[256];
  sd[tid]=run; __syncthreads();
  if (tid==0){ float r=0.f; for(int t=0;t<256;t++){ float t0=sd[t]; sd[t]=r; r+=t0; } }
  __syncthreads();
  float off = sd[tid];
  float lm[8], rm = -3e38f;
  #pragma unroll
  for (int e=0;e<8;e++){
    float F = loc[e]+off; loc[e]=F;
    float aj = ig[base+e]-F;
    ap[(size_t)h*S_+base+e]=aj;
    rm = fmaxf(rm, aj); lm[e]=rm;
  }
  __syncthreads();
  sd[tid]=rm; __syncthreads();
  if (tid==0){ float r=-3e38f; for(int t=0;t<256;t++){ float t0=sd[t]; sd[t]=r; r=fmaxf(r,t0); } }
  __syncthreads();
  float offm = sd[tid];
  #pragma unroll
  for (int e=0;e<8;e++){
    float M = fmaxf(lm[e], offm);
    Mp[(size_t)h*S_+base+e]=M;
    flp[(size_t)h*S_+base+e]=expf(-loc[e]-M);
    rowsum[(size_t)h*S_+base+e]=0.f;
  }
}

// ---------------- v (b,s,n*DH+d) -> vT (h, d, s) ----------------
__global__ __launch_bounds__(256) void transpose_v(const bf16* __restrict__ v,
    bf16* __restrict__ vT){
  int sb = blockIdx.x, db = blockIdx.y, h = blockIdx.z;
  int b = h >> 2, n = h & 3;
  int s0 = sb*64, d0 = db*64;
  __shared__ short tl[64*LS];
  int tid = threadIdx.x;
  #pragma unroll
  for (int i=0;i<2;i++){
    int vv = tid + i*256; int r = vv>>3, c8 = vv&7;
    uint4 x = *(const uint4*)(v + (size_t)(b*S_+s0+r)*INNER_ + n*DH_ + d0 + c8*8);
    *(uint4*)&tl[r*LS + c8*8] = x;
  }
  __syncthreads();
  #pragma unroll
  for (int i=0;i<2;i++){
    int vv = tid + i*256; int r = vv>>3, c8 = vv&7;   // r = local d, c8 = s-chunk
    unsigned short tmp[8];
    #pragma unroll
    for (int e=0;e<8;e++) tmp[e] = (unsigned short)tl[(c8*8+e)*LS + r];
    uint4 o; __builtin_memcpy(&o, tmp, 16);
    *(uint4*)(vT + ((size_t)h*DH_ + d0 + r)*S_ + s0 + c8*8) = o;
  }
}

// ---------------- W = (Q K^T)*scale*exp(a_j - M_i), causal; + rowsums ----------------
// grid.x = 136 lower-triangle tiles (big ti first), grid.z = head
__global__ __launch_bounds__(256) void qk_decay_kernel(const bf16* __restrict__ qg,
    const bf16* __restrict__ kg, const float* __restrict__ ap,
    const float* __restrict__ Mp, float* __restrict__ rowsum, bf16* __restrict__ W){
  int tt = 135 - blockIdx.x;
  int ti = (int)((sqrtf(8.f*tt+1.f)-1.f)*0.5f);
  if ((ti+1)*(ti+2)/2 <= tt) ti++;
  if (ti*(ti+1)/2 > tt) ti--;
  int tj = tt - ti*(ti+1)/2;
  int h = blockIdx.z;
  int b = h >> 2, n = h & 3;
  int i0 = ti*128, j0 = tj*128;
  __shared__ __align__(16) short Qs[128*64];
  __shared__ __align__(16) short Ks[128*64];
  __shared__ float a_s[128], m_s[128];
  int tid = threadIdx.x;
  if (tid < 128){
    a_s[tid] = ap[(size_t)h*S_ + j0 + tid];
    m_s[tid] = Mp[(size_t)h*S_ + i0 + tid];
  }
  int w = tid>>6, l = tid&63, lq = l>>4, lr = l&15;
  int wm = (w>>1)*64, wn = (w&1)*64;
  const bf16* Qbase = qg + (size_t)(b*S_+i0)*INNER_ + n*DH_;
  const bf16* Kbase = kg + (size_t)(b*S_+j0)*INNER_ + n*DH_;
  floatx4 acc[4][4];
  #pragma unroll
  for (int mi=0;mi<4;mi++){
    #pragma unroll
    for (int ni=0;ni<4;ni++) acc[mi][ni] = (floatx4){0.f,0.f,0.f,0.f};
  }
  for (int d0=0; d0<DH_; d0+=64){
    __syncthreads();
    #pragma unroll
    for (int kk=0;kk<4;kk++){
      STAGE_ASYNC(Qs, Qbase + d0, INNER_, kk);
      STAGE_ASYNC(Ks, Kbase + d0, INNER_, kk);
    }
    __syncthreads();
    #pragma unroll
    for (int ks=0; ks<2; ks++){
      bf16x8 af[4], bfr[4];
      #pragma unroll
      for (int mi=0;mi<4;mi++) af[mi] = *(const bf16x8*)&Qs[so_(wm+mi*16+lr, ks*4+lq)];
      #pragma unroll
      for (int ni=0;ni<4;ni++) bfr[ni] = *(const bf16x8*)&Ks[so_(wn+ni*16+lr, ks*4+lq)];
      #pragma unroll
      for (int mi=0;mi<4;mi++){
        #pragma unroll
        for (int ni=0;ni<4;ni++)
          acc[mi][ni] = __builtin_amdgcn_mfma_f32_16x16x32_bf16(af[mi], bfr[ni], acc[mi][ni], 0,0,0);
      }
    }
  }
  const float scale = 0.04419417382415922f;   // 1/sqrt(512)
  float rpart[4][4];
  #pragma unroll
  for (int mi=0;mi<4;mi++){
    #pragma unroll
    for (int r=0;r<4;r++) rpart[mi][r]=0.f;
  }
  #pragma unroll
  for (int mi=0;mi<4;mi++){
    #pragma unroll
    for (int ni=0;ni<4;ni++){
      #pragma unroll
      for (int r=0;r<4;r++){
        int rowl = wm + mi*16 + lq*4 + r;
        int coll = wn + ni*16 + lr;
        int gi = i0 + rowl, gj = j0 + coll;
        float wv = 0.f;
        if (gj <= gi) wv = acc[mi][ni][r]*scale*__expf(a_s[coll]-m_s[rowl]);
        W[((size_t)h*S_ + gi)*S_ + gj] = f2b(wv);
        rpart[mi][r] += wv;
      }
    }
  }
  #pragma unroll
  for (int mi=0;mi<4;mi++){
    #pragma unroll
    for (int r=0;r<4;r++){
      float v = rpart[mi][r];
      v += __shfl_xor(v, 1, 16);
      v += __shfl_xor(v, 2, 16);
      v += __shfl_xor(v, 4, 16);
      v += __shfl_xor(v, 8, 16);
      if (lr == 0)
        atomicAdd(&rowsum[(size_t)h*S_ + i0 + wm + mi*16 + lq*4 + r], v);
    }
  }
}

// ---------------- inv_i = 1/(max(|rowsum_i|, fl_i)+eps) ----------------
__global__ __launch_bounds__(256) void norm_kernel(const float* __restrict__ rowsum,
    const float* __restrict__ fl, float* __restrict__ inv){
  int o = blockIdx.x*256 + threadIdx.x;
  inv[o] = 1.f/(fmaxf(fabsf(rowsum[o]), fl[o]) + EPS_CELL);
}

// ---------------- O = (W * inv_row) @ V  (causal k-range) ----------------
__global__ __launch_bounds__(256) void pv_kernel(const bf16* __restrict__ W,
    const bf16* __restrict__ vT, const float* __restrict__ inv, bf16* __restrict__ O){
  int tn = blockIdx.x, ti = 15 - blockIdx.y, h = blockIdx.z;
  int b = h >> 2, n = h & 3;
  int i0 = ti*128, d0 = tn*128;
  __shared__ __align__(16) short Ws[128*64];
  __shared__ __align__(16) short Vs[128*64];
  __shared__ float inv_s[128];
  int tid = threadIdx.x;
  if (tid < 128) inv_s[tid] = inv[(size_t)h*S_ + i0 + tid];
  int w = tid>>6, l = tid&63, lq = l>>4, lr = l&15;
  int wm = (w>>1)*64, wn = (w&1)*64;
  const bf16* Wbase = W + ((size_t)h*S_ + i0)*S_;
  const bf16* Vbase = vT + ((size_t)h*DH_ + d0)*S_;
  floatx4 acc[4][4];
  #pragma unroll
  for (int mi=0;mi<4;mi++){
    #pragma unroll
    for (int ni=0;ni<4;ni++) acc[mi][ni] = (floatx4){0.f,0.f,0.f,0.f};
  }
  int jmax = i0 + 128;
  for (int j0=0; j0<jmax; j0+=64){
    __syncthreads();
    #pragma unroll
    for (int kk=0;kk<4;kk++){
      STAGE_ASYNC(Ws, Wbase + j0, S_, kk);
      STAGE_ASYNC(Vs, Vbase + j0, S_, kk);
    }
    __syncthreads();
    #pragma unroll
    for (int ks=0; ks<2; ks++){
      bf16x8 af[4], bfr[4];
      #pragma unroll
      for (int mi=0;mi<4;mi++) af[mi] = *(const bf16x8*)&Ws[so_(wm+mi*16+lr, ks*4+lq)];
      #pragma unroll
      for (int ni=0;ni<4;ni++) bfr[ni] = *(const bf16x8*)&Vs[so_(wn+ni*16+lr, ks*4+lq)];
      #pragma unroll
      for (int mi=0;mi<4;mi++){
        #pragma unroll
        for (int ni=0;ni<4;ni++)
          acc[mi][ni] = __builtin_amdgcn_mfma_f32_16x16x32_bf16(af[mi], bfr[ni], acc[mi][ni], 0,0,0);
      }
    }
  }
  #pragma unroll
  for (int mi=0;mi<4;mi++){
    #pragma unroll
    for (int ni=0;ni<4;ni++){
      #pragma unroll
      for (int r=0;r<4;r++){
        int rowl = wm + mi*16 + lq*4 + r;
        int dl = wn + ni*16 + lr;
        float o = acc[mi][ni][r] * inv_s[rowl];
        O[(size_t)(b*S_ + i0 + rowl)*INNER_ + n*DH_ + d0 + dl] = f2b(o);
      }
    }
  }
}

// ---------------- head groupnorm + skip + output gate (in-place into z) ----------
__global__ __launch_bounds__(256) void headnorm_gate(const bf16* __restrict__ h,
    const float* __restrict__ onw, const float* __restrict__ skip,
    const bf16* __restrict__ xca, bf16* __restrict__ up){
  int bid = blockIdx.x;
  int n = bid & 3; int bs = bid >> 2;
  int tid = threadIdx.x;
  size_t hbase = (size_t)bs*INNER_ + n*DH_;
  float v0 = b2f(h[hbase+tid]);
  float v1 = b2f(h[hbase+256+tid]);
  __shared__ float sa[256], sb[256];
  sa[tid]=v0+v1; sb[tid]=v0*v0+v1*v1;
  __syncthreads();
  for (int off=128; off>0; off>>=1){
    if (tid<off){ sa[tid]+=sa[tid+off]; sb[tid]+=sb[tid+off]; }
    __syncthreads();
  }
  float mean = sa[0]*(1.f/DH_);
  float var  = sb[0]*(1.f/DH_) - mean*mean;
  float rstd = rsqrtf(var + LN_EPS_);
  #pragma unroll
  for (int e=0;e<2;e++){
    int dl = e*256+tid; int c = n*DH_+dl;
    float hv = e ? v1 : v0;
    float hn = (hv-mean)*rstd*onw[c];
    float hs = hn + skip[c]*b2f(xca[(size_t)bs*INNER_+c]);
    size_t zoff = (size_t)bs*(2*INNER_) + INNER_ + c;
    float zv = b2f(up[zoff]);
    float sz = zv/(1.f+expf(-zv));
    up[zoff] = f2b(hs*sz);
  }
}

extern "C" void kernel_launch(void* const* d_in, const int* in_sizes, int n_in,
                              void* d_out, int out_size, void* d_ws, size_t ws_size,
                              hipStream_t stream) {
  const float* x      = (const float*)d_in[0];
  const float* w_in   = (const float*)d_in[1];
  const float* b_in   = (const float*)d_in[2];
  const float* ln1_w  = (const float*)d_in[3];
  const float* w_up   = (const float*)d_in[4];
  const float* b_up   = (const float*)d_in[5];
  const float* conv_w = (const float*)d_in[6];
  const float* conv_b = (const float*)d_in[7];
  const float* q_w    = (const float*)d_in[8];
  const float* q_b    = (const float*)d_in[9];
  const float* k_w    = (const float*)d_in[10];
  const float* k_b    = (const float*)d_in[11];
  const float* v_w    = (const float*)d_in[12];
  const float* v_b    = (const float*)d_in[13];
  const float* ig_w   = (const float*)d_in[14];
  const float* ig_b   = (const float*)d_in[15];
  const float* fg_w   = (const float*)d_in[16];
  const float* fg_b   = (const float*)d_in[17];
  const float* onw    = (const float*)d_in[18];
  const float* skip   = (const float*)d_in[19];
  const float* w_down = (const float*)d_in[20];
  const float* b_down = (const float*)d_in[21];
  const float* post_w = (const float*)d_in[22];

  char* p = (char*)d_ws;
  auto alloc = [&](size_t bytes)->void*{ void* r = p; p += (bytes + 255) & ~(size_t)255; return r; };
  bf16* h_in = (bf16*)alloc((size_t)T_*E_*2);        // 8 MB
  bf16* xn   = (bf16*)alloc((size_t)T_*E_*2);        // 8 MB (reused as y later)
  bf16* up   = (bf16*)alloc((size_t)T_*2*INNER_*2);  // 32 MB (x_m | z; z later holds h_gated)
  bf16* xca  = (bf16*)alloc((size_t)T_*INNER_*2);    // 16 MB
  bf16* qb_  = (bf16*)alloc((size_t)T_*INNER_*2);
  bf16* kb_  = (bf16*)alloc((size_t)T_*INNER_*2);
  bf16* vb_  = (bf16*)alloc((size_t)T_*INNER_*2);    // v; later reused as attention O
  bf16* hb_  = (bf16*)alloc((size_t)T_*INNER_*2);    // reused as vT (h,d,s)
  float* igbuf = (float*)alloc((size_t)B_*NH_*S_*4);
  float* fgbuf = (float*)alloc((size_t)B_*NH_*S_*4);
  float* abuf  = (float*)alloc((size_t)B_*NH_*S_*4);
  float* Mbuf  = (float*)alloc((size_t)B_*NH_*S_*4);
  float* flbuf = (float*)alloc((size_t)B_*NH_*S_*4);
  float* rsbuf = (float*)alloc((size_t)B_*NH_*S_*4);
  float* invbuf= (float*)alloc((size_t)B_*NH_*S_*4);
  bf16* Wbuf = (bf16*)alloc((size_t)B_*NH_*S_*S_*2); // 67 MB decay-weighted scores
  bf16* ybuf = xn;   // xn dead after up-projection
  bf16* vTb  = hb_;
  bf16* obuf = vb_;
  // converted-weight scratch overlapping Wbuf (dead until qk_decay / after pv)
  bf16* xbf    = Wbuf;                               // 4 MB, dead after GEMM1
  bf16* w_in_t = Wbuf + (size_t)T_*IN_;              // 1 MB, dead after GEMM1
  bf16* w_up_t = w_in_t + (size_t)E_*IN_;            // 8 MB, dead after GEMM2
  bf16* w_down_t = Wbuf;                             // written AFTER pv_kernel frees Wbuf

  // 0a. convert x -> bf16 ; transpose+convert w_in, w_up
  convert_bf16<<<(T_*IN_/8+255)/256, 256, 0, stream>>>(x, xbf, T_*IN_/8);
  transpose_conv_w<<<dim3(E_/64, IN_/64), 256, 0, stream>>>(w_in, w_in_t, IN_, E_);
  transpose_conv_w<<<dim3((2*INNER_)/64, E_/64), 256, 0, stream>>>(w_up, w_up_t, E_, 2*INNER_);
  // 1. h_in = x @ w_in + b_in
  mfma_gemm<<<dim3(E_/128, T_/128), 256, 0, stream>>>(xbf, w_in_t, b_in, h_in, IN_, IN_, E_);
  // 2. xn = LN(h_in)*ln1_w
  ln_rows<bf16><<<T_, 256, 0, stream>>>(h_in, nullptr, ln1_w, xn);
  // 3. up = xn @ w_up + b_up   (x_m | z)
  mfma_gemm<<<dim3((2*INNER_)/128, T_/128), 256, 0, stream>>>(xn, w_up_t, b_up, up, E_, E_, 2*INNER_);
  // 4. x_conv_act = silu(causal_conv(x_m))
  conv_silu_kernel<<<(T_*INNER_)/256, 256, 0, stream>>>(up, conv_w, conv_b, xca);
  // 5. q,k from x_conv_act; v from x_m (block-diagonal 4x4)
  headwise_kernel<<<(T_*INNER_)/256, 256, 0, stream>>>(xca, up, q_w, q_b, k_w, k_b, v_w, v_b, qb_, kb_, vb_);
  // 6. gate pre-activations (16 tokens/block, LDS-staged weights)
  gates_kernel<<<T_/16, 256, 0, stream>>>(qb_, kb_, vb_, ig_w, ig_b, fg_w, fg_b, igbuf, fgbuf);
  // 7. scans: a, M, floor; zero rowsums
  scan8<<<B_*NH_, 256, 0, stream>>>(igbuf, fgbuf, abuf, Mbuf, flbuf, rsbuf);
  // 8. v -> vT (head-major, d-major)
  transpose_v<<<dim3(S_/64, DH_/64, B_*NH_), 256, 0, stream>>>(vb_, vTb);
  // 9. W = QK^T * scale * decay (lower triangle tiles only), rowsums
  qk_decay_kernel<<<dim3(136, 1, B_*NH_), 256, 0, stream>>>(qb_, kb_, abuf, Mbuf, rsbuf, Wbuf);
  // 10. normalizers
  norm_kernel<<<(B_*NH_*S_)/256, 256, 0, stream>>>(rsbuf, flbuf, invbuf);
  // 11. O = (W*inv) @ V   -> obuf (b,s,n*DH+d)
  pv_kernel<<<dim3(4, 16, B_*NH_), 256, 0, stream>>>(Wbuf, vTb, invbuf, obuf);
  // 12. headnorm + skip + output gate, written in place over z
  headnorm_gate<<<T_*NH_, 256, 0, stream>>>(obuf, onw, skip, xca, up);
  // 12b. transpose+convert w_down (Wbuf now dead)
  transpose_conv_w<<<dim3(E_/64, INNER_/64), 256, 0, stream>>>(w_down, w_down_t, INNER_, E_);
  // 13. y = h_gated @ w_down + b_down
  mfma_gemm<<<dim3(E_/128, T_/128), 256, 0, stream>>>(up + INNER_, w_down_t, b_down, ybuf, INNER_, 2*INNER_, E_);
  // 14. out = LN(h_in + y)*post_w
  ln_rows<float><<<T_, 256, 0, stream>>>(h_in, ybuf, post_w, (float*)d_out);
}

// Round 9
// 484.659 us; speedup vs baseline: 5.9228x; 1.0101x over previous
//
#include <hip/hip_runtime.h>
#include <hip/hip_bf16.h>

typedef __hip_bfloat16 bf16;
typedef float floatx4 __attribute__((ext_vector_type(4)));
typedef short bf16x8 __attribute__((ext_vector_type(8)));

#define B_      2
#define S_      2048
#define IN_     512
#define E_      1024
#define INNER_  2048
#define NH_     4
#define DH_     512
#define T_      (B_*S_)      // 4096 tokens
#define EPS_CELL 1e-6f
#define LN_EPS_  1e-5f
#define LS      72           // padded LDS row stride (shorts) for non-async kernels

__device__ inline float b2f(bf16 x){ return __bfloat162float(x); }
__device__ inline bf16  f2b(float x){ return __float2bfloat16(x); }
__device__ inline float us2f(unsigned short u){ union{unsigned int i; float f;} v; v.i = ((unsigned int)u)<<16; return v.f; }
__device__ inline float u2f(unsigned int u){ union{unsigned int i; float f;} v; v.i = u; return v.f; }
__device__ inline unsigned short f2bu(float x){ bf16 t = __float2bfloat16(x); unsigned short r; __builtin_memcpy(&r,&t,2); return r; }
__device__ inline void unpack8(uint4 u, float* f){
  f[0]=u2f(u.x<<16); f[1]=u2f(u.x&0xffff0000u);
  f[2]=u2f(u.y<<16); f[3]=u2f(u.y&0xffff0000u);
  f[4]=u2f(u.z<<16); f[5]=u2f(u.z&0xffff0000u);
  f[6]=u2f(u.w<<16); f[7]=u2f(u.w&0xffff0000u);
}
__device__ inline void stv(bf16* p, float v){ *p = f2b(v); }
__device__ inline void stv(float* p, float v){ *p = v; }

// ---- async 16B global->LDS copy (wave-uniform base + lane*16 pattern) ----
typedef __attribute__((address_space(3))) unsigned int lds_u32_t;
typedef __attribute__((address_space(1))) const unsigned int glb_u32_t;
__device__ __forceinline__ void cp_async16(const bf16* g, short* l){
  __builtin_amdgcn_global_load_lds((glb_u32_t*)(const void*)g,
                                   (lds_u32_t*)(void*)l, 16, 0, 0);
}
// swizzled LDS offset (shorts) for 128x64 tile: row-dense, chunk XOR row&7
__device__ __forceinline__ int so_(int row, int c8){ return row*64 + (((c8) ^ (row&7))<<3); }

// stage a 128x64-short tile (rows stride `stride` in global) into dst via async DMA
#define STAGE_ASYNC(dst, srcbase, stride, kk) \
  { int slot_ = (kk)*256 + tid; int r_ = slot_>>3; int c8_ = (slot_&7) ^ (r_&7); \
    cp_async16((srcbase) + (size_t)r_*(stride) + c8_*8, &dst[slot_*8]); }

// ---------------- fp32 -> bf16 elementwise convert ----------------
__global__ __launch_bounds__(256) void convert_bf16(const float* __restrict__ X,
    bf16* __restrict__ Y, int n8){
  int i = blockIdx.x*256 + threadIdx.x;
  if (i >= n8) return;
  const float4* p = (const float4*)(X) + i*2;
  float4 a = p[0], b = p[1];
  ushort4 o0, o1;
  o0.x=f2bu(a.x); o0.y=f2bu(a.y); o0.z=f2bu(a.z); o0.w=f2bu(a.w);
  o1.x=f2bu(b.x); o1.y=f2bu(b.y); o1.z=f2bu(b.z); o1.w=f2bu(b.w);
  ushort4* q = (ushort4*)(Y) + i*2;
  q[0]=o0; q[1]=o1;
}

// ---------------- W[K,N] fp32 -> Wt[N,K] bf16 (64x64 LDS tiles) ----------------
__global__ __launch_bounds__(256) void transpose_conv_w(const float* __restrict__ W,
    bf16* __restrict__ Wt, int K, int N){
  int n0 = blockIdx.x*64, k0 = blockIdx.y*64;
  __shared__ float tl[64][65];
  int tid = threadIdx.x;
  #pragma unroll
  for (int i=0;i<4;i++){
    int idx = tid + i*256; int r = idx>>4, c4 = idx&15;
    float4 v = *(const float4*)(W + (size_t)(k0+r)*N + n0 + c4*4);
    tl[r][c4*4+0]=v.x; tl[r][c4*4+1]=v.y; tl[r][c4*4+2]=v.z; tl[r][c4*4+3]=v.w;
  }
  __syncthreads();
  #pragma unroll
  for (int i=0;i<4;i++){
    int idx = tid + i*256; int rn = idx>>4, c4 = idx&15;
    ushort4 o;
    o.x=f2bu(tl[c4*4+0][rn]); o.y=f2bu(tl[c4*4+1][rn]);
    o.z=f2bu(tl[c4*4+2][rn]); o.w=f2bu(tl[c4*4+3][rn]);
    *(ushort4*)(Wt + (size_t)(n0+rn)*K + k0 + c4*4) = o;
  }
}

// ---------------- MFMA GEMM: C[M,N] = A[M,K] @ Bt[N,K]^T + bias ----------------
// 1-D grid MM*NN; per-XCD m-stripe swizzle: xcd gets m-blocks [xcd*MM/8, ...)
__global__ __launch_bounds__(256) void mfma_gemm(const bf16* __restrict__ A,
    const bf16* __restrict__ Bt, const float* __restrict__ bias, bf16* __restrict__ C,
    int Kd, int lda, int ldc, int NN){
  int bid = blockIdx.x;
  int MM = gridDim.x / NN;
  int mPerX = MM >> 3;
  int xcd = bid & 7, seq = bid >> 3;
  int nb = seq % NN, mb = xcd*mPerX + seq / NN;
  int n0 = nb*128, m0 = mb*128;
  __shared__ __align__(16) short As[128*64];
  __shared__ __align__(16) short Bs[128*64];
  int tid = threadIdx.x;
  int w = tid>>6, l = tid&63, lq = l>>4, lr = l&15;
  int wm = (w>>1)*64, wn = (w&1)*64;
  const bf16* Abase = A + (size_t)m0*lda;
  const bf16* Bbase = Bt + (size_t)n0*Kd;
  floatx4 acc[4][4];
  #pragma unroll
  for (int mi=0;mi<4;mi++){
    #pragma unroll
    for (int ni=0;ni<4;ni++) acc[mi][ni] = (floatx4){0.f,0.f,0.f,0.f};
  }
  for (int k0=0; k0<Kd; k0+=64){
    __syncthreads();
    #pragma unroll
    for (int kk=0;kk<4;kk++){
      STAGE_ASYNC(As, Abase + k0, lda, kk);
      STAGE_ASYNC(Bs, Bbase + k0, Kd, kk);
    }
    __syncthreads();
    #pragma unroll
    for (int ks=0; ks<2; ks++){
      bf16x8 af[4], bfr[4];
      #pragma unroll
      for (int mi=0;mi<4;mi++) af[mi] = *(const bf16x8*)&As[so_(wm+mi*16+lr, ks*4+lq)];
      #pragma unroll
      for (int ni=0;ni<4;ni++) bfr[ni] = *(const bf16x8*)&Bs[so_(wn+ni*16+lr, ks*4+lq)];
      #pragma unroll
      for (int mi=0;mi<4;mi++){
        #pragma unroll
        for (int ni=0;ni<4;ni++)
          acc[mi][ni] = __builtin_amdgcn_mfma_f32_16x16x32_bf16(af[mi], bfr[ni], acc[mi][ni], 0,0,0);
      }
    }
  }
  float bb[4];
  #pragma unroll
  for (int ni=0;ni<4;ni++) bb[ni] = bias[n0 + wn + ni*16 + lr];
  #pragma unroll
  for (int mi=0;mi<4;mi++){
    #pragma unroll
    for (int ni=0;ni<4;ni++){
      #pragma unroll
      for (int r=0;r<4;r++){
        int rowl = wm + mi*16 + lq*4 + r;
        int coll = wn + ni*16 + lr;
        C[(size_t)(m0+rowl)*ldc + n0 + coll] = f2b(acc[mi][ni][r] + bb[ni]);
      }
    }
  }
}

// ---------------- layernorm over rows of length E_ (opt. fused add) ----------------
template<typename OutT>
__global__ __launch_bounds__(256) void ln_rows(const bf16* __restrict__ X,
    const bf16* __restrict__ Xadd, const float* __restrict__ w, OutT* __restrict__ Y){
  int row = blockIdx.x, tid = threadIdx.x;
  size_t base = (size_t)row*E_;
  float vals[4], s=0.f, s2=0.f;
  #pragma unroll
  for (int e=0;e<4;e++){
    int c = e*256+tid;
    float v = b2f(X[base+c]);
    if (Xadd) v += b2f(Xadd[base+c]);
    vals[e]=v; s+=v; s2+=v*v;
  }
  __shared__ float sa[256], sb[256];
  sa[tid]=s; sb[tid]=s2; __syncthreads();
  for (int off=128; off>0; off>>=1){
    if (tid<off){ sa[tid]+=sa[tid+off]; sb[tid]+=sb[tid+off]; }
    __syncthreads();
  }
  float mean = sa[0]*(1.f/E_);
  float var  = sb[0]*(1.f/E_) - mean*mean;
  float rstd = rsqrtf(var + LN_EPS_);
  #pragma unroll
  for (int e=0;e<4;e++){
    int c = e*256+tid;
    stv(&Y[base+c], (vals[e]-mean)*rstd*w[c]);
  }
}

// ---------------- causal depthwise conv (K=4) + SiLU ----------------
__global__ __launch_bounds__(256) void conv_silu_kernel(const bf16* __restrict__ up,
    const float* __restrict__ cw, const float* __restrict__ cb, bf16* __restrict__ xca){
  size_t gid = (size_t)blockIdx.x*256 + threadIdx.x;   // over T_*INNER_
  int c = (int)(gid & (INNER_-1));
  size_t bs = gid >> 11;
  int s = (int)(bs & (S_-1));
  float acc = cb[c];
  #pragma unroll
  for (int t=0;t<4;t++){
    int sp = s-3+t;
    if (sp>=0) acc += b2f(up[(bs + (size_t)(t-3))*(size_t)(2*INNER_) + c]) * cw[c*4+t];
  }
  float sg = 1.f/(1.f+expf(-acc));
  xca[gid] = f2b(acc*sg);
}

// ---------------- block-diagonal (4x4) q/k/v projections ----------------
__global__ __launch_bounds__(256) void headwise_kernel(const bf16* __restrict__ xca,
    const bf16* __restrict__ up,
    const float* __restrict__ qw, const float* __restrict__ qb,
    const float* __restrict__ kw, const float* __restrict__ kb,
    const float* __restrict__ vw, const float* __restrict__ vb,
    bf16* __restrict__ q, bf16* __restrict__ k, bf16* __restrict__ v){
  size_t gid = (size_t)blockIdx.x*256 + threadIdx.x;
  int c = (int)(gid & (INNER_-1));
  size_t bs = gid >> 11;
  int hw = c>>2, o = c&3;
  float aq=qb[c], ak=kb[c], av=vb[c];
  size_t xb = bs*(size_t)INNER_ + (hw<<2);
  size_t mb = bs*(size_t)(2*INNER_) + (hw<<2);
  #pragma unroll
  for (int d=0; d<4; d++){
    float xc = b2f(xca[xb+d]);
    float xm = b2f(up[mb+d]);
    int wi = hw*16 + o*4 + d;   // w[h][o][d]
    aq += xc*qw[wi]; ak += xc*kw[wi]; av += xm*vw[wi];
  }
  q[gid]=f2b(aq); k[gid]=f2b(ak); v[gid]=f2b(av);
}

// ---------------- ig/fg gates: 16 tokens/block, weights staged in LDS ----------------
__global__ __launch_bounds__(256) void gates_kernel(const bf16* __restrict__ q,
    const bf16* __restrict__ k, const bf16* __restrict__ v,
    const float* __restrict__ igw, const float* __restrict__ igb,
    const float* __restrict__ fgw, const float* __restrict__ fgb,
    float* __restrict__ igo, float* __restrict__ fgo){
  __shared__ short gw[49160];   // 6144*8 + pad
  int tid = threadIdx.x;
  for (int r = tid; r < 3*INNER_; r += 256){
    float4 a = *(const float4*)(igw + (size_t)r*4);
    float4 b = *(const float4*)(fgw + (size_t)r*4);
    int slot = r ^ ((r>>3)&7);
    ushort4 o0, o1;
    o0.x=f2bu(a.x); o0.y=f2bu(a.y); o0.z=f2bu(a.z); o0.w=f2bu(a.w);
    o1.x=f2bu(b.x); o1.y=f2bu(b.y); o1.z=f2bu(b.z); o1.w=f2bu(b.w);
    *(ushort4*)&gw[slot*8]   = o0;
    *(ushort4*)&gw[slot*8+4] = o1;
  }
  __syncthreads();
  int tok = blockIdx.x*16 + (tid>>4);   // global token
  int sl  = tid & 15;
  int b = tok >> 11, s = tok & (S_-1);
  size_t rb = (size_t)tok * INNER_;
  const bf16* srcs[3] = {q + rb, k + rb, v + rb};
  float acc[8];
  #pragma unroll
  for (int n=0;n<8;n++) acc[n]=0.f;
  #pragma unroll
  for (int src=0; src<3; src++){
    const bf16* ptr = srcs[src];
    int kb = src*INNER_;
    #pragma unroll 4
    for (int j=0; j<16; j++){
      int pos = j*128 + sl*8;
      uint4 dv = *(const uint4*)(ptr + pos);
      float d[8]; unpack8(dv, d);
      int rbase = kb + pos;                 // multiple of 8
      int cxor = (rbase>>3)&7;              // constant over e within the group
      #pragma unroll
      for (int e=0;e<8;e++){
        int slot = (rbase + e) ^ cxor;
        uint4 wv = *(const uint4*)&gw[slot*8];
        float w8[8]; unpack8(wv, w8);
        #pragma unroll
        for (int n=0;n<8;n++) acc[n] += d[e]*w8[n];
      }
    }
  }
  #pragma unroll
  for (int off=1; off<16; off<<=1){
    #pragma unroll
    for (int n=0;n<8;n++) acc[n] += __shfl_xor(acc[n], off, 16);
  }
  if (sl < 8){
    int n = sl & 3;
    if (sl < 4) igo[((size_t)(b*NH_+n))*S_ + s] = acc[sl] + igb[n];
    else        fgo[((size_t)(b*NH_+n))*S_ + s] = acc[sl] + fgb[n];
  }
}

// ---------------- per-head scan: F=cumsum(logsigmoid(fg)); a=ig-F; M=prefmax(a) ----
__global__ __launch_bounds__(256) void scan8(const float* __restrict__ igp,
    const float* __restrict__ fgp, float* __restrict__ ap,
    float* __restrict__ Mp, float* __restrict__ flp, float* __restrict__ rowsum){
  int h = blockIdx.x, tid = threadIdx.x;
  const float* fg = fgp + (size_t)h*S_;
  const float* ig = igp + (size_t)h*S_;
  int base = tid*8;
  float loc[8], run = 0.f;
  #pragma unroll
  for (int e=0;e<8;e++){
    float x = fg[base+e];
    float ls = fminf(x,0.f) - log1pf(expf(-fabsf(x)));
    run += ls; loc[e] = run;
  }
  __shared__ float sd[256];
  sd[tid]=run; __syncthreads();
  if (tid==0){ float r=0.f; for(int t=0;t<256;t++){ float t0=sd[t]; sd[t]=r; r+=t0; } }
  __syncthreads();
  float off = sd[tid];
  float lm[8], rm = -3e38f;
  #pragma unroll
  for (int e=0;e<8;e++){
    float F = loc[e]+off; loc[e]=F;
    float aj = ig[base+e]-F;
    ap[(size_t)h*S_+base+e]=aj;
    rm = fmaxf(rm, aj); lm[e]=rm;
  }
  __syncthreads();
  sd[tid]=rm; __syncthreads();
  if (tid==0){ float r=-3e38f; for(int t=0;t<256;t++){ float t0=sd[t]; sd[t]=r; r=fmaxf(r,t0); } }
  __syncthreads();
  float offm = sd[tid];
  #pragma unroll
  for (int e=0;e<8;e++){
    float M = fmaxf(lm[e], offm);
    Mp[(size_t)h*S_+base+e]=M;
    flp[(size_t)h*S_+base+e]=expf(-loc[e]-M);
    rowsum[(size_t)h*S_+base+e]=0.f;
  }
}

// ---------------- v (b,s,n*DH+d) -> vT (h, d, s) ----------------
__global__ __launch_bounds__(256) void transpose_v(const bf16* __restrict__ v,
    bf16* __restrict__ vT){
  int sb = blockIdx.x, db = blockIdx.y, h = blockIdx.z;
  int b = h >> 2, n = h & 3;
  int s0 = sb*64, d0 = db*64;
  __shared__ short tl[64*LS];
  int tid = threadIdx.x;
  #pragma unroll
  for (int i=0;i<2;i++){
    int vv = tid + i*256; int r = vv>>3, c8 = vv&7;
    uint4 x = *(const uint4*)(v + (size_t)(b*S_+s0+r)*INNER_ + n*DH_ + d0 + c8*8);
    *(uint4*)&tl[r*LS + c8*8] = x;
  }
  __syncthreads();
  #pragma unroll
  for (int i=0;i<2;i++){
    int vv = tid + i*256; int r = vv>>3, c8 = vv&7;   // r = local d, c8 = s-chunk
    unsigned short tmp[8];
    #pragma unroll
    for (int e=0;e<8;e++) tmp[e] = (unsigned short)tl[(c8*8+e)*LS + r];
    uint4 o; __builtin_memcpy(&o, tmp, 16);
    *(uint4*)(vT + ((size_t)h*DH_ + d0 + r)*S_ + s0 + c8*8) = o;
  }
}

// ---------------- W = (Q K^T)*scale*exp(a_j - M_i), causal; + rowsums ----------------
// 1-D grid 8*136; h = bid&7 (XCD-pinned), tt = 135 - bid>>3 (big ti first)
__global__ __launch_bounds__(256) void qk_decay_kernel(const bf16* __restrict__ qg,
    const bf16* __restrict__ kg, const float* __restrict__ ap,
    const float* __restrict__ Mp, float* __restrict__ rowsum, bf16* __restrict__ W){
  int h = blockIdx.x & 7;
  int tt = 135 - (blockIdx.x >> 3);
  int ti = (int)((sqrtf(8.f*tt+1.f)-1.f)*0.5f);
  if ((ti+1)*(ti+2)/2 <= tt) ti++;
  if (ti*(ti+1)/2 > tt) ti--;
  int tj = tt - ti*(ti+1)/2;
  int b = h >> 2, n = h & 3;
  int i0 = ti*128, j0 = tj*128;
  __shared__ __align__(16) short Qs[128*64];
  __shared__ __align__(16) short Ks[128*64];
  __shared__ float a_s[128], m_s[128];
  int tid = threadIdx.x;
  if (tid < 128){
    a_s[tid] = ap[(size_t)h*S_ + j0 + tid];
    m_s[tid] = Mp[(size_t)h*S_ + i0 + tid];
  }
  int w = tid>>6, l = tid&63, lq = l>>4, lr = l&15;
  int wm = (w>>1)*64, wn = (w&1)*64;
  const bf16* Qbase = qg + (size_t)(b*S_+i0)*INNER_ + n*DH_;
  const bf16* Kbase = kg + (size_t)(b*S_+j0)*INNER_ + n*DH_;
  floatx4 acc[4][4];
  #pragma unroll
  for (int mi=0;mi<4;mi++){
    #pragma unroll
    for (int ni=0;ni<4;ni++) acc[mi][ni] = (floatx4){0.f,0.f,0.f,0.f};
  }
  for (int d0=0; d0<DH_; d0+=64){
    __syncthreads();
    #pragma unroll
    for (int kk=0;kk<4;kk++){
      STAGE_ASYNC(Qs, Qbase + d0, INNER_, kk);
      STAGE_ASYNC(Ks, Kbase + d0, INNER_, kk);
    }
    __syncthreads();
    #pragma unroll
    for (int ks=0; ks<2; ks++){
      bf16x8 af[4], bfr[4];
      #pragma unroll
      for (int mi=0;mi<4;mi++) af[mi] = *(const bf16x8*)&Qs[so_(wm+mi*16+lr, ks*4+lq)];
      #pragma unroll
      for (int ni=0;ni<4;ni++) bfr[ni] = *(const bf16x8*)&Ks[so_(wn+ni*16+lr, ks*4+lq)];
      #pragma unroll
      for (int mi=0;mi<4;mi++){
        #pragma unroll
        for (int ni=0;ni<4;ni++)
          acc[mi][ni] = __builtin_amdgcn_mfma_f32_16x16x32_bf16(af[mi], bfr[ni], acc[mi][ni], 0,0,0);
      }
    }
  }
  const float scale = 0.04419417382415922f;   // 1/sqrt(512)
  float rpart[4][4];
  #pragma unroll
  for (int mi=0;mi<4;mi++){
    #pragma unroll
    for (int r=0;r<4;r++) rpart[mi][r]=0.f;
  }
  #pragma unroll
  for (int mi=0;mi<4;mi++){
    #pragma unroll
    for (int ni=0;ni<4;ni++){
      #pragma unroll
      for (int r=0;r<4;r++){
        int rowl = wm + mi*16 + lq*4 + r;
        int coll = wn + ni*16 + lr;
        int gi = i0 + rowl, gj = j0 + coll;
        float wv = 0.f;
        if (gj <= gi) wv = acc[mi][ni][r]*scale*__expf(a_s[coll]-m_s[rowl]);
        W[((size_t)h*S_ + gi)*S_ + gj] = f2b(wv);
        rpart[mi][r] += wv;
      }
    }
  }
  #pragma unroll
  for (int mi=0;mi<4;mi++){
    #pragma unroll
    for (int r=0;r<4;r++){
      float v = rpart[mi][r];
      v += __shfl_xor(v, 1, 16);
      v += __shfl_xor(v, 2, 16);
      v += __shfl_xor(v, 4, 16);
      v += __shfl_xor(v, 8, 16);
      if (lr == 0)
        atomicAdd(&rowsum[(size_t)h*S_ + i0 + wm + mi*16 + lq*4 + r], v);
    }
  }
}

// ---------------- O = (W * inv_row) @ V  (causal k-range), inv fused ----------------
// 1-D grid 8*64; h = bid&7 (XCD-pinned); s = bid>>3: ti = 15-(s>>2), tn = s&3
// -> the 4 d-chunk blocks of one i-tile are adjacent per-XCD (share W via L2)
__global__ __launch_bounds__(256) void pv_kernel(const bf16* __restrict__ W,
    const bf16* __restrict__ vT, const float* __restrict__ rowsum,
    const float* __restrict__ fl, bf16* __restrict__ O){
  int h = blockIdx.x & 7;
  int s = blockIdx.x >> 3;
  int ti = 15 - (s >> 2), tn = s & 3;
  int b = h >> 2, n = h & 3;
  int i0 = ti*128, d0 = tn*128;
  __shared__ __align__(16) short Ws[128*64];
  __shared__ __align__(16) short Vs[128*64];
  __shared__ float inv_s[128];
  int tid = threadIdx.x;
  if (tid < 128){
    size_t o = (size_t)h*S_ + i0 + tid;
    inv_s[tid] = 1.f/(fmaxf(fabsf(rowsum[o]), fl[o]) + EPS_CELL);
  }
  int w = tid>>6, l = tid&63, lq = l>>4, lr = l&15;
  int wm = (w>>1)*64, wn = (w&1)*64;
  const bf16* Wbase = W + ((size_t)h*S_ + i0)*S_;
  const bf16* Vbase = vT + ((size_t)h*DH_ + d0)*S_;
  floatx4 acc[4][4];
  #pragma unroll
  for (int mi=0;mi<4;mi++){
    #pragma unroll
    for (int ni=0;ni<4;ni++) acc[mi][ni] = (floatx4){0.f,0.f,0.f,0.f};
  }
  int jmax = i0 + 128;
  for (int j0=0; j0<jmax; j0+=64){
    __syncthreads();
    #pragma unroll
    for (int kk=0;kk<4;kk++){
      STAGE_ASYNC(Ws, Wbase + j0, S_, kk);
      STAGE_ASYNC(Vs, Vbase + j0, S_, kk);
    }
    __syncthreads();
    #pragma unroll
    for (int ks=0; ks<2; ks++){
      bf16x8 af[4], bfr[4];
      #pragma unroll
      for (int mi=0;mi<4;mi++) af[mi] = *(const bf16x8*)&Ws[so_(wm+mi*16+lr, ks*4+lq)];
      #pragma unroll
      for (int ni=0;ni<4;ni++) bfr[ni] = *(const bf16x8*)&Vs[so_(wn+ni*16+lr, ks*4+lq)];
      #pragma unroll
      for (int mi=0;mi<4;mi++){
        #pragma unroll
        for (int ni=0;ni<4;ni++)
          acc[mi][ni] = __builtin_amdgcn_mfma_f32_16x16x32_bf16(af[mi], bfr[ni], acc[mi][ni], 0,0,0);
      }
    }
  }
  #pragma unroll
  for (int mi=0;mi<4;mi++){
    #pragma unroll
    for (int ni=0;ni<4;ni++){
      #pragma unroll
      for (int r=0;r<4;r++){
        int rowl = wm + mi*16 + lq*4 + r;
        int dl = wn + ni*16 + lr;
        float o = acc[mi][ni][r] * inv_s[rowl];
        O[(size_t)(b*S_ + i0 + rowl)*INNER_ + n*DH_ + d0 + dl] = f2b(o);
      }
    }
  }
}

// ---------------- head groupnorm + skip + output gate (in-place into z) ----------
__global__ __launch_bounds__(256) void headnorm_gate(const bf16* __restrict__ h,
    const float* __restrict__ onw, const float* __restrict__ skip,
    const bf16* __restrict__ xca, bf16* __restrict__ up){
  int bid = blockIdx.x;
  int n = bid & 3; int bs = bid >> 2;
  int tid = threadIdx.x;
  size_t hbase = (size_t)bs*INNER_ + n*DH_;
  float v0 = b2f(h[hbase+tid]);
  float v1 = b2f(h[hbase+256+tid]);
  __shared__ float sa[256], sb[256];
  sa[tid]=v0+v1; sb[tid]=v0*v0+v1*v1;
  __syncthreads();
  for (int off=128; off>0; off>>=1){
    if (tid<off){ sa[tid]+=sa[tid+off]; sb[tid]+=sb[tid+off]; }
    __syncthreads();
  }
  float mean = sa[0]*(1.f/DH_);
  float var  = sb[0]*(1.f/DH_) - mean*mean;
  float rstd = rsqrtf(var + LN_EPS_);
  #pragma unroll
  for (int e=0;e<2;e++){
    int dl = e*256+tid; int c = n*DH_+dl;
    float hv = e ? v1 : v0;
    float hn = (hv-mean)*rstd*onw[c];
    float hs = hn + skip[c]*b2f(xca[(size_t)bs*INNER_+c]);
    size_t zoff = (size_t)bs*(2*INNER_) + INNER_ + c;
    float zv = b2f(up[zoff]);
    float sz = zv/(1.f+expf(-zv));
    up[zoff] = f2b(hs*sz);
  }
}

extern "C" void kernel_launch(void* const* d_in, const int* in_sizes, int n_in,
                              void* d_out, int out_size, void* d_ws, size_t ws_size,
                              hipStream_t stream) {
  const float* x      = (const float*)d_in[0];
  const float* w_in   = (const float*)d_in[1];
  const float* b_in   = (const float*)d_in[2];
  const float* ln1_w  = (const float*)d_in[3];
  const float* w_up   = (const float*)d_in[4];
  const float* b_up   = (const float*)d_in[5];
  const float* conv_w = (const float*)d_in[6];
  const float* conv_b = (const float*)d_in[7];
  const float* q_w    = (const float*)d_in[8];
  const float* q_b    = (const float*)d_in[9];
  const float* k_w    = (const float*)d_in[10];
  const float* k_b    = (const float*)d_in[11];
  const float* v_w    = (const float*)d_in[12];
  const float* v_b    = (const float*)d_in[13];
  const float* ig_w   = (const float*)d_in[14];
  const float* ig_b   = (const float*)d_in[15];
  const float* fg_w   = (const float*)d_in[16];
  const float* fg_b   = (const float*)d_in[17];
  const float* onw    = (const float*)d_in[18];
  const float* skip   = (const float*)d_in[19];
  const float* w_down = (const float*)d_in[20];
  const float* b_down = (const float*)d_in[21];
  const float* post_w = (const float*)d_in[22];

  char* p = (char*)d_ws;
  auto alloc = [&](size_t bytes)->void*{ void* r = p; p += (bytes + 255) & ~(size_t)255; return r; };
  bf16* h_in = (bf16*)alloc((size_t)T_*E_*2);        // 8 MB
  bf16* xn   = (bf16*)alloc((size_t)T_*E_*2);        // 8 MB (reused as y later)
  bf16* up   = (bf16*)alloc((size_t)T_*2*INNER_*2);  // 32 MB (x_m | z; z later holds h_gated)
  bf16* xca  = (bf16*)alloc((size_t)T_*INNER_*2);    // 16 MB
  bf16* qb_  = (bf16*)alloc((size_t)T_*INNER_*2);
  bf16* kb_  = (bf16*)alloc((size_t)T_*INNER_*2);
  bf16* vb_  = (bf16*)alloc((size_t)T_*INNER_*2);    // v; later reused as attention O
  bf16* hb_  = (bf16*)alloc((size_t)T_*INNER_*2);    // reused as vT (h,d,s)
  float* igbuf = (float*)alloc((size_t)B_*NH_*S_*4);
  float* fgbuf = (float*)alloc((size_t)B_*NH_*S_*4);
  float* abuf  = (float*)alloc((size_t)B_*NH_*S_*4);
  float* Mbuf  = (float*)alloc((size_t)B_*NH_*S_*4);
  float* flbuf = (float*)alloc((size_t)B_*NH_*S_*4);
  float* rsbuf = (float*)alloc((size_t)B_*NH_*S_*4);
  bf16* Wbuf = (bf16*)alloc((size_t)B_*NH_*S_*S_*2); // 67 MB decay-weighted scores
  bf16* ybuf = xn;   // xn dead after up-projection
  bf16* vTb  = hb_;
  bf16* obuf = vb_;
  // converted-weight scratch overlapping Wbuf (dead until qk_decay / after pv)
  bf16* xbf    = Wbuf;                               // 4 MB, dead after GEMM1
  bf16* w_in_t = Wbuf + (size_t)T_*IN_;              // 1 MB, dead after GEMM1
  bf16* w_up_t = w_in_t + (size_t)E_*IN_;            // 8 MB, dead after GEMM2
  bf16* w_down_t = Wbuf;                             // written AFTER pv_kernel frees Wbuf

  // 0a. convert x -> bf16 ; transpose+convert w_in, w_up
  convert_bf16<<<(T_*IN_/8+255)/256, 256, 0, stream>>>(x, xbf, T_*IN_/8);
  transpose_conv_w<<<dim3(E_/64, IN_/64), 256, 0, stream>>>(w_in, w_in_t, IN_, E_);
  transpose_conv_w<<<dim3((2*INNER_)/64, E_/64), 256, 0, stream>>>(w_up, w_up_t, E_, 2*INNER_);
  // 1. h_in = x @ w_in + b_in     (MM=32, NN=8)
  mfma_gemm<<<(T_/128)*(E_/128), 256, 0, stream>>>(xbf, w_in_t, b_in, h_in, IN_, IN_, E_, E_/128);
  // 2. xn = LN(h_in)*ln1_w
  ln_rows<bf16><<<T_, 256, 0, stream>>>(h_in, nullptr, ln1_w, xn);
  // 3. up = xn @ w_up + b_up   (x_m | z)  (MM=32, NN=32)
  mfma_gemm<<<(T_/128)*((2*INNER_)/128), 256, 0, stream>>>(xn, w_up_t, b_up, up, E_, E_, 2*INNER_, (2*INNER_)/128);
  // 4. x_conv_act = silu(causal_conv(x_m))
  conv_silu_kernel<<<(T_*INNER_)/256, 256, 0, stream>>>(up, conv_w, conv_b, xca);
  // 5. q,k from x_conv_act; v from x_m (block-diagonal 4x4)
  headwise_kernel<<<(T_*INNER_)/256, 256, 0, stream>>>(xca, up, q_w, q_b, k_w, k_b, v_w, v_b, qb_, kb_, vb_);
  // 6. gate pre-activations (16 tokens/block, LDS-staged weights)
  gates_kernel<<<T_/16, 256, 0, stream>>>(qb_, kb_, vb_, ig_w, ig_b, fg_w, fg_b, igbuf, fgbuf);
  // 7. scans: a, M, floor; zero rowsums
  scan8<<<B_*NH_, 256, 0, stream>>>(igbuf, fgbuf, abuf, Mbuf, flbuf, rsbuf);
  // 8. v -> vT (head-major, d-major)
  transpose_v<<<dim3(S_/64, DH_/64, B_*NH_), 256, 0, stream>>>(vb_, vTb);
  // 9. W = QK^T * scale * decay (lower triangle tiles, head XCD-pinned), rowsums
  qk_decay_kernel<<<8*136, 256, 0, stream>>>(qb_, kb_, abuf, Mbuf, rsbuf, Wbuf);
  // 10. O = (W*inv) @ V -> obuf (b,s,n*DH+d); inv fused, head XCD-pinned
  pv_kernel<<<8*64, 256, 0, stream>>>(Wbuf, vTb, rsbuf, flbuf, obuf);
  // 11. headnorm + skip + output gate, written in place over z
  headnorm_gate<<<T_*NH_, 256, 0, stream>>>(obuf, onw, skip, xca, up);
  // 11b. transpose+convert w_down (Wbuf now dead)
  transpose_conv_w<<<dim3(E_/64, INNER_/64), 256, 0, stream>>>(w_down, w_down_t, INNER_, E_);
  // 12. y = h_gated @ w_down + b_down  (MM=32, NN=8)
  mfma_gemm<<<(T_/128)*(E_/128), 256, 0, stream>>>(up + INNER_, w_down_t, b_down, ybuf, INNER_, 2*INNER_, E_, E_/128);
  // 13. out = LN(h_in + y)*post_w
  ln_rows<float><<<T_, 256, 0, stream>>>(h_in, ybuf, post_w, (float*)d_out);
}

// Round 10
// 465.348 us; speedup vs baseline: 6.1686x; 1.0415x over previous
//
#include <hip/hip_runtime.h>
#include <hip/hip_bf16.h>

typedef __hip_bfloat16 bf16;
typedef float floatx4 __attribute__((ext_vector_type(4)));
typedef short bf16x8 __attribute__((ext_vector_type(8)));

#define B_      2
#define S_      2048
#define IN_     512
#define E_      1024
#define INNER_  2048
#define NH_     4
#define DH_     512
#define T_      (B_*S_)      // 4096 tokens
#define EPS_CELL 1e-6f
#define LN_EPS_  1e-5f
#define LS      72           // padded LDS row stride (shorts) for non-async kernels

__device__ inline float b2f(bf16 x){ return __bfloat162float(x); }
__device__ inline bf16  f2b(float x){ return __float2bfloat16(x); }
__device__ inline float us2f(unsigned short u){ union{unsigned int i; float f;} v; v.i = ((unsigned int)u)<<16; return v.f; }
__device__ inline float u2f(unsigned int u){ union{unsigned int i; float f;} v; v.i = u; return v.f; }
__device__ inline unsigned short f2bu(float x){ bf16 t = __float2bfloat16(x); unsigned short r; __builtin_memcpy(&r,&t,2); return r; }
__device__ inline void unpack8(uint4 u, float* f){
  f[0]=u2f(u.x<<16); f[1]=u2f(u.x&0xffff0000u);
  f[2]=u2f(u.y<<16); f[3]=u2f(u.y&0xffff0000u);
  f[4]=u2f(u.z<<16); f[5]=u2f(u.z&0xffff0000u);
  f[6]=u2f(u.w<<16); f[7]=u2f(u.w&0xffff0000u);
}
__device__ inline void stv(bf16* p, float v){ *p = f2b(v); }
__device__ inline void stv(float* p, float v){ *p = v; }

// ---- async 16B global->LDS copy (wave-uniform base + lane*16 pattern) ----
typedef __attribute__((address_space(3))) unsigned int lds_u32_t;
typedef __attribute__((address_space(1))) const unsigned int glb_u32_t;
__device__ __forceinline__ void cp_async16(const bf16* g, short* l){
  __builtin_amdgcn_global_load_lds((glb_u32_t*)(const void*)g,
                                   (lds_u32_t*)(void*)l, 16, 0, 0);
}
// swizzled LDS offset (shorts) for Nx64 tile: row-dense, chunk XOR row&7
__device__ __forceinline__ int so_(int row, int c8){ return row*64 + (((c8) ^ (row&7))<<3); }

// stage rows of a {64,128}x64-short tile (row stride `stride` in global)
#define STAGE_ASYNC(dst, srcbase, stride, kk) \
  { int slot_ = (kk)*256 + tid; int r_ = slot_>>3; int c8_ = (slot_&7) ^ (r_&7); \
    cp_async16((srcbase) + (size_t)r_*(stride) + c8_*8, &dst[slot_*8]); }

// ---------------- fp32 -> bf16 elementwise convert ----------------
__global__ __launch_bounds__(256) void convert_bf16(const float* __restrict__ X,
    bf16* __restrict__ Y, int n8){
  int i = blockIdx.x*256 + threadIdx.x;
  if (i >= n8) return;
  const float4* p = (const float4*)(X) + i*2;
  float4 a = p[0], b = p[1];
  ushort4 o0, o1;
  o0.x=f2bu(a.x); o0.y=f2bu(a.y); o0.z=f2bu(a.z); o0.w=f2bu(a.w);
  o1.x=f2bu(b.x); o1.y=f2bu(b.y); o1.z=f2bu(b.z); o1.w=f2bu(b.w);
  ushort4* q = (ushort4*)(Y) + i*2;
  q[0]=o0; q[1]=o1;
}

// ---------------- W[K,N] fp32 -> Wt[N,K] bf16 (64x64 LDS tiles) ----------------
__global__ __launch_bounds__(256) void transpose_conv_w(const float* __restrict__ W,
    bf16* __restrict__ Wt, int K, int N){
  int n0 = blockIdx.x*64, k0 = blockIdx.y*64;
  __shared__ float tl[64][65];
  int tid = threadIdx.x;
  #pragma unroll
  for (int i=0;i<4;i++){
    int idx = tid + i*256; int r = idx>>4, c4 = idx&15;
    float4 v = *(const float4*)(W + (size_t)(k0+r)*N + n0 + c4*4);
    tl[r][c4*4+0]=v.x; tl[r][c4*4+1]=v.y; tl[r][c4*4+2]=v.z; tl[r][c4*4+3]=v.w;
  }
  __syncthreads();
  #pragma unroll
  for (int i=0;i<4;i++){
    int idx = tid + i*256; int rn = idx>>4, c4 = idx&15;
    ushort4 o;
    o.x=f2bu(tl[c4*4+0][rn]); o.y=f2bu(tl[c4*4+1][rn]);
    o.z=f2bu(tl[c4*4+2][rn]); o.w=f2bu(tl[c4*4+3][rn]);
    *(ushort4*)(Wt + (size_t)(n0+rn)*K + k0 + c4*4) = o;
  }
}

// ---------------- MFMA GEMM: C[M,N] = A[M,K] @ Bt[N,K]^T + bias ----------------
// 1-D grid MM*NN; per-XCD m-stripe swizzle: xcd gets m-blocks [xcd*MM/8, ...)
__global__ __launch_bounds__(256) void mfma_gemm(const bf16* __restrict__ A,
    const bf16* __restrict__ Bt, const float* __restrict__ bias, bf16* __restrict__ C,
    int Kd, int lda, int ldc, int NN){
  int bid = blockIdx.x;
  int MM = gridDim.x / NN;
  int mPerX = MM >> 3;
  int xcd = bid & 7, seq = bid >> 3;
  int nb = seq % NN, mb = xcd*mPerX + seq / NN;
  int n0 = nb*128, m0 = mb*128;
  __shared__ __align__(16) short As[128*64];
  __shared__ __align__(16) short Bs[128*64];
  int tid = threadIdx.x;
  int w = tid>>6, l = tid&63, lq = l>>4, lr = l&15;
  int wm = (w>>1)*64, wn = (w&1)*64;
  const bf16* Abase = A + (size_t)m0*lda;
  const bf16* Bbase = Bt + (size_t)n0*Kd;
  floatx4 acc[4][4];
  #pragma unroll
  for (int mi=0;mi<4;mi++){
    #pragma unroll
    for (int ni=0;ni<4;ni++) acc[mi][ni] = (floatx4){0.f,0.f,0.f,0.f};
  }
  for (int k0=0; k0<Kd; k0+=64){
    __syncthreads();
    #pragma unroll
    for (int kk=0;kk<4;kk++){
      STAGE_ASYNC(As, Abase + k0, lda, kk);
      STAGE_ASYNC(Bs, Bbase + k0, Kd, kk);
    }
    __syncthreads();
    #pragma unroll
    for (int ks=0; ks<2; ks++){
      bf16x8 af[4], bfr[4];
      #pragma unroll
      for (int mi=0;mi<4;mi++) af[mi] = *(const bf16x8*)&As[so_(wm+mi*16+lr, ks*4+lq)];
      #pragma unroll
      for (int ni=0;ni<4;ni++) bfr[ni] = *(const bf16x8*)&Bs[so_(wn+ni*16+lr, ks*4+lq)];
      #pragma unroll
      for (int mi=0;mi<4;mi++){
        #pragma unroll
        for (int ni=0;ni<4;ni++)
          acc[mi][ni] = __builtin_amdgcn_mfma_f32_16x16x32_bf16(af[mi], bfr[ni], acc[mi][ni], 0,0,0);
      }
    }
  }
  float bb[4];
  #pragma unroll
  for (int ni=0;ni<4;ni++) bb[ni] = bias[n0 + wn + ni*16 + lr];
  #pragma unroll
  for (int mi=0;mi<4;mi++){
    #pragma unroll
    for (int ni=0;ni<4;ni++){
      #pragma unroll
      for (int r=0;r<4;r++){
        int rowl = wm + mi*16 + lq*4 + r;
        int coll = wn + ni*16 + lr;
        C[(size_t)(m0+rowl)*ldc + n0 + coll] = f2b(acc[mi][ni][r] + bb[ni]);
      }
    }
  }
}

// ---------------- layernorm over rows of length E_ (opt. fused add) ----------------
template<typename OutT>
__global__ __launch_bounds__(256) void ln_rows(const bf16* __restrict__ X,
    const bf16* __restrict__ Xadd, const float* __restrict__ w, OutT* __restrict__ Y){
  int row = blockIdx.x, tid = threadIdx.x;
  size_t base = (size_t)row*E_;
  float vals[4], s=0.f, s2=0.f;
  #pragma unroll
  for (int e=0;e<4;e++){
    int c = e*256+tid;
    float v = b2f(X[base+c]);
    if (Xadd) v += b2f(Xadd[base+c]);
    vals[e]=v; s+=v; s2+=v*v;
  }
  __shared__ float sa[256], sb[256];
  sa[tid]=s; sb[tid]=s2; __syncthreads();
  for (int off=128; off>0; off>>=1){
    if (tid<off){ sa[tid]+=sa[tid+off]; sb[tid]+=sb[tid+off]; }
    __syncthreads();
  }
  float mean = sa[0]*(1.f/E_);
  float var  = sb[0]*(1.f/E_) - mean*mean;
  float rstd = rsqrtf(var + LN_EPS_);
  #pragma unroll
  for (int e=0;e<4;e++){
    int c = e*256+tid;
    stv(&Y[base+c], (vals[e]-mean)*rstd*w[c]);
  }
}

// ---------------- causal depthwise conv (K=4) + SiLU ----------------
__global__ __launch_bounds__(256) void conv_silu_kernel(const bf16* __restrict__ up,
    const float* __restrict__ cw, const float* __restrict__ cb, bf16* __restrict__ xca){
  size_t gid = (size_t)blockIdx.x*256 + threadIdx.x;   // over T_*INNER_
  int c = (int)(gid & (INNER_-1));
  size_t bs = gid >> 11;
  int s = (int)(bs & (S_-1));
  float acc = cb[c];
  #pragma unroll
  for (int t=0;t<4;t++){
    int sp = s-3+t;
    if (sp>=0) acc += b2f(up[(bs + (size_t)(t-3))*(size_t)(2*INNER_) + c]) * cw[c*4+t];
  }
  float sg = 1.f/(1.f+expf(-acc));
  xca[gid] = f2b(acc*sg);
}

// ---------------- block-diagonal (4x4) q/k/v projections ----------------
__global__ __launch_bounds__(256) void headwise_kernel(const bf16* __restrict__ xca,
    const bf16* __restrict__ up,
    const float* __restrict__ qw, const float* __restrict__ qb,
    const float* __restrict__ kw, const float* __restrict__ kb,
    const float* __restrict__ vw, const float* __restrict__ vb,
    bf16* __restrict__ q, bf16* __restrict__ k, bf16* __restrict__ v){
  size_t gid = (size_t)blockIdx.x*256 + threadIdx.x;
  int c = (int)(gid & (INNER_-1));
  size_t bs = gid >> 11;
  int hw = c>>2, o = c&3;
  float aq=qb[c], ak=kb[c], av=vb[c];
  size_t xb = bs*(size_t)INNER_ + (hw<<2);
  size_t mb = bs*(size_t)(2*INNER_) + (hw<<2);
  #pragma unroll
  for (int d=0; d<4; d++){
    float xc = b2f(xca[xb+d]);
    float xm = b2f(up[mb+d]);
    int wi = hw*16 + o*4 + d;   // w[h][o][d]
    aq += xc*qw[wi]; ak += xc*kw[wi]; av += xm*vw[wi];
  }
  q[gid]=f2b(aq); k[gid]=f2b(ak); v[gid]=f2b(av);
}

// ---------------- ig/fg gates: 16 tokens/block, weights staged in LDS ----------------
__global__ __launch_bounds__(256) void gates_kernel(const bf16* __restrict__ q,
    const bf16* __restrict__ k, const bf16* __restrict__ v,
    const float* __restrict__ igw, const float* __restrict__ igb,
    const float* __restrict__ fgw, const float* __restrict__ fgb,
    float* __restrict__ igo, float* __restrict__ fgo){
  __shared__ short gw[49160];   // 6144*8 + pad
  int tid = threadIdx.x;
  for (int r = tid; r < 3*INNER_; r += 256){
    float4 a = *(const float4*)(igw + (size_t)r*4);
    float4 b = *(const float4*)(fgw + (size_t)r*4);
    int slot = r ^ ((r>>3)&7);
    ushort4 o0, o1;
    o0.x=f2bu(a.x); o0.y=f2bu(a.y); o0.z=f2bu(a.z); o0.w=f2bu(a.w);
    o1.x=f2bu(b.x); o1.y=f2bu(b.y); o1.z=f2bu(b.z); o1.w=f2bu(b.w);
    *(ushort4*)&gw[slot*8]   = o0;
    *(ushort4*)&gw[slot*8+4] = o1;
  }
  __syncthreads();
  int tok = blockIdx.x*16 + (tid>>4);   // global token
  int sl  = tid & 15;
  int b = tok >> 11, s = tok & (S_-1);
  size_t rb = (size_t)tok * INNER_;
  const bf16* srcs[3] = {q + rb, k + rb, v + rb};
  float acc[8];
  #pragma unroll
  for (int n=0;n<8;n++) acc[n]=0.f;
  #pragma unroll
  for (int src=0; src<3; src++){
    const bf16* ptr = srcs[src];
    int kb = src*INNER_;
    #pragma unroll 4
    for (int j=0; j<16; j++){
      int pos = j*128 + sl*8;
      uint4 dv = *(const uint4*)(ptr + pos);
      float d[8]; unpack8(dv, d);
      int rbase = kb + pos;                 // multiple of 8
      int cxor = (rbase>>3)&7;              // constant over e within the group
      #pragma unroll
      for (int e=0;e<8;e++){
        int slot = (rbase + e) ^ cxor;
        uint4 wv = *(const uint4*)&gw[slot*8];
        float w8[8]; unpack8(wv, w8);
        #pragma unroll
        for (int n=0;n<8;n++) acc[n] += d[e]*w8[n];
      }
    }
  }
  #pragma unroll
  for (int off=1; off<16; off<<=1){
    #pragma unroll
    for (int n=0;n<8;n++) acc[n] += __shfl_xor(acc[n], off, 16);
  }
  if (sl < 8){
    int n = sl & 3;
    if (sl < 4) igo[((size_t)(b*NH_+n))*S_ + s] = acc[sl] + igb[n];
    else        fgo[((size_t)(b*NH_+n))*S_ + s] = acc[sl] + fgb[n];
  }
}

// ---------------- per-head scan: F=cumsum(logsigmoid(fg)); a=ig-F; M=prefmax(a) ----
__global__ __launch_bounds__(256) void scan8(const float* __restrict__ igp,
    const float* __restrict__ fgp, float* __restrict__ ap,
    float* __restrict__ Mp, float* __restrict__ flp, float* __restrict__ rowsum){
  int h = blockIdx.x, tid = threadIdx.x;
  const float* fg = fgp + (size_t)h*S_;
  const float* ig = igp + (size_t)h*S_;
  int base = tid*8;
  float loc[8], run = 0.f;
  #pragma unroll
  for (int e=0;e<8;e++){
    float x = fg[base+e];
    float ls = fminf(x,0.f) - log1pf(expf(-fabsf(x)));
    run += ls; loc[e] = run;
  }
  __shared__ float sd[256];
  sd[tid]=run; __syncthreads();
  if (tid==0){ float r=0.f; for(int t=0;t<256;t++){ float t0=sd[t]; sd[t]=r; r+=t0; } }
  __syncthreads();
  float off = sd[tid];
  float lm[8], rm = -3e38f;
  #pragma unroll
  for (int e=0;e<8;e++){
    float F = loc[e]+off; loc[e]=F;
    float aj = ig[base+e]-F;
    ap[(size_t)h*S_+base+e]=aj;
    rm = fmaxf(rm, aj); lm[e]=rm;
  }
  __syncthreads();
  sd[tid]=rm; __syncthreads();
  if (tid==0){ float r=-3e38f; for(int t=0;t<256;t++){ float t0=sd[t]; sd[t]=r; r=fmaxf(r,t0); } }
  __syncthreads();
  float offm = sd[tid];
  #pragma unroll
  for (int e=0;e<8;e++){
    float M = fmaxf(lm[e], offm);
    Mp[(size_t)h*S_+base+e]=M;
    flp[(size_t)h*S_+base+e]=expf(-loc[e]-M);
    rowsum[(size_t)h*S_+base+e]=0.f;
  }
}

// ---------------- v (b,s,n*DH+d) -> vT (h, d, s) ----------------
__global__ __launch_bounds__(256) void transpose_v(const bf16* __restrict__ v,
    bf16* __restrict__ vT){
  int sb = blockIdx.x, db = blockIdx.y, h = blockIdx.z;
  int b = h >> 2, n = h & 3;
  int s0 = sb*64, d0 = db*64;
  __shared__ short tl[64*LS];
  int tid = threadIdx.x;
  #pragma unroll
  for (int i=0;i<2;i++){
    int vv = tid + i*256; int r = vv>>3, c8 = vv&7;
    uint4 x = *(const uint4*)(v + (size_t)(b*S_+s0+r)*INNER_ + n*DH_ + d0 + c8*8);
    *(uint4*)&tl[r*LS + c8*8] = x;
  }
  __syncthreads();
  #pragma unroll
  for (int i=0;i<2;i++){
    int vv = tid + i*256; int r = vv>>3, c8 = vv&7;   // r = local d, c8 = s-chunk
    unsigned short tmp[8];
    #pragma unroll
    for (int e=0;e<8;e++) tmp[e] = (unsigned short)tl[(c8*8+e)*LS + r];
    uint4 o; __builtin_memcpy(&o, tmp, 16);
    *(uint4*)(vT + ((size_t)h*DH_ + d0 + r)*S_ + s0 + c8*8) = o;
  }
}

// ---------------- W = (Q K^T)*scale*exp(a_j - M_i), causal; + rowsums ----------------
// 64x128 i x j tiles, lower triangle: per head 272 tiles; grid 8*272, h = bid&7.
// pair p (i-tiles 2p,2p+1) has 2(p+1) tiles; cum = p(p+1). Big tiles first.
__global__ __launch_bounds__(256) void qk_decay_kernel(const bf16* __restrict__ qg,
    const bf16* __restrict__ kg, const float* __restrict__ ap,
    const float* __restrict__ Mp, float* __restrict__ rowsum, bf16* __restrict__ W){
  int h = blockIdx.x & 7;
  int t = 271 - (blockIdx.x >> 3);
  int p = (int)((sqrtf(4.f*t+1.f)-1.f)*0.5f);
  while ((p+1)*(p+2) <= t) p++;
  while (p*(p+1) > t) p--;
  int r0 = t - p*(p+1);
  int nj = p + 1;
  int it = 2*p + (r0 >= nj ? 1 : 0);
  int tj = r0 >= nj ? r0 - nj : r0;
  int b = h >> 2, n = h & 3;
  int i0 = it*64, j0 = tj*128;
  __shared__ __align__(16) short Qs[64*64];
  __shared__ __align__(16) short Ks[128*64];
  __shared__ float a_s[128], m_s[64];
  int tid = threadIdx.x;
  if (tid < 128) a_s[tid] = ap[(size_t)h*S_ + j0 + tid];
  if (tid < 64)  m_s[tid] = Mp[(size_t)h*S_ + i0 + tid];
  int w = tid>>6, l = tid&63, lq = l>>4, lr = l&15;
  int wm = (w>>1)*32, wn = (w&1)*64;
  const bf16* Qbase = qg + (size_t)(b*S_+i0)*INNER_ + n*DH_;
  const bf16* Kbase = kg + (size_t)(b*S_+j0)*INNER_ + n*DH_;
  floatx4 acc[2][4];
  #pragma unroll
  for (int mi=0;mi<2;mi++){
    #pragma unroll
    for (int ni=0;ni<4;ni++) acc[mi][ni] = (floatx4){0.f,0.f,0.f,0.f};
  }
  for (int d0=0; d0<DH_; d0+=64){
    __syncthreads();
    STAGE_ASYNC(Qs, Qbase + d0, INNER_, 0);
    STAGE_ASYNC(Qs, Qbase + d0, INNER_, 1);
    #pragma unroll
    for (int kk=0;kk<4;kk++){
      STAGE_ASYNC(Ks, Kbase + d0, INNER_, kk);
    }
    __syncthreads();
    #pragma unroll
    for (int ks=0; ks<2; ks++){
      bf16x8 af[2], bfr[4];
      #pragma unroll
      for (int mi=0;mi<2;mi++) af[mi] = *(const bf16x8*)&Qs[so_(wm+mi*16+lr, ks*4+lq)];
      #pragma unroll
      for (int ni=0;ni<4;ni++) bfr[ni] = *(const bf16x8*)&Ks[so_(wn+ni*16+lr, ks*4+lq)];
      #pragma unroll
      for (int mi=0;mi<2;mi++){
        #pragma unroll
        for (int ni=0;ni<4;ni++)
          acc[mi][ni] = __builtin_amdgcn_mfma_f32_16x16x32_bf16(af[mi], bfr[ni], acc[mi][ni], 0,0,0);
      }
    }
  }
  const float scale = 0.04419417382415922f;   // 1/sqrt(512)
  float rpart[2][4];
  #pragma unroll
  for (int mi=0;mi<2;mi++){
    #pragma unroll
    for (int r=0;r<4;r++) rpart[mi][r]=0.f;
  }
  #pragma unroll
  for (int mi=0;mi<2;mi++){
    #pragma unroll
    for (int ni=0;ni<4;ni++){
      #pragma unroll
      for (int r=0;r<4;r++){
        int rowl = wm + mi*16 + lq*4 + r;
        int coll = wn + ni*16 + lr;
        int gi = i0 + rowl, gj = j0 + coll;
        float wv = 0.f;
        if (gj <= gi) wv = acc[mi][ni][r]*scale*__expf(a_s[coll]-m_s[rowl]);
        W[((size_t)h*S_ + gi)*S_ + gj] = f2b(wv);
        rpart[mi][r] += wv;
      }
    }
  }
  #pragma unroll
  for (int mi=0;mi<2;mi++){
    #pragma unroll
    for (int r=0;r<4;r++){
      float v = rpart[mi][r];
      v += __shfl_xor(v, 1, 16);
      v += __shfl_xor(v, 2, 16);
      v += __shfl_xor(v, 4, 16);
      v += __shfl_xor(v, 8, 16);
      if (lr == 0)
        atomicAdd(&rowsum[(size_t)h*S_ + i0 + wm + mi*16 + lq*4 + r], v);
    }
  }
}

// ---------------- O = (W * inv_row) @ V  (causal k-range), inv fused ----------------
// 64-row i-tiles x 128-d tiles: grid 8*128; h = bid&7; ti descending (big first);
// 4 d-blocks of one i-tile adjacent per-XCD (share W via L2)
__global__ __launch_bounds__(256) void pv_kernel(const bf16* __restrict__ W,
    const bf16* __restrict__ vT, const float* __restrict__ rowsum,
    const float* __restrict__ fl, bf16* __restrict__ O){
  int h = blockIdx.x & 7;
  int s = blockIdx.x >> 3;
  int ti = 31 - (s >> 2), tn = s & 3;
  int b = h >> 2, n = h & 3;
  int i0 = ti*64, d0 = tn*128;
  __shared__ __align__(16) short Ws[64*64];
  __shared__ __align__(16) short Vs[128*64];
  __shared__ float inv_s[64];
  int tid = threadIdx.x;
  if (tid < 64){
    size_t o = (size_t)h*S_ + i0 + tid;
    inv_s[tid] = 1.f/(fmaxf(fabsf(rowsum[o]), fl[o]) + EPS_CELL);
  }
  int w = tid>>6, l = tid&63, lq = l>>4, lr = l&15;
  int wm = (w>>1)*32, wn = (w&1)*64;
  const bf16* Wbase = W + ((size_t)h*S_ + i0)*S_;
  const bf16* Vbase = vT + ((size_t)h*DH_ + d0)*S_;
  floatx4 acc[2][4];
  #pragma unroll
  for (int mi=0;mi<2;mi++){
    #pragma unroll
    for (int ni=0;ni<4;ni++) acc[mi][ni] = (floatx4){0.f,0.f,0.f,0.f};
  }
  int jmax = i0 + 64;
  for (int j0=0; j0<jmax; j0+=64){
    __syncthreads();
    STAGE_ASYNC(Ws, Wbase + j0, S_, 0);
    STAGE_ASYNC(Ws, Wbase + j0, S_, 1);
    #pragma unroll
    for (int kk=0;kk<4;kk++){
      STAGE_ASYNC(Vs, Vbase + j0, S_, kk);
    }
    __syncthreads();
    #pragma unroll
    for (int ks=0; ks<2; ks++){
      bf16x8 af[2], bfr[4];
      #pragma unroll
      for (int mi=0;mi<2;mi++) af[mi] = *(const bf16x8*)&Ws[so_(wm+mi*16+lr, ks*4+lq)];
      #pragma unroll
      for (int ni=0;ni<4;ni++) bfr[ni] = *(const bf16x8*)&Vs[so_(wn+ni*16+lr, ks*4+lq)];
      #pragma unroll
      for (int mi=0;mi<2;mi++){
        #pragma unroll
        for (int ni=0;ni<4;ni++)
          acc[mi][ni] = __builtin_amdgcn_mfma_f32_16x16x32_bf16(af[mi], bfr[ni], acc[mi][ni], 0,0,0);
      }
    }
  }
  #pragma unroll
  for (int mi=0;mi<2;mi++){
    #pragma unroll
    for (int ni=0;ni<4;ni++){
      #pragma unroll
      for (int r=0;r<4;r++){
        int rowl = wm + mi*16 + lq*4 + r;
        int dl = wn + ni*16 + lr;
        float o = acc[mi][ni][r] * inv_s[rowl];
        O[(size_t)(b*S_ + i0 + rowl)*INNER_ + n*DH_ + d0 + dl] = f2b(o);
      }
    }
  }
}

// ---------------- head groupnorm + skip + output gate (in-place into z) ----------
__global__ __launch_bounds__(256) void headnorm_gate(const bf16* __restrict__ h,
    const float* __restrict__ onw, const float* __restrict__ skip,
    const bf16* __restrict__ xca, bf16* __restrict__ up){
  int bid = blockIdx.x;
  int n = bid & 3; int bs = bid >> 2;
  int tid = threadIdx.x;
  size_t hbase = (size_t)bs*INNER_ + n*DH_;
  float v0 = b2f(h[hbase+tid]);
  float v1 = b2f(h[hbase+256+tid]);
  __shared__ float sa[256], sb[256];
  sa[tid]=v0+v1; sb[tid]=v0*v0+v1*v1;
  __syncthreads();
  for (int off=128; off>0; off>>=1){
    if (tid<off){ sa[tid]+=sa[tid+off]; sb[tid]+=sb[tid+off]; }
    __syncthreads();
  }
  float mean = sa[0]*(1.f/DH_);
  float var  = sb[0]*(1.f/DH_) - mean*mean;
  float rstd = rsqrtf(var + LN_EPS_);
  #pragma unroll
  for (int e=0;e<2;e++){
    int dl = e*256+tid; int c = n*DH_+dl;
    float hv = e ? v1 : v0;
    float hn = (hv-mean)*rstd*onw[c];
    float hs = hn + skip[c]*b2f(xca[(size_t)bs*INNER_+c]);
    size_t zoff = (size_t)bs*(2*INNER_) + INNER_ + c;
    float zv = b2f(up[zoff]);
    float sz = zv/(1.f+expf(-zv));
    up[zoff] = f2b(hs*sz);
  }
}

extern "C" void kernel_launch(void* const* d_in, const int* in_sizes, int n_in,
                              void* d_out, int out_size, void* d_ws, size_t ws_size,
                              hipStream_t stream) {
  const float* x      = (const float*)d_in[0];
  const float* w_in   = (const float*)d_in[1];
  const float* b_in   = (const float*)d_in[2];
  const float* ln1_w  = (const float*)d_in[3];
  const float* w_up   = (const float*)d_in[4];
  const float* b_up   = (const float*)d_in[5];
  const float* conv_w = (const float*)d_in[6];
  const float* conv_b = (const float*)d_in[7];
  const float* q_w    = (const float*)d_in[8];
  const float* q_b    = (const float*)d_in[9];
  const float* k_w    = (const float*)d_in[10];
  const float* k_b    = (const float*)d_in[11];
  const float* v_w    = (const float*)d_in[12];
  const float* v_b    = (const float*)d_in[13];
  const float* ig_w   = (const float*)d_in[14];
  const float* ig_b   = (const float*)d_in[15];
  const float* fg_w   = (const float*)d_in[16];
  const float* fg_b   = (const float*)d_in[17];
  const float* onw    = (const float*)d_in[18];
  const float* skip   = (const float*)d_in[19];
  const float* w_down = (const float*)d_in[20];
  const float* b_down = (const float*)d_in[21];
  const float* post_w = (const float*)d_in[22];

  char* p = (char*)d_ws;
  auto alloc = [&](size_t bytes)->void*{ void* r = p; p += (bytes + 255) & ~(size_t)255; return r; };
  bf16* h_in = (bf16*)alloc((size_t)T_*E_*2);        // 8 MB
  bf16* xn   = (bf16*)alloc((size_t)T_*E_*2);        // 8 MB (reused as y later)
  bf16* up   = (bf16*)alloc((size_t)T_*2*INNER_*2);  // 32 MB (x_m | z; z later holds h_gated)
  bf16* xca  = (bf16*)alloc((size_t)T_*INNER_*2);    // 16 MB
  bf16* qb_  = (bf16*)alloc((size_t)T_*INNER_*2);
  bf16* kb_  = (bf16*)alloc((size_t)T_*INNER_*2);
  bf16* vb_  = (bf16*)alloc((size_t)T_*INNER_*2);    // v; later reused as attention O
  bf16* hb_  = (bf16*)alloc((size_t)T_*INNER_*2);    // reused as vT (h,d,s)
  float* igbuf = (float*)alloc((size_t)B_*NH_*S_*4);
  float* fgbuf = (float*)alloc((size_t)B_*NH_*S_*4);
  float* abuf  = (float*)alloc((size_t)B_*NH_*S_*4);
  float* Mbuf  = (float*)alloc((size_t)B_*NH_*S_*4);
  float* flbuf = (float*)alloc((size_t)B_*NH_*S_*4);
  float* rsbuf = (float*)alloc((size_t)B_*NH_*S_*4);
  bf16* Wbuf = (bf16*)alloc((size_t)B_*NH_*S_*S_*2); // 67 MB decay-weighted scores
  bf16* ybuf = xn;   // xn dead after up-projection
  bf16* vTb  = hb_;
  bf16* obuf = vb_;
  // converted-weight scratch overlapping Wbuf (dead until qk_decay / after pv)
  bf16* xbf    = Wbuf;                               // 4 MB, dead after GEMM1
  bf16* w_in_t = Wbuf + (size_t)T_*IN_;              // 1 MB, dead after GEMM1
  bf16* w_up_t = w_in_t + (size_t)E_*IN_;            // 8 MB, dead after GEMM2
  bf16* w_down_t = Wbuf;                             // written AFTER pv_kernel frees Wbuf

  // 0a. convert x -> bf16 ; transpose+convert w_in, w_up
  convert_bf16<<<(T_*IN_/8+255)/256, 256, 0, stream>>>(x, xbf, T_*IN_/8);
  transpose_conv_w<<<dim3(E_/64, IN_/64), 256, 0, stream>>>(w_in, w_in_t, IN_, E_);
  transpose_conv_w<<<dim3((2*INNER_)/64, E_/64), 256, 0, stream>>>(w_up, w_up_t, E_, 2*INNER_);
  // 1. h_in = x @ w_in + b_in     (MM=32, NN=8)
  mfma_gemm<<<(T_/128)*(E_/128), 256, 0, stream>>>(xbf, w_in_t, b_in, h_in, IN_, IN_, E_, E_/128);
  // 2. xn = LN(h_in)*ln1_w
  ln_rows<bf16><<<T_, 256, 0, stream>>>(h_in, nullptr, ln1_w, xn);
  // 3. up = xn @ w_up + b_up   (x_m | z)  (MM=32, NN=32)
  mfma_gemm<<<(T_/128)*((2*INNER_)/128), 256, 0, stream>>>(xn, w_up_t, b_up, up, E_, E_, 2*INNER_, (2*INNER_)/128);
  // 4. x_conv_act = silu(causal_conv(x_m))
  conv_silu_kernel<<<(T_*INNER_)/256, 256, 0, stream>>>(up, conv_w, conv_b, xca);
  // 5. q,k from x_conv_act; v from x_m (block-diagonal 4x4)
  headwise_kernel<<<(T_*INNER_)/256, 256, 0, stream>>>(xca, up, q_w, q_b, k_w, k_b, v_w, v_b, qb_, kb_, vb_);
  // 6. gate pre-activations (16 tokens/block, LDS-staged weights)
  gates_kernel<<<T_/16, 256, 0, stream>>>(qb_, kb_, vb_, ig_w, ig_b, fg_w, fg_b, igbuf, fgbuf);
  // 7. scans: a, M, floor; zero rowsums
  scan8<<<B_*NH_, 256, 0, stream>>>(igbuf, fgbuf, abuf, Mbuf, flbuf, rsbuf);
  // 8. v -> vT (head-major, d-major)
  transpose_v<<<dim3(S_/64, DH_/64, B_*NH_), 256, 0, stream>>>(vb_, vTb);
  // 9. W = QK^T * scale * decay (64x128 lower-triangle tiles, head XCD-pinned), rowsums
  qk_decay_kernel<<<8*272, 256, 0, stream>>>(qb_, kb_, abuf, Mbuf, rsbuf, Wbuf);
  // 10. O = (W*inv) @ V -> obuf; inv fused, head XCD-pinned, 64-row tiles
  pv_kernel<<<8*128, 256, 0, stream>>>(Wbuf, vTb, rsbuf, flbuf, obuf);
  // 11. headnorm + skip + output gate, written in place over z
  headnorm_gate<<<T_*NH_, 256, 0, stream>>>(obuf, onw, skip, xca, up);
  // 11b. transpose+convert w_down (Wbuf now dead)
  transpose_conv_w<<<dim3(E_/64, INNER_/64), 256, 0, stream>>>(w_down, w_down_t, INNER_, E_);
  // 12. y = h_gated @ w_down + b_down  (MM=32, NN=8)
  mfma_gemm<<<(T_/128)*(E_/128), 256, 0, stream>>>(up + INNER_, w_down_t, b_down, ybuf, INNER_, 2*INNER_, E_, E_/128);
  // 13. out = LN(h_in + y)*post_w
  ln_rows<float><<<T_, 256, 0, stream>>>(h_in, ybuf, post_w, (float*)d_out);
}

// Round 11
// 452.243 us; speedup vs baseline: 6.3473x; 1.0290x over previous
//
#include <hip/hip_runtime.h>
#include <hip/hip_bf16.h>

typedef __hip_bfloat16 bf16;
typedef float floatx4 __attribute__((ext_vector_type(4)));
typedef short bf16x8 __attribute__((ext_vector_type(8)));

#define B_      2
#define S_      2048
#define IN_     512
#define E_      1024
#define INNER_  2048
#define NH_     4
#define DH_     512
#define T_      (B_*S_)      // 4096 tokens
#define EPS_CELL 1e-6f
#define LN_EPS_  1e-5f
#define LS      72           // padded LDS row stride (shorts) for non-async kernels

__device__ inline float b2f(bf16 x){ return __bfloat162float(x); }
__device__ inline bf16  f2b(float x){ return __float2bfloat16(x); }
__device__ inline float us2f(unsigned short u){ union{unsigned int i; float f;} v; v.i = ((unsigned int)u)<<16; return v.f; }
__device__ inline float u2f(unsigned int u){ union{unsigned int i; float f;} v; v.i = u; return v.f; }
__device__ inline unsigned short f2bu(float x){ bf16 t = __float2bfloat16(x); unsigned short r; __builtin_memcpy(&r,&t,2); return r; }
__device__ inline void unpack8(uint4 u, float* f){
  f[0]=u2f(u.x<<16); f[1]=u2f(u.x&0xffff0000u);
  f[2]=u2f(u.y<<16); f[3]=u2f(u.y&0xffff0000u);
  f[4]=u2f(u.z<<16); f[5]=u2f(u.z&0xffff0000u);
  f[6]=u2f(u.w<<16); f[7]=u2f(u.w&0xffff0000u);
}
__device__ inline void stv(bf16* p, float v){ *p = f2b(v); }
__device__ inline void stv(float* p, float v){ *p = v; }

// ---- async 16B global->LDS copy (wave-uniform base + lane*16 pattern) ----
typedef __attribute__((address_space(3))) unsigned int lds_u32_t;
typedef __attribute__((address_space(1))) const unsigned int glb_u32_t;
__device__ __forceinline__ void cp_async16(const bf16* g, short* l){
  __builtin_amdgcn_global_load_lds((glb_u32_t*)(const void*)g,
                                   (lds_u32_t*)(void*)l, 16, 0, 0);
}
// swizzled LDS offset (shorts) for Nx64 tile: row-dense, chunk XOR row&7
__device__ __forceinline__ int so_(int row, int c8){ return row*64 + (((c8) ^ (row&7))<<3); }
// epilogue repack offset for Nx128-short tile: chunk XOR row&15
__device__ __forceinline__ int eo_(int row, int ch){ return row*128 + (((ch) ^ (row&15))<<3); }

// stage rows of a {64,128}x64-short tile (row stride `stride` in global)
#define STAGE_ASYNC(dst, srcbase, stride, kk) \
  { int slot_ = (kk)*256 + tid; int r_ = slot_>>3; int c8_ = (slot_&7) ^ (r_&7); \
    cp_async16((srcbase) + (size_t)r_*(stride) + c8_*8, &dst[slot_*8]); }

// ---------------- fp32 -> bf16 elementwise convert ----------------
__global__ __launch_bounds__(256) void convert_bf16(const float* __restrict__ X,
    bf16* __restrict__ Y, int n8){
  int i = blockIdx.x*256 + threadIdx.x;
  if (i >= n8) return;
  const float4* p = (const float4*)(X) + i*2;
  float4 a = p[0], b = p[1];
  ushort4 o0, o1;
  o0.x=f2bu(a.x); o0.y=f2bu(a.y); o0.z=f2bu(a.z); o0.w=f2bu(a.w);
  o1.x=f2bu(b.x); o1.y=f2bu(b.y); o1.z=f2bu(b.z); o1.w=f2bu(b.w);
  ushort4* q = (ushort4*)(Y) + i*2;
  q[0]=o0; q[1]=o1;
}

// ---------------- W[K,N] fp32 -> Wt[N,K] bf16 (64x64 LDS tiles) ----------------
__global__ __launch_bounds__(256) void transpose_conv_w(const float* __restrict__ W,
    bf16* __restrict__ Wt, int K, int N){
  int n0 = blockIdx.x*64, k0 = blockIdx.y*64;
  __shared__ float tl[64][65];
  int tid = threadIdx.x;
  #pragma unroll
  for (int i=0;i<4;i++){
    int idx = tid + i*256; int r = idx>>4, c4 = idx&15;
    float4 v = *(const float4*)(W + (size_t)(k0+r)*N + n0 + c4*4);
    tl[r][c4*4+0]=v.x; tl[r][c4*4+1]=v.y; tl[r][c4*4+2]=v.z; tl[r][c4*4+3]=v.w;
  }
  __syncthreads();
  #pragma unroll
  for (int i=0;i<4;i++){
    int idx = tid + i*256; int rn = idx>>4, c4 = idx&15;
    ushort4 o;
    o.x=f2bu(tl[c4*4+0][rn]); o.y=f2bu(tl[c4*4+1][rn]);
    o.z=f2bu(tl[c4*4+2][rn]); o.w=f2bu(tl[c4*4+3][rn]);
    *(ushort4*)(Wt + (size_t)(n0+rn)*K + k0 + c4*4) = o;
  }
}

// ---------------- MFMA GEMM: C[M,N] = A[M,K] @ Bt[N,K]^T + bias ----------------
// 1-D grid MM*NN; per-XCD m-stripe swizzle. Vectorized LDS-repack epilogue.
__global__ __launch_bounds__(256) void mfma_gemm(const bf16* __restrict__ A,
    const bf16* __restrict__ Bt, const float* __restrict__ bias, bf16* __restrict__ C,
    int Kd, int lda, int ldc, int NN){
  int bid = blockIdx.x;
  int MM = gridDim.x / NN;
  int mPerX = MM >> 3;
  int xcd = bid & 7, seq = bid >> 3;
  int nb = seq % NN, mb = xcd*mPerX + seq / NN;
  int n0 = nb*128, m0 = mb*128;
  __shared__ __align__(16) short smem[128*128];   // As | Bs ; reused for C repack
  short* As = smem;
  short* Bs = smem + 128*64;
  int tid = threadIdx.x;
  int w = tid>>6, l = tid&63, lq = l>>4, lr = l&15;
  int wm = (w>>1)*64, wn = (w&1)*64;
  const bf16* Abase = A + (size_t)m0*lda;
  const bf16* Bbase = Bt + (size_t)n0*Kd;
  floatx4 acc[4][4];
  #pragma unroll
  for (int mi=0;mi<4;mi++){
    #pragma unroll
    for (int ni=0;ni<4;ni++) acc[mi][ni] = (floatx4){0.f,0.f,0.f,0.f};
  }
  for (int k0=0; k0<Kd; k0+=64){
    __syncthreads();
    #pragma unroll
    for (int kk=0;kk<4;kk++){
      STAGE_ASYNC(As, Abase + k0, lda, kk);
      STAGE_ASYNC(Bs, Bbase + k0, Kd, kk);
    }
    __syncthreads();
    #pragma unroll
    for (int ks=0; ks<2; ks++){
      bf16x8 af[4], bfr[4];
      #pragma unroll
      for (int mi=0;mi<4;mi++) af[mi] = *(const bf16x8*)&As[so_(wm+mi*16+lr, ks*4+lq)];
      #pragma unroll
      for (int ni=0;ni<4;ni++) bfr[ni] = *(const bf16x8*)&Bs[so_(wn+ni*16+lr, ks*4+lq)];
      #pragma unroll
      for (int mi=0;mi<4;mi++){
        #pragma unroll
        for (int ni=0;ni<4;ni++)
          acc[mi][ni] = __builtin_amdgcn_mfma_f32_16x16x32_bf16(af[mi], bfr[ni], acc[mi][ni], 0,0,0);
      }
    }
  }
  float bb[4];
  #pragma unroll
  for (int ni=0;ni<4;ni++) bb[ni] = bias[n0 + wn + ni*16 + lr];
  __syncthreads();   // staging LDS dead -> reuse for C repack
  #pragma unroll
  for (int mi=0;mi<4;mi++){
    #pragma unroll
    for (int ni=0;ni<4;ni++){
      int coll = wn + ni*16 + lr;
      int ch = coll>>3, off = coll&7;
      #pragma unroll
      for (int r=0;r<4;r++){
        int rowl = wm + mi*16 + lq*4 + r;
        smem[rowl*128 + (((ch) ^ (rowl&15))<<3) + off] = (short)f2bu(acc[mi][ni][r] + bb[ni]);
      }
    }
  }
  __syncthreads();
  #pragma unroll
  for (int i=0;i<8;i++){
    int slot = i*256 + tid;
    int r = slot >> 4, c8 = slot & 15;
    uint4 val = *(const uint4*)&smem[eo_(r, c8)];
    *(uint4*)(C + (size_t)(m0+r)*ldc + n0 + c8*8) = val;
  }
}

// ---------------- layernorm over rows of length E_ (opt. fused add) ----------------
template<typename OutT>
__global__ __launch_bounds__(256) void ln_rows(const bf16* __restrict__ X,
    const bf16* __restrict__ Xadd, const float* __restrict__ w, OutT* __restrict__ Y){
  int row = blockIdx.x, tid = threadIdx.x;
  size_t base = (size_t)row*E_;
  float vals[4], s=0.f, s2=0.f;
  #pragma unroll
  for (int e=0;e<4;e++){
    int c = e*256+tid;
    float v = b2f(X[base+c]);
    if (Xadd) v += b2f(Xadd[base+c]);
    vals[e]=v; s+=v; s2+=v*v;
  }
  __shared__ float sa[256], sb[256];
  sa[tid]=s; sb[tid]=s2; __syncthreads();
  for (int off=128; off>0; off>>=1){
    if (tid<off){ sa[tid]+=sa[tid+off]; sb[tid]+=sb[tid+off]; }
    __syncthreads();
  }
  float mean = sa[0]*(1.f/E_);
  float var  = sb[0]*(1.f/E_) - mean*mean;
  float rstd = rsqrtf(var + LN_EPS_);
  #pragma unroll
  for (int e=0;e<4;e++){
    int c = e*256+tid;
    stv(&Y[base+c], (vals[e]-mean)*rstd*w[c]);
  }
}

// ---------------- fused causal conv(K=4)+SiLU and block-diagonal q/k/v ----------------
// block = 256 consecutive channels of one token; xca shared via LDS
__global__ __launch_bounds__(256) void conv_headwise(const bf16* __restrict__ up,
    const float* __restrict__ cw, const float* __restrict__ cb,
    const float* __restrict__ qw, const float* __restrict__ qb,
    const float* __restrict__ kw, const float* __restrict__ kb,
    const float* __restrict__ vw, const float* __restrict__ vb,
    bf16* __restrict__ xca, bf16* __restrict__ q, bf16* __restrict__ k,
    bf16* __restrict__ v){
  size_t gid = (size_t)blockIdx.x*256 + threadIdx.x;
  int c = (int)(gid & (INNER_-1));
  size_t bs = gid >> 11;
  int s = (int)(bs & (S_-1));
  float acc = cb[c];
  #pragma unroll
  for (int t=0;t<4;t++){
    int sp = s-3+t;
    if (sp>=0) acc += b2f(up[(bs + (size_t)(t-3))*(size_t)(2*INNER_) + c]) * cw[c*4+t];
  }
  float xcv = acc/(1.f+expf(-acc));
  __shared__ float xcs[256];
  xcs[threadIdx.x] = xcv;
  xca[gid] = f2b(xcv);
  __syncthreads();
  int o = c&3;
  int lb = threadIdx.x & ~3;
  int hw = c>>2;
  float aq=qb[c], ak=kb[c], av=vb[c];
  size_t mb = bs*(size_t)(2*INNER_) + (size_t)(c&~3);
  #pragma unroll
  for (int d=0; d<4; d++){
    float xc = xcs[lb+d];
    float xm = b2f(up[mb+d]);
    int wi = hw*16 + o*4 + d;   // w[h][o][d]
    aq += xc*qw[wi]; ak += xc*kw[wi]; av += xm*vw[wi];
  }
  q[gid]=f2b(aq); k[gid]=f2b(ak); v[gid]=f2b(av);
}

// ---------------- ig/fg gates: 16 tokens/block, weights staged in LDS ----------------
__global__ __launch_bounds__(256) void gates_kernel(const bf16* __restrict__ q,
    const bf16* __restrict__ k, const bf16* __restrict__ v,
    const float* __restrict__ igw, const float* __restrict__ igb,
    const float* __restrict__ fgw, const float* __restrict__ fgb,
    float* __restrict__ igo, float* __restrict__ fgo){
  __shared__ short gw[49160];   // 6144*8 + pad
  int tid = threadIdx.x;
  for (int r = tid; r < 3*INNER_; r += 256){
    float4 a = *(const float4*)(igw + (size_t)r*4);
    float4 b = *(const float4*)(fgw + (size_t)r*4);
    int slot = r ^ ((r>>3)&7);
    ushort4 o0, o1;
    o0.x=f2bu(a.x); o0.y=f2bu(a.y); o0.z=f2bu(a.z); o0.w=f2bu(a.w);
    o1.x=f2bu(b.x); o1.y=f2bu(b.y); o1.z=f2bu(b.z); o1.w=f2bu(b.w);
    *(ushort4*)&gw[slot*8]   = o0;
    *(ushort4*)&gw[slot*8+4] = o1;
  }
  __syncthreads();
  int tok = blockIdx.x*16 + (tid>>4);   // global token
  int sl  = tid & 15;
  int b = tok >> 11, s = tok & (S_-1);
  size_t rb = (size_t)tok * INNER_;
  const bf16* srcs[3] = {q + rb, k + rb, v + rb};
  float acc[8];
  #pragma unroll
  for (int n=0;n<8;n++) acc[n]=0.f;
  #pragma unroll
  for (int src=0; src<3; src++){
    const bf16* ptr = srcs[src];
    int kb = src*INNER_;
    #pragma unroll 4
    for (int j=0; j<16; j++){
      int pos = j*128 + sl*8;
      uint4 dv = *(const uint4*)(ptr + pos);
      float d[8]; unpack8(dv, d);
      int rbase = kb + pos;                 // multiple of 8
      int cxor = (rbase>>3)&7;              // constant over e within the group
      #pragma unroll
      for (int e=0;e<8;e++){
        int slot = (rbase + e) ^ cxor;
        uint4 wv = *(const uint4*)&gw[slot*8];
        float w8[8]; unpack8(wv, w8);
        #pragma unroll
        for (int n=0;n<8;n++) acc[n] += d[e]*w8[n];
      }
    }
  }
  #pragma unroll
  for (int off=1; off<16; off<<=1){
    #pragma unroll
    for (int n=0;n<8;n++) acc[n] += __shfl_xor(acc[n], off, 16);
  }
  if (sl < 8){
    int n = sl & 3;
    if (sl < 4) igo[((size_t)(b*NH_+n))*S_ + s] = acc[sl] + igb[n];
    else        fgo[((size_t)(b*NH_+n))*S_ + s] = acc[sl] + fgb[n];
  }
}

// ---------------- per-head scan: F=cumsum(logsigmoid(fg)); a=ig-F; M=prefmax(a) ----
__global__ __launch_bounds__(256) void scan8(const float* __restrict__ igp,
    const float* __restrict__ fgp, float* __restrict__ ap,
    float* __restrict__ Mp, float* __restrict__ flp, float* __restrict__ rowsum){
  int h = blockIdx.x, tid = threadIdx.x;
  const float* fg = fgp + (size_t)h*S_;
  const float* ig = igp + (size_t)h*S_;
  int base = tid*8;
  float loc[8], run = 0.f;
  #pragma unroll
  for (int e=0;e<8;e++){
    float x = fg[base+e];
    float ls = fminf(x,0.f) - log1pf(expf(-fabsf(x)));
    run += ls; loc[e] = run;
  }
  __shared__ float sd[256];
  sd[tid]=run; __syncthreads();
  if (tid==0){ float r=0.f; for(int t=0;t<256;t++){ float t0=sd[t]; sd[t]=r; r+=t0; } }
  __syncthreads();
  float off = sd[tid];
  float lm[8], rm = -3e38f;
  #pragma unroll
  for (int e=0;e<8;e++){
    float F = loc[e]+off; loc[e]=F;
    float aj = ig[base+e]-F;
    ap[(size_t)h*S_+base+e]=aj;
    rm = fmaxf(rm, aj); lm[e]=rm;
  }
  __syncthreads();
  sd[tid]=rm; __syncthreads();
  if (tid==0){ float r=-3e38f; for(int t=0;t<256;t++){ float t0=sd[t]; sd[t]=r; r=fmaxf(r,t0); } }
  __syncthreads();
  float offm = sd[tid];
  #pragma unroll
  for (int e=0;e<8;e++){
    float M = fmaxf(lm[e], offm);
    Mp[(size_t)h*S_+base+e]=M;
    flp[(size_t)h*S_+base+e]=expf(-loc[e]-M);
    rowsum[(size_t)h*S_+base+e]=0.f;
  }
}

// ---------------- v (b,s,n*DH+d) -> vT (h, d, s) ----------------
__global__ __launch_bounds__(256) void transpose_v(const bf16* __restrict__ v,
    bf16* __restrict__ vT){
  int sb = blockIdx.x, db = blockIdx.y, h = blockIdx.z;
  int b = h >> 2, n = h & 3;
  int s0 = sb*64, d0 = db*64;
  __shared__ short tl[64*LS];
  int tid = threadIdx.x;
  #pragma unroll
  for (int i=0;i<2;i++){
    int vv = tid + i*256; int r = vv>>3, c8 = vv&7;
    uint4 x = *(const uint4*)(v + (size_t)(b*S_+s0+r)*INNER_ + n*DH_ + d0 + c8*8);
    *(uint4*)&tl[r*LS + c8*8] = x;
  }
  __syncthreads();
  #pragma unroll
  for (int i=0;i<2;i++){
    int vv = tid + i*256; int r = vv>>3, c8 = vv&7;   // r = local d, c8 = s-chunk
    unsigned short tmp[8];
    #pragma unroll
    for (int e=0;e<8;e++) tmp[e] = (unsigned short)tl[(c8*8+e)*LS + r];
    uint4 o; __builtin_memcpy(&o, tmp, 16);
    *(uint4*)(vT + ((size_t)h*DH_ + d0 + r)*S_ + s0 + c8*8) = o;
  }
}

// ---------------- W = (Q K^T)*scale*exp(a_j - M_i), causal; + rowsums ----------------
// 64x128 i x j tiles, lower triangle; grid 8*272, h = bid&7 (XCD-pinned).
__global__ __launch_bounds__(256) void qk_decay_kernel(const bf16* __restrict__ qg,
    const bf16* __restrict__ kg, const float* __restrict__ ap,
    const float* __restrict__ Mp, float* __restrict__ rowsum, bf16* __restrict__ W){
  int h = blockIdx.x & 7;
  int t = 271 - (blockIdx.x >> 3);
  int p = (int)((sqrtf(4.f*t+1.f)-1.f)*0.5f);
  while ((p+1)*(p+2) <= t) p++;
  while (p*(p+1) > t) p--;
  int r0 = t - p*(p+1);
  int nj = p + 1;
  int it = 2*p + (r0 >= nj ? 1 : 0);
  int tj = r0 >= nj ? r0 - nj : r0;
  int b = h >> 2, n = h & 3;
  int i0 = it*64, j0 = tj*128;
  __shared__ __align__(16) short smem[64*64 + 128*64];  // Qs | Ks ; reused for W repack
  short* Qs = smem;
  short* Ks = smem + 64*64;
  __shared__ float a_s[128], m_s[64];
  int tid = threadIdx.x;
  if (tid < 128) a_s[tid] = ap[(size_t)h*S_ + j0 + tid];
  if (tid < 64)  m_s[tid] = Mp[(size_t)h*S_ + i0 + tid];
  int w = tid>>6, l = tid&63, lq = l>>4, lr = l&15;
  int wm = (w>>1)*32, wn = (w&1)*64;
  const bf16* Qbase = qg + (size_t)(b*S_+i0)*INNER_ + n*DH_;
  const bf16* Kbase = kg + (size_t)(b*S_+j0)*INNER_ + n*DH_;
  floatx4 acc[2][4];
  #pragma unroll
  for (int mi=0;mi<2;mi++){
    #pragma unroll
    for (int ni=0;ni<4;ni++) acc[mi][ni] = (floatx4){0.f,0.f,0.f,0.f};
  }
  for (int d0=0; d0<DH_; d0+=64){
    __syncthreads();
    STAGE_ASYNC(Qs, Qbase + d0, INNER_, 0);
    STAGE_ASYNC(Qs, Qbase + d0, INNER_, 1);
    #pragma unroll
    for (int kk=0;kk<4;kk++){
      STAGE_ASYNC(Ks, Kbase + d0, INNER_, kk);
    }
    __syncthreads();
    #pragma unroll
    for (int ks=0; ks<2; ks++){
      bf16x8 af[2], bfr[4];
      #pragma unroll
      for (int mi=0;mi<2;mi++) af[mi] = *(const bf16x8*)&Qs[so_(wm+mi*16+lr, ks*4+lq)];
      #pragma unroll
      for (int ni=0;ni<4;ni++) bfr[ni] = *(const bf16x8*)&Ks[so_(wn+ni*16+lr, ks*4+lq)];
      #pragma unroll
      for (int mi=0;mi<2;mi++){
        #pragma unroll
        for (int ni=0;ni<4;ni++)
          acc[mi][ni] = __builtin_amdgcn_mfma_f32_16x16x32_bf16(af[mi], bfr[ni], acc[mi][ni], 0,0,0);
      }
    }
  }
  const float scale = 0.04419417382415922f;   // 1/sqrt(512)
  float rpart[2][4];
  #pragma unroll
  for (int mi=0;mi<2;mi++){
    #pragma unroll
    for (int r=0;r<4;r++) rpart[mi][r]=0.f;
  }
  __syncthreads();   // staging LDS dead -> reuse for W repack
  #pragma unroll
  for (int mi=0;mi<2;mi++){
    #pragma unroll
    for (int ni=0;ni<4;ni++){
      int coll = wn + ni*16 + lr;
      int ch = coll>>3, off = coll&7;
      float av = a_s[coll];
      #pragma unroll
      for (int r=0;r<4;r++){
        int rowl = wm + mi*16 + lq*4 + r;
        int gi = i0 + rowl, gj = j0 + coll;
        float wv = 0.f;
        if (gj <= gi) wv = acc[mi][ni][r]*scale*__expf(av-m_s[rowl]);
        smem[rowl*128 + (((ch) ^ (rowl&15))<<3) + off] = (short)f2bu(wv);
        rpart[mi][r] += wv;
      }
    }
  }
  __syncthreads();
  #pragma unroll
  for (int i=0;i<4;i++){
    int slot = i*256 + tid;
    int r = slot >> 4, c8 = slot & 15;
    uint4 val = *(const uint4*)&smem[eo_(r, c8)];
    *(uint4*)(W + ((size_t)h*S_ + i0 + r)*S_ + j0 + c8*8) = val;
  }
  #pragma unroll
  for (int mi=0;mi<2;mi++){
    #pragma unroll
    for (int r=0;r<4;r++){
      float v = rpart[mi][r];
      v += __shfl_xor(v, 1, 16);
      v += __shfl_xor(v, 2, 16);
      v += __shfl_xor(v, 4, 16);
      v += __shfl_xor(v, 8, 16);
      if (lr == 0)
        atomicAdd(&rowsum[(size_t)h*S_ + i0 + wm + mi*16 + lq*4 + r], v);
    }
  }
}

// ---------------- O = (W * inv_row) @ V  (causal k-range), inv fused ----------------
// 64-row i-tiles x 128-d tiles: grid 8*128; h = bid&7 (XCD-pinned); ti descending
__global__ __launch_bounds__(256) void pv_kernel(const bf16* __restrict__ W,
    const bf16* __restrict__ vT, const float* __restrict__ rowsum,
    const float* __restrict__ fl, bf16* __restrict__ O){
  int h = blockIdx.x & 7;
  int s = blockIdx.x >> 3;
  int ti = 31 - (s >> 2), tn = s & 3;
  int b = h >> 2, n = h & 3;
  int i0 = ti*64, d0 = tn*128;
  __shared__ __align__(16) short smem[64*64 + 128*64];  // Ws | Vs ; reused for O repack
  short* Ws = smem;
  short* Vs = smem + 64*64;
  __shared__ float inv_s[64];
  int tid = threadIdx.x;
  if (tid < 64){
    size_t o = (size_t)h*S_ + i0 + tid;
    inv_s[tid] = 1.f/(fmaxf(fabsf(rowsum[o]), fl[o]) + EPS_CELL);
  }
  int w = tid>>6, l = tid&63, lq = l>>4, lr = l&15;
  int wm = (w>>1)*32, wn = (w&1)*64;
  const bf16* Wbase = W + ((size_t)h*S_ + i0)*S_;
  const bf16* Vbase = vT + ((size_t)h*DH_ + d0)*S_;
  floatx4 acc[2][4];
  #pragma unroll
  for (int mi=0;mi<2;mi++){
    #pragma unroll
    for (int ni=0;ni<4;ni++) acc[mi][ni] = (floatx4){0.f,0.f,0.f,0.f};
  }
  int jmax = i0 + 64;
  for (int j0=0; j0<jmax; j0+=64){
    __syncthreads();
    STAGE_ASYNC(Ws, Wbase + j0, S_, 0);
    STAGE_ASYNC(Ws, Wbase + j0, S_, 1);
    #pragma unroll
    for (int kk=0;kk<4;kk++){
      STAGE_ASYNC(Vs, Vbase + j0, S_, kk);
    }
    __syncthreads();
    #pragma unroll
    for (int ks=0; ks<2; ks++){
      bf16x8 af[2], bfr[4];
      #pragma unroll
      for (int mi=0;mi<2;mi++) af[mi] = *(const bf16x8*)&Ws[so_(wm+mi*16+lr, ks*4+lq)];
      #pragma unroll
      for (int ni=0;ni<4;ni++) bfr[ni] = *(const bf16x8*)&Vs[so_(wn+ni*16+lr, ks*4+lq)];
      #pragma unroll
      for (int mi=0;mi<2;mi++){
        #pragma unroll
        for (int ni=0;ni<4;ni++)
          acc[mi][ni] = __builtin_amdgcn_mfma_f32_16x16x32_bf16(af[mi], bfr[ni], acc[mi][ni], 0,0,0);
      }
    }
  }
  __syncthreads();   // staging LDS dead -> reuse for O repack
  #pragma unroll
  for (int mi=0;mi<2;mi++){
    #pragma unroll
    for (int ni=0;ni<4;ni++){
      int dl = wn + ni*16 + lr;
      int ch = dl>>3, off = dl&7;
      #pragma unroll
      for (int r=0;r<4;r++){
        int rowl = wm + mi*16 + lq*4 + r;
        smem[rowl*128 + (((ch) ^ (rowl&15))<<3) + off] = (short)f2bu(acc[mi][ni][r] * inv_s[rowl]);
      }
    }
  }
  __syncthreads();
  #pragma unroll
  for (int i=0;i<4;i++){
    int slot = i*256 + tid;
    int r = slot >> 4, c8 = slot & 15;
    uint4 val = *(const uint4*)&smem[eo_(r, c8)];
    *(uint4*)(O + (size_t)(b*S_ + i0 + r)*INNER_ + n*DH_ + d0 + c8*8) = val;
  }
}

// ---------------- head groupnorm + skip + output gate (in-place into z) ----------
__global__ __launch_bounds__(256) void headnorm_gate(const bf16* __restrict__ h,
    const float* __restrict__ onw, const float* __restrict__ skip,
    const bf16* __restrict__ xca, bf16* __restrict__ up){
  int bid = blockIdx.x;
  int n = bid & 3; int bs = bid >> 2;
  int tid = threadIdx.x;
  size_t hbase = (size_t)bs*INNER_ + n*DH_;
  float v0 = b2f(h[hbase+tid]);
  float v1 = b2f(h[hbase+256+tid]);
  __shared__ float sa[256], sb[256];
  sa[tid]=v0+v1; sb[tid]=v0*v0+v1*v1;
  __syncthreads();
  for (int off=128; off>0; off>>=1){
    if (tid<off){ sa[tid]+=sa[tid+off]; sb[tid]+=sb[tid+off]; }
    __syncthreads();
  }
  float mean = sa[0]*(1.f/DH_);
  float var  = sb[0]*(1.f/DH_) - mean*mean;
  float rstd = rsqrtf(var + LN_EPS_);
  #pragma unroll
  for (int e=0;e<2;e++){
    int dl = e*256+tid; int c = n*DH_+dl;
    float hv = e ? v1 : v0;
    float hn = (hv-mean)*rstd*onw[c];
    float hs = hn + skip[c]*b2f(xca[(size_t)bs*INNER_+c]);
    size_t zoff = (size_t)bs*(2*INNER_) + INNER_ + c;
    float zv = b2f(up[zoff]);
    float sz = zv/(1.f+expf(-zv));
    up[zoff] = f2b(hs*sz);
  }
}

extern "C" void kernel_launch(void* const* d_in, const int* in_sizes, int n_in,
                              void* d_out, int out_size, void* d_ws, size_t ws_size,
                              hipStream_t stream) {
  const float* x      = (const float*)d_in[0];
  const float* w_in   = (const float*)d_in[1];
  const float* b_in   = (const float*)d_in[2];
  const float* ln1_w  = (const float*)d_in[3];
  const float* w_up   = (const float*)d_in[4];
  const float* b_up   = (const float*)d_in[5];
  const float* conv_w = (const float*)d_in[6];
  const float* conv_b = (const float*)d_in[7];
  const float* q_w    = (const float*)d_in[8];
  const float* q_b    = (const float*)d_in[9];
  const float* k_w    = (const float*)d_in[10];
  const float* k_b    = (const float*)d_in[11];
  const float* v_w    = (const float*)d_in[12];
  const float* v_b    = (const float*)d_in[13];
  const float* ig_w   = (const float*)d_in[14];
  const float* ig_b   = (const float*)d_in[15];
  const float* fg_w   = (const float*)d_in[16];
  const float* fg_b   = (const float*)d_in[17];
  const float* onw    = (const float*)d_in[18];
  const float* skip   = (const float*)d_in[19];
  const float* w_down = (const float*)d_in[20];
  const float* b_down = (const float*)d_in[21];
  const float* post_w = (const float*)d_in[22];

  char* p = (char*)d_ws;
  auto alloc = [&](size_t bytes)->void*{ void* r = p; p += (bytes + 255) & ~(size_t)255; return r; };
  bf16* h_in = (bf16*)alloc((size_t)T_*E_*2);        // 8 MB
  bf16* xn   = (bf16*)alloc((size_t)T_*E_*2);        // 8 MB (reused as y later)
  bf16* up   = (bf16*)alloc((size_t)T_*2*INNER_*2);  // 32 MB (x_m | z; z later holds h_gated)
  bf16* xca  = (bf16*)alloc((size_t)T_*INNER_*2);    // 16 MB
  bf16* qb_  = (bf16*)alloc((size_t)T_*INNER_*2);
  bf16* kb_  = (bf16*)alloc((size_t)T_*INNER_*2);
  bf16* vb_  = (bf16*)alloc((size_t)T_*INNER_*2);    // v; later reused as attention O
  bf16* hb_  = (bf16*)alloc((size_t)T_*INNER_*2);    // reused as vT (h,d,s)
  float* igbuf = (float*)alloc((size_t)B_*NH_*S_*4);
  float* fgbuf = (float*)alloc((size_t)B_*NH_*S_*4);
  float* abuf  = (float*)alloc((size_t)B_*NH_*S_*4);
  float* Mbuf  = (float*)alloc((size_t)B_*NH_*S_*4);
  float* flbuf = (float*)alloc((size_t)B_*NH_*S_*4);
  float* rsbuf = (float*)alloc((size_t)B_*NH_*S_*4);
  bf16* Wbuf = (bf16*)alloc((size_t)B_*NH_*S_*S_*2); // 67 MB decay-weighted scores
  bf16* ybuf = xn;   // xn dead after up-projection
  bf16* vTb  = hb_;
  bf16* obuf = vb_;
  // converted-weight scratch overlapping Wbuf (dead until qk_decay / after pv)
  bf16* xbf    = Wbuf;                               // 4 MB, dead after GEMM1
  bf16* w_in_t = Wbuf + (size_t)T_*IN_;              // 1 MB, dead after GEMM1
  bf16* w_up_t = w_in_t + (size_t)E_*IN_;            // 8 MB, dead after GEMM2
  bf16* w_down_t = Wbuf;                             // written AFTER pv_kernel frees Wbuf

  // 0a. convert x -> bf16 ; transpose+convert w_in, w_up
  convert_bf16<<<(T_*IN_/8+255)/256, 256, 0, stream>>>(x, xbf, T_*IN_/8);
  transpose_conv_w<<<dim3(E_/64, IN_/64), 256, 0, stream>>>(w_in, w_in_t, IN_, E_);
  transpose_conv_w<<<dim3((2*INNER_)/64, E_/64), 256, 0, stream>>>(w_up, w_up_t, E_, 2*INNER_);
  // 1. h_in = x @ w_in + b_in     (MM=32, NN=8)
  mfma_gemm<<<(T_/128)*(E_/128), 256, 0, stream>>>(xbf, w_in_t, b_in, h_in, IN_, IN_, E_, E_/128);
  // 2. xn = LN(h_in)*ln1_w
  ln_rows<bf16><<<T_, 256, 0, stream>>>(h_in, nullptr, ln1_w, xn);
  // 3. up = xn @ w_up + b_up   (x_m | z)  (MM=32, NN=32)
  mfma_gemm<<<(T_/128)*((2*INNER_)/128), 256, 0, stream>>>(xn, w_up_t, b_up, up, E_, E_, 2*INNER_, (2*INNER_)/128);
  // 4+5. fused conv+SiLU and q/k/v projections
  conv_headwise<<<(T_*INNER_)/256, 256, 0, stream>>>(up, conv_w, conv_b,
      q_w, q_b, k_w, k_b, v_w, v_b, xca, qb_, kb_, vb_);
  // 6. gate pre-activations (16 tokens/block, LDS-staged weights)
  gates_kernel<<<T_/16, 256, 0, stream>>>(qb_, kb_, vb_, ig_w, ig_b, fg_w, fg_b, igbuf, fgbuf);
  // 7. scans: a, M, floor; zero rowsums
  scan8<<<B_*NH_, 256, 0, stream>>>(igbuf, fgbuf, abuf, Mbuf, flbuf, rsbuf);
  // 8. v -> vT (head-major, d-major)
  transpose_v<<<dim3(S_/64, DH_/64, B_*NH_), 256, 0, stream>>>(vb_, vTb);
  // 9. W = QK^T * scale * decay (64x128 lower-triangle tiles, head XCD-pinned), rowsums
  qk_decay_kernel<<<8*272, 256, 0, stream>>>(qb_, kb_, abuf, Mbuf, rsbuf, Wbuf);
  // 10. O = (W*inv) @ V -> obuf; inv fused, head XCD-pinned, 64-row tiles
  pv_kernel<<<8*128, 256, 0, stream>>>(Wbuf, vTb, rsbuf, flbuf, obuf);
  // 11. headnorm + skip + output gate, written in place over z
  headnorm_gate<<<T_*NH_, 256, 0, stream>>>(obuf, onw, skip, xca, up);
  // 11b. transpose+convert w_down (Wbuf now dead)
  transpose_conv_w<<<dim3(E_/64, INNER_/64), 256, 0, stream>>>(w_down, w_down_t, INNER_, E_);
  // 12. y = h_gated @ w_down + b_down  (MM=32, NN=8)
  mfma_gemm<<<(T_/128)*(E_/128), 256, 0, stream>>>(up + INNER_, w_down_t, b_down, ybuf, INNER_, 2*INNER_, E_, E_/128);
  // 13. out = LN(h_in + y)*post_w
  ln_rows<float><<<T_, 256, 0, stream>>>(h_in, ybuf, post_w, (float*)d_out);
}